// Round 10
// baseline (3663.792 us; speedup 1.0000x reference)
//
#include <hip/hip_runtime.h>
#include <hip/hip_bf16.h>

typedef __hip_bfloat16 bf16;
typedef __attribute__((ext_vector_type(4))) short short4v;
typedef __attribute__((ext_vector_type(8))) short short8v;
typedef __attribute__((ext_vector_type(4))) float f32x4;

#define B_   16
#define L_   512
#define HR   300
#define DM_  600
#define DK_  75
#define MAXA 8
#define NCH  38            // u-chunks per dir (37*8 + 4)

// ---------------------------------------------------------------- embed
// embs layout: [seq = t*16 + b][360]
__global__ __launch_bounds__(256) void k_embed(
    const int* __restrict__ tok, const int* __restrict__ pos, const int* __restrict__ post,
    const float* __restrict__ emb_w, const float* __restrict__ pos_w, const float* __restrict__ post_w,
    float* __restrict__ embs)
{
  int idx = blockIdx.x * 256 + threadIdx.x;
  if (idx >= L_ * B_ * 360) return;
  int d = idx % 360;
  int seq = idx / 360;
  int b = seq & 15, t = seq >> 4;
  int si = b * L_ + t;
  float v;
  if (d < 300)       v = emb_w[(long)tok[si] * 300 + d];
  else if (d < 330)  v = pos_w[pos[si] * 30 + (d - 300)];
  else               v = post_w[post[si] * 30 + (d - 330)];
  embs[idx] = v;
}

// ---------------------------------------------------------------- weight staging (one launch)
// dst layout: wqk[720000] | bqk[1200] | wih[864000] | aff[180000]
__global__ __launch_bounds__(256) void k_stage(
    const float* __restrict__ wq, const float* __restrict__ wk,
    const float* __restrict__ bq, const float* __restrict__ bk,
    const float* __restrict__ wihf, const float* __restrict__ wihb,
    const float* __restrict__ aff1, const float* __restrict__ aff2,
    float* __restrict__ wqk, float* __restrict__ bqk,
    float* __restrict__ wih, float* __restrict__ aff)
{
  int i = blockIdx.x * 256 + threadIdx.x;
  if (i < 360000) wqk[i] = wq[i];
  else if (i < 720000) wqk[i] = wk[i - 360000];
  else if (i < 720600) bqk[i - 720000] = bq[i - 720000];
  else if (i < 721200) bqk[i - 720000] = bk[i - 720600];
  else if (i < 1153200) wih[i - 721200] = wihf[i - 721200];
  else if (i < 1585200) wih[i - 721200] = wihb[i - 1153200];
  else if (i < 1675200) aff[i - 1585200] = aff1[i - 1585200];
  else if (i < 1765200) aff[i - 1585200] = aff2[i - 1675200];
}

// ---------------------------------------------------------------- MFMA GEMM (bf16x3 split), 128x128 tile, 2x2 waves
__device__ inline short2 splitf(float x) {
  bf16 h = __float2bfloat16(x);
  float r = x - __bfloat162float(h);
  bf16 l2 = __float2bfloat16(r);
  short2 out;
  out.x = *reinterpret_cast<short*>(&h);
  out.y = *reinterpret_cast<short*>(&l2);
  return out;
}

__device__ inline short8v ld_frag(const short* p) {
  short4v a = *reinterpret_cast<const short4v*>(p);
  short4v b = *reinterpret_cast<const short4v*>(p + 16);
  short8v r;
  r[0]=a[0]; r[1]=a[1]; r[2]=a[2]; r[3]=a[3];
  r[4]=b[0]; r[5]=b[1]; r[6]=b[2]; r[7]=b[3];
  return r;
}

#define LDA_ 36   // row stride in shorts (32 + 4 pad)

template<bool NT>
__global__ __launch_bounds__(256) void k_mgemm(
    const float* __restrict__ A, int lda, long sA1, long sA2,
    const float* __restrict__ Bm, int ldb, long sB1, long sB2,
    float* __restrict__ C, bf16* __restrict__ Cbf, int ldc, long sC1, long sC2,
    const float* __restrict__ bias, long sBias,
    const float* __restrict__ rowdiv,
    float alpha, int relu, int M, int N, int K, int nb2)
{
  __shared__ short Ah[128 * LDA_], Al[128 * LDA_], Bh[128 * LDA_], Bl[128 * LDA_];
  const int tid = threadIdx.x;
  const int w = tid >> 6, l = tid & 63;
  const int wm = w >> 1, wn = w & 1;
  const int z = blockIdx.z;
  const int b1 = z / nb2, b2 = z - b1 * nb2;
  const float* Ab = A + b1 * sA1 + b2 * sA2;
  const float* Bb = Bm + b1 * sB1 + b2 * sB2;
  const int row0 = blockIdx.y * 128, col0 = blockIdx.x * 128;

  f32x4 acc[4][4];   // [fr][fc]
#pragma unroll
  for (int fr = 0; fr < 4; ++fr)
#pragma unroll
    for (int fc = 0; fc < 4; ++fc) acc[fr][fc] = (f32x4){0.f, 0.f, 0.f, 0.f};

  const int lrow = l & 15, lk = (l >> 4) * 4;

  for (int k0 = 0; k0 < K; k0 += 32) {
    // ---- stage A: 128 rows x 32 k (1024 float4-slots, 4/thread) ----
#pragma unroll
    for (int j = 0; j < 4; ++j) {
      int slot = j * 256 + tid;
      int r = slot >> 3, kq = slot & 7;
      int gr = row0 + r, gk = k0 + kq * 4;
      float v[4] = {0.f, 0.f, 0.f, 0.f};
      if (gr < M) {
        if (gk + 3 < K) {
          float4 t = *reinterpret_cast<const float4*>(Ab + (long)gr * lda + gk);
          v[0] = t.x; v[1] = t.y; v[2] = t.z; v[3] = t.w;
        } else {
#pragma unroll
          for (int q = 0; q < 4; ++q) if (gk + q < K) v[q] = Ab[(long)gr * lda + gk + q];
        }
      }
      short4v hv, lv;
#pragma unroll
      for (int q = 0; q < 4; ++q) {
        short2 t2 = splitf(v[q]);
        hv[q] = t2.x; lv[q] = t2.y;
      }
      *reinterpret_cast<short4v*>(&Ah[r * LDA_ + kq * 4]) = hv;
      *reinterpret_cast<short4v*>(&Al[r * LDA_ + kq * 4]) = lv;
    }
    // ---- stage B: 128 x 32 ----
    if (NT) {
#pragma unroll
      for (int j = 0; j < 4; ++j) {
        int slot = j * 256 + tid;
        int r = slot >> 3, kq = slot & 7;
        int gc = col0 + r, gk = k0 + kq * 4;
        float v[4] = {0.f, 0.f, 0.f, 0.f};
        if (gc < N) {
          if (gk + 3 < K) {
            float4 t = *reinterpret_cast<const float4*>(Bb + (long)gc * ldb + gk);
            v[0] = t.x; v[1] = t.y; v[2] = t.z; v[3] = t.w;
          } else {
#pragma unroll
            for (int q = 0; q < 4; ++q) if (gk + q < K) v[q] = Bb[(long)gc * ldb + gk + q];
          }
        }
        short4v hv, lv;
#pragma unroll
        for (int q = 0; q < 4; ++q) {
          short2 t2 = splitf(v[q]);
          hv[q] = t2.x; lv[q] = t2.y;
        }
        *reinterpret_cast<short4v*>(&Bh[r * LDA_ + kq * 4]) = hv;
        *reinterpret_cast<short4v*>(&Bl[r * LDA_ + kq * 4]) = lv;
      }
    } else {
#pragma unroll
      for (int j = 0; j < 4; ++j) {
        int slot = j * 256 + tid;
        int kk = slot >> 5, nq = slot & 31;
        int gk = k0 + kk, gn = col0 + nq * 4;
        float v[4] = {0.f, 0.f, 0.f, 0.f};
        if (gk < K) {
          if (gn + 3 < N) {
            float4 t = *reinterpret_cast<const float4*>(Bb + (long)gk * ldb + gn);
            v[0] = t.x; v[1] = t.y; v[2] = t.z; v[3] = t.w;
          } else {
#pragma unroll
            for (int q = 0; q < 4; ++q) if (gn + q < N) v[q] = Bb[(long)gk * ldb + gn + q];
          }
        }
#pragma unroll
        for (int q = 0; q < 4; ++q) {
          short2 t2 = splitf(v[q]);
          Bh[(nq * 4 + q) * LDA_ + kk] = t2.x;
          Bl[(nq * 4 + q) * LDA_ + kk] = t2.y;
        }
      }
    }
    __syncthreads();

    // ---- compute: wave (wm,wn) owns rows wm*64.., cols wn*64.. ----
    short8v ah[4], al[4];
#pragma unroll
    for (int fr = 0; fr < 4; ++fr) {
      int ar = wm * 64 + fr * 16 + lrow;
      ah[fr] = ld_frag(&Ah[ar * LDA_ + lk]);
      al[fr] = ld_frag(&Al[ar * LDA_ + lk]);
    }
#pragma unroll
    for (int fc = 0; fc < 4; ++fc) {
      int br = wn * 64 + fc * 16 + lrow;
      short8v bh = ld_frag(&Bh[br * LDA_ + lk]);
      short8v bl = ld_frag(&Bl[br * LDA_ + lk]);
#pragma unroll
      for (int fr = 0; fr < 4; ++fr) {
        acc[fr][fc] = __builtin_amdgcn_mfma_f32_16x16x32_bf16(ah[fr], bh, acc[fr][fc], 0, 0, 0);
        acc[fr][fc] = __builtin_amdgcn_mfma_f32_16x16x32_bf16(ah[fr], bl, acc[fr][fc], 0, 0, 0);
        acc[fr][fc] = __builtin_amdgcn_mfma_f32_16x16x32_bf16(al[fr], bh, acc[fr][fc], 0, 0, 0);
      }
    }
    __syncthreads();
  }

  float* Cb = C ? C + b1 * sC1 + b2 * sC2 : (float*)0;
  bf16*  Cf = Cbf ? Cbf + b1 * sC1 + b2 * sC2 : (bf16*)0;
#pragma unroll
  for (int fr = 0; fr < 4; ++fr)
#pragma unroll
  for (int fc = 0; fc < 4; ++fc) {
    int cc = col0 + wn * 64 + fc * 16 + lrow;
    if (cc >= N) continue;
#pragma unroll
    for (int reg = 0; reg < 4; ++reg) {
      int r = row0 + wm * 64 + fr * 16 + (l >> 4) * 4 + reg;
      if (r >= M) continue;
      float v = acc[fr][fc][reg] * alpha;
      if (bias) v += bias[b1 * sBias + cc];
      if (rowdiv) v /= rowdiv[(long)z * M + r];
      if (relu) v = fmaxf(v, 0.f);
      if (Cf) Cf[(long)r * ldc + cc] = __float2bfloat16(v);
      else    Cb[(long)r * ldc + cc] = v;
    }
  }
}

// ---------------------------------------------------------------- BiLSTM (tagged-word sync)
__global__ __launch_bounds__(256, 1) void k_lstm(
    const float* __restrict__ preT_f, const float* __restrict__ preT_b,
    const float* __restrict__ whh_f, const float* __restrict__ whh_b,
    const float* __restrict__ bih_f, const float* __restrict__ bhh_f,
    const float* __restrict__ bih_b, const float* __restrict__ bhh_b,
    float* __restrict__ gcn, unsigned* __restrict__ hg)
{
  const int tid = threadIdx.x;
  const int dir = blockIdx.x / NCH;
  const int blk = blockIdx.x - dir * NCH;
  const int u0 = blk * 8;
  const int uc = min(8, HR - u0);
  const float* pre = dir ? preT_b : preT_f;
  const float* whh = dir ? whh_b : whh_f;
  const float* bih = dir ? bih_b : bih_f;
  const float* bhh = dir ? bhh_b : bhh_f;
  unsigned* hgd = hg + dir * 4800;              // + buf*9600

  __shared__ float4 h5[1200];                   // h[k][b] linear
  __shared__ float part[32 * 545 + 64];
  __shared__ float g_lds[512];
  float* h5f = reinterpret_cast<float*>(h5);

  const int kc = tid >> 3;
  const int rq = tid & 7;
  const int kl = (kc < 12) ? 10 : 9;
  const int k0 = kc * 9 + min(kc, 12);

  float wreg[4][10];
#pragma unroll
  for (int i = 0; i < 4; ++i) {
    int lr = rq * 4 + i;
    int gate = lr >> 3, unit = lr & 7;
    bool valid = unit < uc;
    int growc = gate * HR + u0 + min(unit, uc - 1);
#pragma unroll
    for (int kk = 0; kk < 10; ++kk) {
      int k = min(k0 + kk, 299);
      float wv = whh[(long)growc * HR + k];
      wreg[i][kk] = (valid && kk < kl) ? wv : 0.f;
    }
  }

  const int o0 = tid * 2;
  const int lr0 = o0 >> 4;
  const int b0 = o0 & 15;
  const int gate0 = lr0 >> 3, unit0 = lr0 & 7;
  const int grow0 = gate0 * HR + u0 + min(unit0, uc - 1);
  const float breg = bih[grow0] + bhh[grow0];
  const float* prebase = pre + (long)grow0 * 8192;

  const int au = tid >> 4, ab = tid & 15;
  float c_reg = 0.f;

  const int own_lo = u0 * 16, own_hi = (u0 + uc) * 16;

#pragma unroll 1
  for (int s = 0; s < L_; ++s) {
    const int tf = dir ? (L_ - 1 - s) : s;

    float p0 = prebase[tf * 16 + b0];
    float p1 = prebase[tf * 16 + b0 + 1];

    if (s > 0) {
      unsigned* srcb = hgd + (s & 1) * 9600;
      const unsigned tag = (unsigned)s;
      unsigned vals[19];
      int idxs[19];
#pragma unroll
      for (int j = 0; j < 19; ++j) {
        int idx = tid + j * 256;
        bool act = (idx < 4800) && (idx < own_lo || idx >= own_hi);
        idxs[j] = act ? idx : -1;
        vals[j] = act ? __hip_atomic_load(&srcb[idx], __ATOMIC_RELAXED, __HIP_MEMORY_SCOPE_AGENT)
                      : (tag << 16);
      }
      for (;;) {
        bool ok = true;
#pragma unroll
        for (int j = 0; j < 19; ++j)
          if ((vals[j] >> 16) != tag) ok = false;
        if (ok) break;
#pragma unroll
        for (int j = 0; j < 19; ++j)
          if ((vals[j] >> 16) != tag)
            vals[j] = __hip_atomic_load(&srcb[idxs[j]], __ATOMIC_RELAXED, __HIP_MEMORY_SCOPE_AGENT);
      }
#pragma unroll
      for (int j = 0; j < 19; ++j) {
        int idx = idxs[j];
        if (idx >= 0) {
          unsigned short hb = (unsigned short)(vals[j] & 0xffffu);
          bf16 hbf = *reinterpret_cast<bf16*>(&hb);
          h5f[idx] = __bfloat162float(hbf);
        }
      }
    }
    __syncthreads();

    if (s > 0) {
      float4 acc[4][4];
#pragma unroll
      for (int i = 0; i < 4; ++i)
#pragma unroll
        for (int q = 0; q < 4; ++q) acc[i][q] = make_float4(0.f, 0.f, 0.f, 0.f);
#pragma unroll
      for (int kk = 0; kk < 10; ++kk) {
        if (kk < kl) {
          int k = k0 + kk;
          float4 hb0 = h5[k * 4 + 0];
          float4 hb1 = h5[k * 4 + 1];
          float4 hb2 = h5[k * 4 + 2];
          float4 hb3 = h5[k * 4 + 3];
#pragma unroll
          for (int i = 0; i < 4; ++i) {
            float w = wreg[i][kk];
            acc[i][0].x = fmaf(w, hb0.x, acc[i][0].x); acc[i][0].y = fmaf(w, hb0.y, acc[i][0].y);
            acc[i][0].z = fmaf(w, hb0.z, acc[i][0].z); acc[i][0].w = fmaf(w, hb0.w, acc[i][0].w);
            acc[i][1].x = fmaf(w, hb1.x, acc[i][1].x); acc[i][1].y = fmaf(w, hb1.y, acc[i][1].y);
            acc[i][1].z = fmaf(w, hb1.z, acc[i][1].z); acc[i][1].w = fmaf(w, hb1.w, acc[i][1].w);
            acc[i][2].x = fmaf(w, hb2.x, acc[i][2].x); acc[i][2].y = fmaf(w, hb2.y, acc[i][2].y);
            acc[i][2].z = fmaf(w, hb2.z, acc[i][2].z); acc[i][2].w = fmaf(w, hb2.w, acc[i][2].w);
            acc[i][3].x = fmaf(w, hb3.x, acc[i][3].x); acc[i][3].y = fmaf(w, hb3.y, acc[i][3].y);
            acc[i][3].z = fmaf(w, hb3.z, acc[i][3].z); acc[i][3].w = fmaf(w, hb3.w, acc[i][3].w);
          }
        }
      }
#pragma unroll
      for (int i = 0; i < 4; ++i) {
        int lr = rq * 4 + i;
        float* pb = part + kc * 545 + lr * 17;
#pragma unroll
        for (int q = 0; q < 4; ++q) {
          pb[q * 4 + 0] = acc[i][q].x; pb[q * 4 + 1] = acc[i][q].y;
          pb[q * 4 + 2] = acc[i][q].z; pb[q * 4 + 3] = acc[i][q].w;
        }
      }
    }
    __syncthreads();

    float g0 = p0 + breg, g1 = p1 + breg;
    if (s > 0) {
      const float* pb = part + lr0 * 17 + b0;
#pragma unroll
      for (int q = 0; q < 32; ++q) { g0 += pb[q * 545]; g1 += pb[q * 545 + 1]; }
    }
    g_lds[o0] = g0; g_lds[o0 + 1] = g1;
    __syncthreads();

    if (tid < 128 && au < uc) {
      float gi = g_lds[(0 * 8 + au) * 16 + ab];
      float gf = g_lds[(1 * 8 + au) * 16 + ab];
      float gg = g_lds[(2 * 8 + au) * 16 + ab];
      float go = g_lds[(3 * 8 + au) * 16 + ab];
      float si = 1.f / (1.f + __expf(-gi));
      float sf = 1.f / (1.f + __expf(-gf));
      float so = 1.f / (1.f + __expf(-go));
      float tg = tanhf(gg);
      c_reg = sf * c_reg + si * tg;
      float h = so * tanhf(c_reg);
      h5f[(u0 + au) * 16 + ab] = h;
      bf16 hbf = __float2bfloat16(h);
      unsigned bits = *reinterpret_cast<unsigned short*>(&hbf);
      unsigned val = ((unsigned)(s + 1) << 16) | bits;
      __hip_atomic_store(&hgd[((s + 1) & 1) * 9600 + (u0 + au) * 16 + ab], val,
                         __ATOMIC_RELAXED, __HIP_MEMORY_SCOPE_AGENT);
      gcn[((long)ab * L_ + tf) * DM_ + dir * HR + u0 + au] = h;
    }
  }
}

// ---------------------------------------------------------------- small aspect kernels
__global__ void k_asplist(const float* __restrict__ asp_mask, int* __restrict__ apos, int* __restrict__ acnt)
{
  int b = threadIdx.x;
  if (b >= B_) return;
  int c = 0;
  for (int l = 0; l < L_; ++l)
    if (asp_mask[b * L_ + l] > 0.f) { if (c < MAXA) apos[b * MAXA + c] = l; ++c; }
  acnt[b] = (c < MAXA) ? c : MAXA;
}

__global__ void k_t0(const float* __restrict__ bd, const float* __restrict__ wm, float* __restrict__ t0)
{
  int i = blockIdx.x * 256 + threadIdx.x;
  if (i >= 8 * DK_) return;
  int h = i / DK_, e = i % DK_;
  float s = 0.f;
  for (int d = 0; d < DK_; ++d) s += bd[d] * wm[(h * DK_ + d) * DK_ + e];
  t0[i] = s;
}

__global__ void k_aspd(const float* __restrict__ gcn, const float* __restrict__ asp_mask,
                       const int* __restrict__ apos, const int* __restrict__ acnt,
                       const float* __restrict__ wd, const float* __restrict__ bd, float* __restrict__ aspd)
{
  int i = blockIdx.x * 256 + threadIdx.x;
  if (i >= B_ * MAXA * DK_) return;
  int d = i % DK_;
  int ba = i / DK_;
  int a = ba % MAXA, b = ba / MAXA;
  if (a >= acnt[b]) { aspd[i] = 0.f; return; }
  int p = apos[b * MAXA + a];
  float mv = asp_mask[b * L_ + p];
  const float* row = gcn + ((long)b * L_ + p) * DM_;
  float s = 0.f;
  for (int k = 0; k < DM_; ++k) s += row[k] * wd[d * DM_ + k];
  aspd[i] = s * mv + bd[d];
}

__global__ void k_tasp(const float* __restrict__ aspd, const int* __restrict__ acnt,
                       const float* __restrict__ wm, float* __restrict__ tasp)
{
  int i = blockIdx.x * 256 + threadIdx.x;
  if (i >= B_ * 8 * MAXA * DK_) return;
  int e = i % DK_;
  int t3 = i / DK_;
  int a = t3 % MAXA;
  int t4 = t3 / MAXA;
  int h = t4 % 8, b = t4 / 8;
  if (a >= acnt[b]) { tasp[i] = 0.f; return; }
  const float* ar = aspd + (b * MAXA + a) * DK_;
  float s = 0.f;
  for (int d = 0; d < DK_; ++d) s += ar[d] * wm[(h * DK_ + d) * DK_ + e];
  tasp[i] = s;
}

__global__ void k_avg(const float* __restrict__ k_lin, const float* __restrict__ t0,
                      const float* __restrict__ tasp, const int* __restrict__ acnt,
                      const float* __restrict__ bias_m, float* __restrict__ s0, float* __restrict__ avg)
{
  int i = blockIdx.x * 256 + threadIdx.x;
  if (i >= B_ * 8 * L_) return;
  int m = i % L_;
  int bh = i / L_;
  int h = bh % 8, b = bh / 8;
  const float* kr = k_lin + ((long)b * L_ + m) * DM_ + h * DK_;
  float bm = bias_m[0];
  const float* t0r = t0 + h * DK_;
  float d0 = 0.f;
  for (int e = 0; e < DK_; ++e) d0 += t0r[e] * kr[e];
  float sv = tanhf(d0 + bm);
  int cnt = acnt[b];
  float acc = (float)(L_ - cnt) * sv;
  for (int a = 0; a < cnt; ++a) {
    const float* tr = tasp + (((b * 8 + h) * MAXA) + a) * DK_;
    float dd = 0.f;
    for (int e = 0; e < DK_; ++e) dd += tr[e] * kr[e];
    acc += tanhf(dd + bm);
  }
  s0[i] = sv;
  avg[i] = acc * (1.f / (float)L_);
}

__global__ void k_bar(const float* __restrict__ s0, const float* __restrict__ avg,
                      float* __restrict__ s0bar, float* __restrict__ avbar)
{
  int i = blockIdx.x * 256 + threadIdx.x;
  if (i >= B_ * L_) return;
  int m = i % L_, b = i / L_;
  float sa = 0.f, aa = 0.f;
  for (int h = 0; h < 8; ++h) { sa += s0[(b * 8 + h) * L_ + m]; aa += avg[(b * 8 + h) * L_ + m]; }
  s0bar[i] = sa * 0.125f;
  avbar[i] = aa * 0.125f;
}

__global__ __launch_bounds__(256) void k_adjag(
    const float* __restrict__ asp_mask, const float* __restrict__ adjr,
    const float* __restrict__ s0bar, const float* __restrict__ avbar,
    float* __restrict__ adjag, float* __restrict__ denag)
{
  int bl = blockIdx.x;
  int b = bl >> 9, l = bl & 511;
  bool rA = asp_mask[b * L_ + l] > 0.f;
  float avl = avbar[b * L_ + l];
  float lsum = 0.f;
  for (int q = 0; q < 2; ++q) {
    int m = threadIdx.x + q * 256;
    bool cA = asp_mask[b * L_ + m] > 0.f;
    float asv;
    if (cA && (!rA || m > l)) asv = avl;
    else if (rA)              asv = avbar[b * L_ + m];
    else                      asv = s0bar[b * L_ + m];
    float r = (asv > 0.9f) ? 1.f : __expf(0.8f * adjr[((long)b * L_ + l) * L_ + m]);
    float v = r * asv;
    adjag[((long)b * L_ + l) * L_ + m] = v;
    lsum += v;
  }
  __shared__ float red[256];
  red[threadIdx.x] = lsum;
  __syncthreads();
  for (int st = 128; st > 0; st >>= 1) {
    if (threadIdx.x < st) red[threadIdx.x] += red[threadIdx.x + st];
    __syncthreads();
  }
  if (threadIdx.x == 0) denag[bl] = red[0] + 1.f;
}

// fused stats + head-mean softmax + diag/mask + denom; one block per (b,l)
__global__ __launch_bounds__(256) void k_adjs2(
    const bf16* __restrict__ sc, const int* __restrict__ tok,
    float* __restrict__ adjs, float* __restrict__ dens)
{
  int bl = blockIdx.x;
  int b = bl >> 9, l = bl & 511;
  int tid = threadIdx.x;
  __shared__ float srow[8][512];
  __shared__ float stats[16];    // mx[0..7], inv[8..15]
  __shared__ float red[256];

  int t0v = tok[b * L_ + tid], t1v = tok[b * L_ + tid + 256];
#pragma unroll
  for (int h = 0; h < 8; ++h) {
    const bf16* p = sc + ((long)((b * 8 + h) * L_) + l) * L_;
    float v0 = __bfloat162float(p[tid]);
    float v1 = __bfloat162float(p[tid + 256]);
    srow[h][tid]       = (t0v != 0) ? v0 : -1e9f;
    srow[h][tid + 256] = (t1v != 0) ? v1 : -1e9f;
  }
  __syncthreads();

  int wv = tid >> 6, lane = tid & 63;
#pragma unroll
  for (int hh = 0; hh < 2; ++hh) {
    int h = wv * 2 + hh;
    float vv[8];
#pragma unroll
    for (int i = 0; i < 8; ++i) vv[i] = srow[h][lane + i * 64];
    float m = vv[0];
#pragma unroll
    for (int i = 1; i < 8; ++i) m = fmaxf(m, vv[i]);
    for (int off = 32; off > 0; off >>= 1) m = fmaxf(m, __shfl_xor(m, off));
    float s = 0.f;
#pragma unroll
    for (int i = 0; i < 8; ++i) s += __expf(vv[i] - m);
    for (int off = 32; off > 0; off >>= 1) s += __shfl_xor(s, off);
    if (lane == 0) { stats[h] = m; stats[8 + h] = 1.f / s; }
  }
  __syncthreads();

  float acc0 = 0.f, acc1 = 0.f;
#pragma unroll
  for (int h = 0; h < 8; ++h) {
    float m = stats[h], inv = stats[8 + h];
    acc0 += __expf(srow[h][tid] - m) * inv;
    acc1 += __expf(srow[h][tid + 256] - m) * inv;
  }
  float rmask = (tok[b * L_ + l] != 0) ? 1.f : 0.f;
  float lsum = 0.f;
  {
    int m = tid;
    float v = acc0 * 0.125f;
    v = (m == l) ? 1.f : v;
    v *= rmask;
    adjs[(long)bl * L_ + m] = v;
    lsum += v;
  }
  {
    int m = tid + 256;
    float v = acc1 * 0.125f;
    v = (m == l) ? 1.f : v;
    v *= rmask;
    adjs[(long)bl * L_ + m] = v;
    lsum += v;
  }
  red[tid] = lsum;
  __syncthreads();
  for (int st = 128; st > 0; st >>= 1) {
    if (tid < st) red[tid] += red[tid + st];
    __syncthreads();
  }
  if (tid == 0) dens[bl] = red[0] + 1.f;
}

__global__ __launch_bounds__(256) void k_softmax(float* __restrict__ X)
{
  long row = blockIdx.x;
  float* p = X + row * L_;
  int tid = threadIdx.x;
  float a = p[tid], b = p[tid + 256];
  __shared__ float red[256];
  red[tid] = fmaxf(a, b);
  __syncthreads();
  for (int st = 128; st > 0; st >>= 1) {
    if (tid < st) red[tid] = fmaxf(red[tid], red[tid + st]);
    __syncthreads();
  }
  float mxv = red[0];
  __syncthreads();
  float ea = __expf(a - mxv), eb = __expf(b - mxv);
  red[tid] = ea + eb;
  __syncthreads();
  for (int st = 128; st > 0; st >>= 1) {
    if (tid < st) red[tid] += red[tid + st];
    __syncthreads();
  }
  float inv = 1.f / red[0];
  p[tid] = ea * inv;
  p[tid + 256] = eb * inv;
}

// ---------------------------------------------------------------- host side
static void gemm(hipStream_t st, bool nt,
                 const float* A, int lda, long sA1, long sA2,
                 const float* Bm, int ldb, long sB1, long sB2,
                 float* C, bf16* Cbf, int ldc, long sC1, long sC2,
                 const float* bias, long sBias, const float* rowdiv,
                 float alpha, int relu, int M, int N, int K, int nb1, int nb2)
{
  dim3 g((N + 127) / 128, (M + 127) / 128, nb1 * nb2);
  if (nt)
    k_mgemm<true><<<g, 256, 0, st>>>(A, lda, sA1, sA2, Bm, ldb, sB1, sB2, C, Cbf, ldc, sC1, sC2,
                                     bias, sBias, rowdiv, alpha, relu, M, N, K, nb2);
  else
    k_mgemm<false><<<g, 256, 0, st>>>(A, lda, sA1, sA2, Bm, ldb, sB1, sB2, C, Cbf, ldc, sC1, sC2,
                                      bias, sBias, rowdiv, alpha, relu, M, N, K, nb2);
}

extern "C" void kernel_launch(void* const* d_in, const int* in_sizes, int n_in,
                              void* d_out, int out_size, void* d_ws, size_t ws_size,
                              hipStream_t stream)
{
  const int*   tok     = (const int*)d_in[0];
  const int*   pos     = (const int*)d_in[1];
  const int*   post    = (const int*)d_in[2];
  const float* asp_mask= (const float*)d_in[3];
  const float* adjr    = (const float*)d_in[5];
  const float* emb_w   = (const float*)d_in[6];
  const float* pos_w   = (const float*)d_in[7];
  const float* post_w  = (const float*)d_in[8];
  const float* w_ih_f  = (const float*)d_in[9];
  const float* w_hh_f  = (const float*)d_in[10];
  const float* b_ih_f  = (const float*)d_in[11];
  const float* b_hh_f  = (const float*)d_in[12];
  const float* w_ih_b  = (const float*)d_in[13];
  const float* w_hh_b  = (const float*)d_in[14];
  const float* b_ih_b  = (const float*)d_in[15];
  const float* b_hh_b  = (const float*)d_in[16];
  const float* wq      = (const float*)d_in[17];
  const float* bq      = (const float*)d_in[18];
  const float* wk      = (const float*)d_in[19];
  const float* bk      = (const float*)d_in[20];
  const float* wd      = (const float*)d_in[21];
  const float* bd      = (const float*)d_in[22];
  const float* wm      = (const float*)d_in[23];
  const float* bias_m  = (const float*)d_in[24];
  const float* wa0     = (const float*)d_in[25];
  const float* ba0     = (const float*)d_in[26];
  const float* wa1     = (const float*)d_in[27];
  const float* ba1     = (const float*)d_in[28];
  const float* ws0     = (const float*)d_in[29];
  const float* bs0     = (const float*)d_in[30];
  const float* ws1     = (const float*)d_in[31];
  const float* bs1     = (const float*)d_in[32];
  const float* aff1    = (const float*)d_in[33];
  const float* aff2    = (const float*)d_in[34];
  float* out = (float*)d_out;
  float* W = (float*)d_ws;

  // ---- workspace layout (float units) ----
  size_t off = 0;
  auto alloc = [&](size_t n) { size_t o = off; off += (n + 63) & ~(size_t)63; return o; };
  size_t o_gcn   = alloc((size_t)8192 * DM_);
  size_t o_q     = alloc((size_t)8192 * DM_);
  size_t o_k     = alloc((size_t)8192 * DM_);
  size_t o_adjs  = alloc((size_t)B_ * L_ * L_);
  size_t o_adjag = alloc((size_t)B_ * L_ * L_);
  size_t o_denag = alloc(8192);
  size_t o_dens  = alloc(8192);
  size_t o_t0    = alloc(600);
  size_t o_apos  = alloc(B_ * MAXA);
  size_t o_acnt  = alloc(64);
  size_t o_aspd  = alloc(B_ * MAXA * DK_);
  size_t o_tasp  = alloc(B_ * 8 * MAXA * DK_);
  size_t o_s0    = alloc(B_ * 8 * L_);
  size_t o_avg   = alloc(B_ * 8 * L_);
  size_t o_s0bar = alloc(B_ * L_);
  size_t o_avbar = alloc(B_ * L_);
  size_t o_hg    = alloc(2 * 2 * 4800);  // u32 tagged-h
  size_t o_wqk   = alloc(720000);
  size_t o_bqk   = alloc(1200);
  size_t o_wih   = alloc(864000);
  size_t o_aff   = alloc(180000);
  size_t o_oag1  = alloc((size_t)8192 * 300);
  size_t o_os1   = alloc((size_t)8192 * 300);
  size_t o_big   = alloc(23134300);      // union region
  size_t o_embs = o_big;
  size_t o_pref = o_big + 2949120;
  size_t o_preb = o_pref + 9830400;
  size_t o_sc   = o_big;
  size_t o_tmp  = o_big;
  size_t o_gag  = o_big + 4915200;
  size_t o_gs   = o_gag + 2457600;
  size_t o_h1   = o_gs  + 2457600;      // h1b = o_h1 + 2457600
  size_t o_a1m  = o_h1  + 4915200;
  size_t o_a2m  = o_a1m + 4194304;

  if (ws_size < off * sizeof(float)) {
    (void)hipMemsetAsync(d_out, 0x7F, (size_t)out_size * sizeof(float), stream);
    return;
  }

  // 0) stage packed weights (wqk | bqk | wih | aff)
  k_stage<<<(1765200 + 255) / 256, 256, 0, stream>>>(
      wq, wk, bq, bk, w_ih_f, w_ih_b, aff1, aff2,
      W + o_wqk, W + o_bqk, W + o_wih, W + o_aff);

  // 1) embeddings -> [t*16+b][360]
  k_embed<<<(L_ * B_ * 360 + 255) / 256, 256, 0, stream>>>(tok, pos, post, emb_w, pos_w, post_w, W + o_embs);

  // 2) pre-GEMMs batched (z=2): preT[j][t*16+b] = w_ih[j] . embs
  gemm(stream, true, W + o_wih, 360, 432000, 0, W + o_embs, 360, 0, 0,
       W + o_pref, nullptr, 8192, 9830400, 0, nullptr, 0, nullptr, 1.f, 0, 1200, 8192, 360, 2, 1);

  // 3) BiLSTM: 76 sharded blocks, tagged-word sync
  k_lstm<<<2 * NCH, 256, 0, stream>>>(W + o_pref, W + o_preb, w_hh_f, w_hh_b,
                                      b_ih_f, b_hh_f, b_ih_b, b_hh_b,
                                      W + o_gcn, (unsigned*)(W + o_hg));

  // 4) q/k batched (z=2)
  gemm(stream, true, W + o_gcn, DM_, 0, 0, W + o_wqk, DM_, 360000, 0,
       W + o_q, nullptr, DM_, (long)(o_k - o_q), 0, W + o_bqk, 600, nullptr,
       1.f, 0, 8192, DM_, DM_, 2, 1);

  // 5) aspect structure
  k_asplist<<<1, 64, 0, stream>>>(asp_mask, (int*)(W + o_apos), (int*)(W + o_acnt));
  k_t0<<<(600 + 255) / 256, 256, 0, stream>>>(bd, wm, W + o_t0);
  k_aspd<<<(B_ * MAXA * DK_ + 255) / 256, 256, 0, stream>>>(W + o_gcn, asp_mask,
      (const int*)(W + o_apos), (const int*)(W + o_acnt), wd, bd, W + o_aspd);
  k_tasp<<<(B_ * 8 * MAXA * DK_ + 255) / 256, 256, 0, stream>>>(W + o_aspd,
      (const int*)(W + o_acnt), wm, W + o_tasp);
  k_avg<<<(B_ * 8 * L_ + 255) / 256, 256, 0, stream>>>(W + o_k, W + o_t0, W + o_tasp,
      (const int*)(W + o_acnt), bias_m, W + o_s0, W + o_avg);
  k_bar<<<(B_ * L_ + 255) / 256, 256, 0, stream>>>(W + o_s0, W + o_avg, W + o_s0bar, W + o_avbar);

  // 6) scores (bf16) -> fused adj_s ; adj_ag
  gemm(stream, true, W + o_q, DM_, (long)L_ * DM_, DK_, W + o_k, DM_, (long)L_ * DM_, DK_,
       nullptr, (bf16*)(W + o_sc), L_, (long)8 * L_ * L_, (long)L_ * L_,
       nullptr, 0, nullptr, 0.1154700538f, 0, L_, L_, DK_, B_, 8);
  k_adjs2<<<B_ * L_, 256, 0, stream>>>((const bf16*)(W + o_sc), tok, W + o_adjs, W + o_dens);
  k_adjag<<<B_ * L_, 256, 0, stream>>>(asp_mask, adjr, W + o_s0bar, W + o_avbar,
                                       W + o_adjag, W + o_denag);

  // 7) two GCN layers
  const float* waL[2] = {wa0, wa1};
  const float* baL[2] = {ba0, ba1};
  const float* wsL[2] = {ws0, ws1};
  const float* bsL[2] = {bs0, bs1};
  const float* inAg = W + o_gcn;
  const float* inS  = W + o_gcn;
  int D = DM_;
  for (int layer = 0; layer < 2; ++layer) {
    gemm(stream, false, W + o_adjag, L_, (long)L_ * L_, 0, inAg, D, (long)L_ * D, 0,
         W + o_tmp, nullptr, D, (long)L_ * D, 0, nullptr, 0, nullptr, 1.f, 0, L_, D, L_, B_, 1);
    gemm(stream, true, W + o_tmp, D, 0, 0, waL[layer], D, 0, 0,
         W + o_gag, nullptr, 300, 0, 0, baL[layer], 0, W + o_denag, 1.f, 1, 8192, 300, D, 1, 1);
    gemm(stream, false, W + o_adjs, L_, (long)L_ * L_, 0, inS, D, (long)L_ * D, 0,
         W + o_tmp, nullptr, D, (long)L_ * D, 0, nullptr, 0, nullptr, 1.f, 0, L_, D, L_, B_, 1);
    gemm(stream, true, W + o_tmp, D, 0, 0, wsL[layer], D, 0, 0,
         W + o_gs, nullptr, 300, 0, 0, bsL[layer], 0, W + o_dens, 1.f, 1, 8192, 300, D, 1, 1);
    // affine batched (z=2): h1 = gag@aff1 ; h1b = gs@aff2
    gemm(stream, false, W + o_gag, 300, (long)(o_gs - o_gag), 0, W + o_aff, 300, 90000, 0,
         W + o_h1, nullptr, 300, 2457600, 0, nullptr, 0, nullptr, 1.f, 0, 8192, 300, 300, 2, 1);
    // A1/A2 batched (z=2x16): a1m = h1 @ gs^T ; a2m = h1b @ gag^T
    gemm(stream, true, W + o_h1, 300, 2457600, (long)L_ * 300,
         W + o_gs, 300, (long)o_gag - (long)o_gs, (long)L_ * 300,
         W + o_a1m, nullptr, L_, 4194304, (long)L_ * L_,
         nullptr, 0, nullptr, 1.f, 0, L_, L_, 300, 2, B_);
    k_softmax<<<2 * B_ * L_, 256, 0, stream>>>(W + o_a1m);
    // out batched (z=2x16): out_ag = A1 @ gs ; out_s = A2 @ gag
    float* dstC; int ldcO; long sC1o, sC2o;
    if (layer == 0) { dstC = W + o_oag1; ldcO = 300; sC1o = (long)(o_os1 - o_oag1); sC2o = (long)L_ * 300; }
    else            { dstC = out;        ldcO = 600; sC1o = 300;                    sC2o = (long)L_ * 600; }
    gemm(stream, false, W + o_a1m, L_, 4194304, (long)L_ * L_,
         W + o_gs, 300, (long)o_gag - (long)o_gs, (long)L_ * 300,
         dstC, nullptr, ldcO, sC1o, sC2o,
         nullptr, 0, nullptr, 1.f, 0, L_, 300, L_, 2, B_);
    inAg = W + o_oag1;
    inS  = W + o_os1;
    D = 300;
  }
}

// Round 11
// 3134.282 us; speedup vs baseline: 1.1689x; 1.1689x over previous
//
#include <hip/hip_runtime.h>
#include <hip/hip_bf16.h>

typedef __hip_bfloat16 bf16;
typedef __attribute__((ext_vector_type(4))) short short4v;
typedef __attribute__((ext_vector_type(8))) short short8v;
typedef __attribute__((ext_vector_type(4))) float f32x4;
typedef unsigned long long u64;

#define B_   16
#define L_   512
#define HR   300
#define DM_  600
#define DK_  75
#define MAXA 8
#define NCH  38            // u-chunks per dir (37*8 + 4)

// ---------------------------------------------------------------- embed
// embs layout: [seq = t*16 + b][360]
__global__ __launch_bounds__(256) void k_embed(
    const int* __restrict__ tok, const int* __restrict__ pos, const int* __restrict__ post,
    const float* __restrict__ emb_w, const float* __restrict__ pos_w, const float* __restrict__ post_w,
    float* __restrict__ embs)
{
  int idx = blockIdx.x * 256 + threadIdx.x;
  if (idx >= L_ * B_ * 360) return;
  int d = idx % 360;
  int seq = idx / 360;
  int b = seq & 15, t = seq >> 4;
  int si = b * L_ + t;
  float v;
  if (d < 300)       v = emb_w[(long)tok[si] * 300 + d];
  else if (d < 330)  v = pos_w[pos[si] * 30 + (d - 300)];
  else               v = post_w[post[si] * 30 + (d - 330)];
  embs[idx] = v;
}

// ---------------------------------------------------------------- weight staging (one launch)
// dst layout: wqk[720000] | bqk[1200] | wih[864000] | aff[180000]
__global__ __launch_bounds__(256) void k_stage(
    const float* __restrict__ wq, const float* __restrict__ wk,
    const float* __restrict__ bq, const float* __restrict__ bk,
    const float* __restrict__ wihf, const float* __restrict__ wihb,
    const float* __restrict__ aff1, const float* __restrict__ aff2,
    float* __restrict__ wqk, float* __restrict__ bqk,
    float* __restrict__ wih, float* __restrict__ aff)
{
  int i = blockIdx.x * 256 + threadIdx.x;
  if (i < 360000) wqk[i] = wq[i];
  else if (i < 720000) wqk[i] = wk[i - 360000];
  else if (i < 720600) bqk[i - 720000] = bq[i - 720000];
  else if (i < 721200) bqk[i - 720000] = bk[i - 720600];
  else if (i < 1153200) wih[i - 721200] = wihf[i - 721200];
  else if (i < 1585200) wih[i - 721200] = wihb[i - 1153200];
  else if (i < 1675200) aff[i - 1585200] = aff1[i - 1585200];
  else if (i < 1765200) aff[i - 1585200] = aff2[i - 1675200];
}

// ---------------------------------------------------------------- MFMA GEMM (bf16x3 split), 128x64 tile
__device__ inline short2 splitf(float x) {
  bf16 h = __float2bfloat16(x);
  float r = x - __bfloat162float(h);
  bf16 l2 = __float2bfloat16(r);
  short2 out;
  out.x = *reinterpret_cast<short*>(&h);
  out.y = *reinterpret_cast<short*>(&l2);
  return out;
}

__device__ inline short8v ld_frag(const short* p) {
  short4v a = *reinterpret_cast<const short4v*>(p);
  short4v b = *reinterpret_cast<const short4v*>(p + 16);
  short8v r;
  r[0]=a[0]; r[1]=a[1]; r[2]=a[2]; r[3]=a[3];
  r[4]=b[0]; r[5]=b[1]; r[6]=b[2]; r[7]=b[3];
  return r;
}

#define LDA_ 36   // row stride in shorts (32 + 4 pad)

template<bool NT>
__global__ __launch_bounds__(256) void k_mgemm(
    const float* __restrict__ A, int lda, long sA1, long sA2,
    const float* __restrict__ Bm, int ldb, long sB1, long sB2,
    float* __restrict__ C, bf16* __restrict__ Cbf, int ldc, long sC1, long sC2,
    const float* __restrict__ bias, long sBias,
    const float* __restrict__ rowdiv,
    float alpha, int relu, int M, int N, int K, int nb2)
{
  __shared__ short Ah[128 * LDA_], Al[128 * LDA_], Bh[64 * LDA_], Bl[64 * LDA_];
  const int tid = threadIdx.x;
  const int w = tid >> 6, l = tid & 63;
  const int z = blockIdx.z;
  const int b1 = z / nb2, b2 = z - b1 * nb2;
  const float* Ab = A + b1 * sA1 + b2 * sA2;
  const float* Bb = Bm + b1 * sB1 + b2 * sB2;
  const int row0 = blockIdx.y * 128, col0 = blockIdx.x * 64;

  f32x4 acc[2][4];
#pragma unroll
  for (int f = 0; f < 2; ++f)
#pragma unroll
    for (int c = 0; c < 4; ++c) acc[f][c] = (f32x4){0.f, 0.f, 0.f, 0.f};

  const int lrow = l & 15, lk = (l >> 4) * 4;

  for (int k0 = 0; k0 < K; k0 += 32) {
    // ---- stage A: 128 rows x 32 k (1024 float4-slots) ----
#pragma unroll
    for (int j = 0; j < 4; ++j) {
      int slot = j * 256 + tid;
      int r = slot >> 3, kq = slot & 7;
      int gr = row0 + r, gk = k0 + kq * 4;
      float v[4] = {0.f, 0.f, 0.f, 0.f};
      if (gr < M) {
        if (gk + 3 < K) {
          float4 t = *reinterpret_cast<const float4*>(Ab + (long)gr * lda + gk);
          v[0] = t.x; v[1] = t.y; v[2] = t.z; v[3] = t.w;
        } else {
#pragma unroll
          for (int q = 0; q < 4; ++q) if (gk + q < K) v[q] = Ab[(long)gr * lda + gk + q];
        }
      }
      short4v hv, lv;
#pragma unroll
      for (int q = 0; q < 4; ++q) {
        short2 t2 = splitf(v[q]);
        hv[q] = t2.x; lv[q] = t2.y;
      }
      *reinterpret_cast<short4v*>(&Ah[r * LDA_ + kq * 4]) = hv;
      *reinterpret_cast<short4v*>(&Al[r * LDA_ + kq * 4]) = lv;
    }
    // ---- stage B: 64 x 32 ----
    if (NT) {
#pragma unroll
      for (int j = 0; j < 2; ++j) {
        int slot = j * 256 + tid;
        int r = slot >> 3, kq = slot & 7;
        int gc = col0 + r, gk = k0 + kq * 4;
        float v[4] = {0.f, 0.f, 0.f, 0.f};
        if (gc < N) {
          if (gk + 3 < K) {
            float4 t = *reinterpret_cast<const float4*>(Bb + (long)gc * ldb + gk);
            v[0] = t.x; v[1] = t.y; v[2] = t.z; v[3] = t.w;
          } else {
#pragma unroll
            for (int q = 0; q < 4; ++q) if (gk + q < K) v[q] = Bb[(long)gc * ldb + gk + q];
          }
        }
        short4v hv, lv;
#pragma unroll
        for (int q = 0; q < 4; ++q) {
          short2 t2 = splitf(v[q]);
          hv[q] = t2.x; lv[q] = t2.y;
        }
        *reinterpret_cast<short4v*>(&Bh[r * LDA_ + kq * 4]) = hv;
        *reinterpret_cast<short4v*>(&Bl[r * LDA_ + kq * 4]) = lv;
      }
    } else {
#pragma unroll
      for (int j = 0; j < 2; ++j) {
        int slot = j * 256 + tid;
        int kk = slot >> 4, nq = slot & 15;
        int gk = k0 + kk, gn = col0 + nq * 4;
        float v[4] = {0.f, 0.f, 0.f, 0.f};
        if (gk < K) {
          if (gn + 3 < N) {
            float4 t = *reinterpret_cast<const float4*>(Bb + (long)gk * ldb + gn);
            v[0] = t.x; v[1] = t.y; v[2] = t.z; v[3] = t.w;
          } else {
#pragma unroll
            for (int q = 0; q < 4; ++q) if (gn + q < N) v[q] = Bb[(long)gk * ldb + gn + q];
          }
        }
#pragma unroll
        for (int q = 0; q < 4; ++q) {
          short2 t2 = splitf(v[q]);
          Bh[(nq * 4 + q) * LDA_ + kk] = t2.x;
          Bl[(nq * 4 + q) * LDA_ + kk] = t2.y;
        }
      }
    }
    __syncthreads();

    // ---- compute: wave w owns rows w*32..w*32+31 (2 frags) ----
    short8v ah[2], al[2];
#pragma unroll
    for (int f = 0; f < 2; ++f) {
      int ar = w * 32 + f * 16 + lrow;
      ah[f] = ld_frag(&Ah[ar * LDA_ + lk]);
      al[f] = ld_frag(&Al[ar * LDA_ + lk]);
    }
#pragma unroll
    for (int c = 0; c < 4; ++c) {
      short8v bh = ld_frag(&Bh[(c * 16 + lrow) * LDA_ + lk]);
      short8v bl = ld_frag(&Bl[(c * 16 + lrow) * LDA_ + lk]);
#pragma unroll
      for (int f = 0; f < 2; ++f) {
        acc[f][c] = __builtin_amdgcn_mfma_f32_16x16x32_bf16(ah[f], bh, acc[f][c], 0, 0, 0);
        acc[f][c] = __builtin_amdgcn_mfma_f32_16x16x32_bf16(ah[f], bl, acc[f][c], 0, 0, 0);
        acc[f][c] = __builtin_amdgcn_mfma_f32_16x16x32_bf16(al[f], bh, acc[f][c], 0, 0, 0);
      }
    }
    __syncthreads();
  }

  float* Cb = C ? C + b1 * sC1 + b2 * sC2 : (float*)0;
  bf16*  Cf = Cbf ? Cbf + b1 * sC1 + b2 * sC2 : (bf16*)0;
#pragma unroll
  for (int f = 0; f < 2; ++f)
#pragma unroll
  for (int c = 0; c < 4; ++c) {
    int cc = col0 + c * 16 + lrow;
    if (cc >= N) continue;
#pragma unroll
    for (int reg = 0; reg < 4; ++reg) {
      int r = row0 + w * 32 + f * 16 + (l >> 4) * 4 + reg;
      if (r >= M) continue;
      float v = acc[f][c][reg] * alpha;
      if (bias) v += bias[b1 * sBias + cc];
      if (rowdiv) v /= rowdiv[(long)z * M + r];
      if (relu) v = fmaxf(v, 0.f);
      if (Cf) Cf[(long)r * ldc + cc] = __float2bfloat16(v);
      else    Cb[(long)r * ldc + cc] = v;
    }
  }
}

// ---------------------------------------------------------------- BiLSTM (u64 tagged-word sync)
// Exchange word: u64 = (step_tag<<32) | bf16(h_odd)<<16 | bf16(h_even) for a
// (unit, batch-pair). 2400 words per dir per buffer. Halves store count and
// poll working set vs u32 scheme. Still zero fences, one one-way trip/step.
__global__ __launch_bounds__(256, 1) void k_lstm(
    const float* __restrict__ preT_f, const float* __restrict__ preT_b,
    const float* __restrict__ whh_f, const float* __restrict__ whh_b,
    const float* __restrict__ bih_f, const float* __restrict__ bhh_f,
    const float* __restrict__ bih_b, const float* __restrict__ bhh_b,
    float* __restrict__ gcn, u64* __restrict__ hg)
{
  const int tid = threadIdx.x;
  const int dir = blockIdx.x / NCH;
  const int blk = blockIdx.x - dir * NCH;
  const int u0 = blk * 8;
  const int uc = min(8, HR - u0);
  const float* pre = dir ? preT_b : preT_f;
  const float* whh = dir ? whh_b : whh_f;
  const float* bih = dir ? bih_b : bih_f;
  const float* bhh = dir ? bhh_b : bhh_f;
  u64* hgd = hg + dir * 2400;                   // + buf*4800

  __shared__ float4 h5[1200];                   // h[k][b] linear
  __shared__ float part[32 * 545 + 64];
  __shared__ float g_lds[512];
  float* h5f = reinterpret_cast<float*>(h5);

  const int kc = tid >> 3;
  const int rq = tid & 7;
  const int kl = (kc < 12) ? 10 : 9;
  const int k0 = kc * 9 + min(kc, 12);

  float wreg[4][10];
#pragma unroll
  for (int i = 0; i < 4; ++i) {
    int lr = rq * 4 + i;
    int gate = lr >> 3, unit = lr & 7;
    bool valid = unit < uc;
    int growc = gate * HR + u0 + min(unit, uc - 1);
#pragma unroll
    for (int kk = 0; kk < 10; ++kk) {
      int k = min(k0 + kk, 299);
      float wv = whh[(long)growc * HR + k];
      wreg[i][kk] = (valid && kk < kl) ? wv : 0.f;
    }
  }

  const int o0 = tid * 2;
  const int lr0 = o0 >> 4;
  const int b0 = o0 & 15;
  const int gate0 = lr0 >> 3, unit0 = lr0 & 7;
  const int grow0 = gate0 * HR + u0 + min(unit0, uc - 1);
  const float breg = bih[grow0] + bhh[grow0];
  const float* prebase = pre + (long)grow0 * 8192;

  // activation role: tid<64, unit au = tid>>3, batch pair bp = tid&7
  const int au = tid >> 3, abp = tid & 7;
  float c_reg0 = 0.f, c_reg1 = 0.f;

  const int own_lo = u0 * 8, own_hi = (u0 + uc) * 8;   // u64-index space

#pragma unroll 1
  for (int s = 0; s < L_; ++s) {
    const int tf = dir ? (L_ - 1 - s) : s;

    float p0 = prebase[tf * 16 + b0];
    float p1 = prebase[tf * 16 + b0 + 1];

    if (s > 0) {
      u64* srcb = hgd + (s & 1) * 4800;
      const u64 tag = (u64)s;
      u64 vals[10];
      int idxs[10];
#pragma unroll
      for (int j = 0; j < 10; ++j) {
        int idx = tid + j * 256;
        bool act = (idx < 2400) && (idx < own_lo || idx >= own_hi);
        idxs[j] = act ? idx : -1;
        vals[j] = act ? __hip_atomic_load(&srcb[idx], __ATOMIC_RELAXED, __HIP_MEMORY_SCOPE_AGENT)
                      : (tag << 32);
      }
      for (;;) {
        bool ok = true;
#pragma unroll
        for (int j = 0; j < 10; ++j)
          if ((vals[j] >> 32) != tag) ok = false;
        if (ok) break;
#pragma unroll
        for (int j = 0; j < 10; ++j)
          if ((vals[j] >> 32) != tag)
            vals[j] = __hip_atomic_load(&srcb[idxs[j]], __ATOMIC_RELAXED, __HIP_MEMORY_SCOPE_AGENT);
      }
#pragma unroll
      for (int j = 0; j < 10; ++j) {
        int idx = idxs[j];
        if (idx >= 0) {
          unsigned lo = (unsigned)(vals[j] & 0xffffffffu);
          unsigned short be = (unsigned short)(lo & 0xffffu);
          unsigned short bo = (unsigned short)(lo >> 16);
          bf16 he = *reinterpret_cast<bf16*>(&be);
          bf16 ho = *reinterpret_cast<bf16*>(&bo);
          int u = idx >> 3, bp = idx & 7;
          h5f[u * 16 + bp * 2]     = __bfloat162float(he);
          h5f[u * 16 + bp * 2 + 1] = __bfloat162float(ho);
        }
      }
    }
    __syncthreads();

    if (s > 0) {
      float4 acc[4][4];
#pragma unroll
      for (int i = 0; i < 4; ++i)
#pragma unroll
        for (int q = 0; q < 4; ++q) acc[i][q] = make_float4(0.f, 0.f, 0.f, 0.f);
#pragma unroll
      for (int kk = 0; kk < 10; ++kk) {
        if (kk < kl) {
          int k = k0 + kk;
          float4 hb0 = h5[k * 4 + 0];
          float4 hb1 = h5[k * 4 + 1];
          float4 hb2 = h5[k * 4 + 2];
          float4 hb3 = h5[k * 4 + 3];
#pragma unroll
          for (int i = 0; i < 4; ++i) {
            float w = wreg[i][kk];
            acc[i][0].x = fmaf(w, hb0.x, acc[i][0].x); acc[i][0].y = fmaf(w, hb0.y, acc[i][0].y);
            acc[i][0].z = fmaf(w, hb0.z, acc[i][0].z); acc[i][0].w = fmaf(w, hb0.w, acc[i][0].w);
            acc[i][1].x = fmaf(w, hb1.x, acc[i][1].x); acc[i][1].y = fmaf(w, hb1.y, acc[i][1].y);
            acc[i][1].z = fmaf(w, hb1.z, acc[i][1].z); acc[i][1].w = fmaf(w, hb1.w, acc[i][1].w);
            acc[i][2].x = fmaf(w, hb2.x, acc[i][2].x); acc[i][2].y = fmaf(w, hb2.y, acc[i][2].y);
            acc[i][2].z = fmaf(w, hb2.z, acc[i][2].z); acc[i][2].w = fmaf(w, hb2.w, acc[i][2].w);
            acc[i][3].x = fmaf(w, hb3.x, acc[i][3].x); acc[i][3].y = fmaf(w, hb3.y, acc[i][3].y);
            acc[i][3].z = fmaf(w, hb3.z, acc[i][3].z); acc[i][3].w = fmaf(w, hb3.w, acc[i][3].w);
          }
        }
      }
#pragma unroll
      for (int i = 0; i < 4; ++i) {
        int lr = rq * 4 + i;
        float* pb = part + kc * 545 + lr * 17;
#pragma unroll
        for (int q = 0; q < 4; ++q) {
          pb[q * 4 + 0] = acc[i][q].x; pb[q * 4 + 1] = acc[i][q].y;
          pb[q * 4 + 2] = acc[i][q].z; pb[q * 4 + 3] = acc[i][q].w;
        }
      }
    }
    __syncthreads();

    float g0 = p0 + breg, g1 = p1 + breg;
    if (s > 0) {
      const float* pb = part + lr0 * 17 + b0;
#pragma unroll
      for (int q = 0; q < 32; ++q) { g0 += pb[q * 545]; g1 += pb[q * 545 + 1]; }
    }
    g_lds[o0] = g0; g_lds[o0 + 1] = g1;
    __syncthreads();

    if (tid < 64 && au < uc) {
      int be = abp * 2, bo = abp * 2 + 1;
      float gi0 = g_lds[(0 * 8 + au) * 16 + be];
      float gf0 = g_lds[(1 * 8 + au) * 16 + be];
      float gg0 = g_lds[(2 * 8 + au) * 16 + be];
      float go0 = g_lds[(3 * 8 + au) * 16 + be];
      float gi1 = g_lds[(0 * 8 + au) * 16 + bo];
      float gf1 = g_lds[(1 * 8 + au) * 16 + bo];
      float gg1 = g_lds[(2 * 8 + au) * 16 + bo];
      float go1 = g_lds[(3 * 8 + au) * 16 + bo];
      float si0 = 1.f / (1.f + __expf(-gi0));
      float sf0 = 1.f / (1.f + __expf(-gf0));
      float so0 = 1.f / (1.f + __expf(-go0));
      float tg0 = tanhf(gg0);
      float si1 = 1.f / (1.f + __expf(-gi1));
      float sf1 = 1.f / (1.f + __expf(-gf1));
      float so1 = 1.f / (1.f + __expf(-go1));
      float tg1 = tanhf(gg1);
      c_reg0 = sf0 * c_reg0 + si0 * tg0;
      c_reg1 = sf1 * c_reg1 + si1 * tg1;
      float h0 = so0 * tanhf(c_reg0);
      float h1 = so1 * tanhf(c_reg1);
      h5f[(u0 + au) * 16 + be] = h0;
      h5f[(u0 + au) * 16 + bo] = h1;
      bf16 hbe = __float2bfloat16(h0);
      bf16 hbo = __float2bfloat16(h1);
      unsigned bitse = *reinterpret_cast<unsigned short*>(&hbe);
      unsigned bitso = *reinterpret_cast<unsigned short*>(&hbo);
      u64 val = ((u64)(s + 1) << 32) | ((u64)bitso << 16) | (u64)bitse;
      __hip_atomic_store(&hgd[((s + 1) & 1) * 4800 + (u0 + au) * 8 + abp], val,
                         __ATOMIC_RELAXED, __HIP_MEMORY_SCOPE_AGENT);
      gcn[((long)be * L_ + tf) * DM_ + dir * HR + u0 + au] = h0;
      gcn[((long)bo * L_ + tf) * DM_ + dir * HR + u0 + au] = h1;
    }
  }
}

// ---------------------------------------------------------------- small aspect kernels
__global__ void k_asplist(const float* __restrict__ asp_mask, int* __restrict__ apos, int* __restrict__ acnt)
{
  int b = threadIdx.x;
  if (b >= B_) return;
  int c = 0;
  for (int l = 0; l < L_; ++l)
    if (asp_mask[b * L_ + l] > 0.f) { if (c < MAXA) apos[b * MAXA + c] = l; ++c; }
  acnt[b] = (c < MAXA) ? c : MAXA;
}

__global__ void k_t0(const float* __restrict__ bd, const float* __restrict__ wm, float* __restrict__ t0)
{
  int i = blockIdx.x * 256 + threadIdx.x;
  if (i >= 8 * DK_) return;
  int h = i / DK_, e = i % DK_;
  float s = 0.f;
  for (int d = 0; d < DK_; ++d) s += bd[d] * wm[(h * DK_ + d) * DK_ + e];
  t0[i] = s;
}

__global__ void k_aspd(const float* __restrict__ gcn, const float* __restrict__ asp_mask,
                       const int* __restrict__ apos, const int* __restrict__ acnt,
                       const float* __restrict__ wd, const float* __restrict__ bd, float* __restrict__ aspd)
{
  int i = blockIdx.x * 256 + threadIdx.x;
  if (i >= B_ * MAXA * DK_) return;
  int d = i % DK_;
  int ba = i / DK_;
  int a = ba % MAXA, b = ba / MAXA;
  if (a >= acnt[b]) { aspd[i] = 0.f; return; }
  int p = apos[b * MAXA + a];
  float mv = asp_mask[b * L_ + p];
  const float* row = gcn + ((long)b * L_ + p) * DM_;
  float s = 0.f;
  for (int k = 0; k < DM_; ++k) s += row[k] * wd[d * DM_ + k];
  aspd[i] = s * mv + bd[d];
}

__global__ void k_tasp(const float* __restrict__ aspd, const int* __restrict__ acnt,
                       const float* __restrict__ wm, float* __restrict__ tasp)
{
  int i = blockIdx.x * 256 + threadIdx.x;
  if (i >= B_ * 8 * MAXA * DK_) return;
  int e = i % DK_;
  int t3 = i / DK_;
  int a = t3 % MAXA;
  int t4 = t3 / MAXA;
  int h = t4 % 8, b = t4 / 8;
  if (a >= acnt[b]) { tasp[i] = 0.f; return; }
  const float* ar = aspd + (b * MAXA + a) * DK_;
  float s = 0.f;
  for (int d = 0; d < DK_; ++d) s += ar[d] * wm[(h * DK_ + d) * DK_ + e];
  tasp[i] = s;
}

__global__ void k_avg(const float* __restrict__ k_lin, const float* __restrict__ t0,
                      const float* __restrict__ tasp, const int* __restrict__ acnt,
                      const float* __restrict__ bias_m, float* __restrict__ s0, float* __restrict__ avg)
{
  int i = blockIdx.x * 256 + threadIdx.x;
  if (i >= B_ * 8 * L_) return;
  int m = i % L_;
  int bh = i / L_;
  int h = bh % 8, b = bh / 8;
  const float* kr = k_lin + ((long)b * L_ + m) * DM_ + h * DK_;
  float bm = bias_m[0];
  const float* t0r = t0 + h * DK_;
  float d0 = 0.f;
  for (int e = 0; e < DK_; ++e) d0 += t0r[e] * kr[e];
  float sv = tanhf(d0 + bm);
  int cnt = acnt[b];
  float acc = (float)(L_ - cnt) * sv;
  for (int a = 0; a < cnt; ++a) {
    const float* tr = tasp + (((b * 8 + h) * MAXA) + a) * DK_;
    float dd = 0.f;
    for (int e = 0; e < DK_; ++e) dd += tr[e] * kr[e];
    acc += tanhf(dd + bm);
  }
  s0[i] = sv;
  avg[i] = acc * (1.f / (float)L_);
}

__global__ void k_bar(const float* __restrict__ s0, const float* __restrict__ avg,
                      float* __restrict__ s0bar, float* __restrict__ avbar)
{
  int i = blockIdx.x * 256 + threadIdx.x;
  if (i >= B_ * L_) return;
  int m = i % L_, b = i / L_;
  float sa = 0.f, aa = 0.f;
  for (int h = 0; h < 8; ++h) { sa += s0[(b * 8 + h) * L_ + m]; aa += avg[(b * 8 + h) * L_ + m]; }
  s0bar[i] = sa * 0.125f;
  avbar[i] = aa * 0.125f;
}

__global__ __launch_bounds__(256) void k_adjag(
    const float* __restrict__ asp_mask, const float* __restrict__ adjr,
    const float* __restrict__ s0bar, const float* __restrict__ avbar,
    float* __restrict__ adjag, float* __restrict__ denag)
{
  int bl = blockIdx.x;
  int b = bl >> 9, l = bl & 511;
  bool rA = asp_mask[b * L_ + l] > 0.f;
  float avl = avbar[b * L_ + l];
  float lsum = 0.f;
  for (int q = 0; q < 2; ++q) {
    int m = threadIdx.x + q * 256;
    bool cA = asp_mask[b * L_ + m] > 0.f;
    float asv;
    if (cA && (!rA || m > l)) asv = avl;
    else if (rA)              asv = avbar[b * L_ + m];
    else                      asv = s0bar[b * L_ + m];
    float r = (asv > 0.9f) ? 1.f : __expf(0.8f * adjr[((long)b * L_ + l) * L_ + m]);
    float v = r * asv;
    adjag[((long)b * L_ + l) * L_ + m] = v;
    lsum += v;
  }
  __shared__ float red[256];
  red[threadIdx.x] = lsum;
  __syncthreads();
  for (int st = 128; st > 0; st >>= 1) {
    if (threadIdx.x < st) red[threadIdx.x] += red[threadIdx.x + st];
    __syncthreads();
  }
  if (threadIdx.x == 0) denag[bl] = red[0] + 1.f;
}

// fused stats + head-mean softmax + diag/mask + denom; one block per (b,l)
__global__ __launch_bounds__(256) void k_adjs2(
    const bf16* __restrict__ sc, const int* __restrict__ tok,
    float* __restrict__ adjs, float* __restrict__ dens)
{
  int bl = blockIdx.x;
  int b = bl >> 9, l = bl & 511;
  int tid = threadIdx.x;
  __shared__ float srow[8][512];
  __shared__ float stats[16];    // mx[0..7], inv[8..15]
  __shared__ float red[256];

  int t0v = tok[b * L_ + tid], t1v = tok[b * L_ + tid + 256];
#pragma unroll
  for (int h = 0; h < 8; ++h) {
    const bf16* p = sc + ((long)((b * 8 + h) * L_) + l) * L_;
    float v0 = __bfloat162float(p[tid]);
    float v1 = __bfloat162float(p[tid + 256]);
    srow[h][tid]       = (t0v != 0) ? v0 : -1e9f;
    srow[h][tid + 256] = (t1v != 0) ? v1 : -1e9f;
  }
  __syncthreads();

  int wv = tid >> 6, lane = tid & 63;
#pragma unroll
  for (int hh = 0; hh < 2; ++hh) {
    int h = wv * 2 + hh;
    float vv[8];
#pragma unroll
    for (int i = 0; i < 8; ++i) vv[i] = srow[h][lane + i * 64];
    float m = vv[0];
#pragma unroll
    for (int i = 1; i < 8; ++i) m = fmaxf(m, vv[i]);
    for (int off = 32; off > 0; off >>= 1) m = fmaxf(m, __shfl_xor(m, off));
    float s = 0.f;
#pragma unroll
    for (int i = 0; i < 8; ++i) s += __expf(vv[i] - m);
    for (int off = 32; off > 0; off >>= 1) s += __shfl_xor(s, off);
    if (lane == 0) { stats[h] = m; stats[8 + h] = 1.f / s; }
  }
  __syncthreads();

  float acc0 = 0.f, acc1 = 0.f;
#pragma unroll
  for (int h = 0; h < 8; ++h) {
    float m = stats[h], inv = stats[8 + h];
    acc0 += __expf(srow[h][tid] - m) * inv;
    acc1 += __expf(srow[h][tid + 256] - m) * inv;
  }
  float rmask = (tok[b * L_ + l] != 0) ? 1.f : 0.f;
  float lsum = 0.f;
  {
    int m = tid;
    float v = acc0 * 0.125f;
    v = (m == l) ? 1.f : v;
    v *= rmask;
    adjs[(long)bl * L_ + m] = v;
    lsum += v;
  }
  {
    int m = tid + 256;
    float v = acc1 * 0.125f;
    v = (m == l) ? 1.f : v;
    v *= rmask;
    adjs[(long)bl * L_ + m] = v;
    lsum += v;
  }
  red[tid] = lsum;
  __syncthreads();
  for (int st = 128; st > 0; st >>= 1) {
    if (tid < st) red[tid] += red[tid + st];
    __syncthreads();
  }
  if (tid == 0) dens[bl] = red[0] + 1.f;
}

__global__ __launch_bounds__(256) void k_softmax(float* __restrict__ X)
{
  long row = blockIdx.x;
  float* p = X + row * L_;
  int tid = threadIdx.x;
  float a = p[tid], b = p[tid + 256];
  __shared__ float red[256];
  red[tid] = fmaxf(a, b);
  __syncthreads();
  for (int st = 128; st > 0; st >>= 1) {
    if (tid < st) red[tid] = fmaxf(red[tid], red[tid + st]);
    __syncthreads();
  }
  float mxv = red[0];
  __syncthreads();
  float ea = __expf(a - mxv), eb = __expf(b - mxv);
  red[tid] = ea + eb;
  __syncthreads();
  for (int st = 128; st > 0; st >>= 1) {
    if (tid < st) red[tid] += red[tid + st];
    __syncthreads();
  }
  float inv = 1.f / red[0];
  p[tid] = ea * inv;
  p[tid + 256] = eb * inv;
}

// ---------------------------------------------------------------- host side
static void gemm(hipStream_t st, bool nt,
                 const float* A, int lda, long sA1, long sA2,
                 const float* Bm, int ldb, long sB1, long sB2,
                 float* C, bf16* Cbf, int ldc, long sC1, long sC2,
                 const float* bias, long sBias, const float* rowdiv,
                 float alpha, int relu, int M, int N, int K, int nb1, int nb2)
{
  dim3 g((N + 63) / 64, (M + 127) / 128, nb1 * nb2);
  if (nt)
    k_mgemm<true><<<g, 256, 0, st>>>(A, lda, sA1, sA2, Bm, ldb, sB1, sB2, C, Cbf, ldc, sC1, sC2,
                                     bias, sBias, rowdiv, alpha, relu, M, N, K, nb2);
  else
    k_mgemm<false><<<g, 256, 0, st>>>(A, lda, sA1, sA2, Bm, ldb, sB1, sB2, C, Cbf, ldc, sC1, sC2,
                                      bias, sBias, rowdiv, alpha, relu, M, N, K, nb2);
}

extern "C" void kernel_launch(void* const* d_in, const int* in_sizes, int n_in,
                              void* d_out, int out_size, void* d_ws, size_t ws_size,
                              hipStream_t stream)
{
  const int*   tok     = (const int*)d_in[0];
  const int*   pos     = (const int*)d_in[1];
  const int*   post    = (const int*)d_in[2];
  const float* asp_mask= (const float*)d_in[3];
  const float* adjr    = (const float*)d_in[5];
  const float* emb_w   = (const float*)d_in[6];
  const float* pos_w   = (const float*)d_in[7];
  const float* post_w  = (const float*)d_in[8];
  const float* w_ih_f  = (const float*)d_in[9];
  const float* w_hh_f  = (const float*)d_in[10];
  const float* b_ih_f  = (const float*)d_in[11];
  const float* b_hh_f  = (const float*)d_in[12];
  const float* w_ih_b  = (const float*)d_in[13];
  const float* w_hh_b  = (const float*)d_in[14];
  const float* b_ih_b  = (const float*)d_in[15];
  const float* b_hh_b  = (const float*)d_in[16];
  const float* wq      = (const float*)d_in[17];
  const float* bq      = (const float*)d_in[18];
  const float* wk      = (const float*)d_in[19];
  const float* bk      = (const float*)d_in[20];
  const float* wd      = (const float*)d_in[21];
  const float* bd      = (const float*)d_in[22];
  const float* wm      = (const float*)d_in[23];
  const float* bias_m  = (const float*)d_in[24];
  const float* wa0     = (const float*)d_in[25];
  const float* ba0     = (const float*)d_in[26];
  const float* wa1     = (const float*)d_in[27];
  const float* ba1     = (const float*)d_in[28];
  const float* ws0     = (const float*)d_in[29];
  const float* bs0     = (const float*)d_in[30];
  const float* ws1     = (const float*)d_in[31];
  const float* bs1     = (const float*)d_in[32];
  const float* aff1    = (const float*)d_in[33];
  const float* aff2    = (const float*)d_in[34];
  float* out = (float*)d_out;
  float* W = (float*)d_ws;

  // ---- workspace layout (float units) ----
  size_t off = 0;
  auto alloc = [&](size_t n) { size_t o = off; off += (n + 63) & ~(size_t)63; return o; };
  size_t o_gcn   = alloc((size_t)8192 * DM_);
  size_t o_q     = alloc((size_t)8192 * DM_);
  size_t o_k     = alloc((size_t)8192 * DM_);
  size_t o_adjs  = alloc((size_t)B_ * L_ * L_);
  size_t o_adjag = alloc((size_t)B_ * L_ * L_);
  size_t o_denag = alloc(8192);
  size_t o_dens  = alloc(8192);
  size_t o_t0    = alloc(600);
  size_t o_apos  = alloc(B_ * MAXA);
  size_t o_acnt  = alloc(64);
  size_t o_aspd  = alloc(B_ * MAXA * DK_);
  size_t o_tasp  = alloc(B_ * 8 * MAXA * DK_);
  size_t o_s0    = alloc(B_ * 8 * L_);
  size_t o_avg   = alloc(B_ * 8 * L_);
  size_t o_s0bar = alloc(B_ * L_);
  size_t o_avbar = alloc(B_ * L_);
  size_t o_hg    = alloc(2 * 2 * 4800);  // u64 tagged-h pairs (2 buf x 2 dir x 2400 u64 = 19200 floats)
  size_t o_wqk   = alloc(720000);
  size_t o_bqk   = alloc(1200);
  size_t o_wih   = alloc(864000);
  size_t o_aff   = alloc(180000);
  size_t o_oag1  = alloc((size_t)8192 * 300);
  size_t o_os1   = alloc((size_t)8192 * 300);
  size_t o_big   = alloc(23134300);      // union region
  size_t o_embs = o_big;
  size_t o_pref = o_big + 2949120;
  size_t o_preb = o_pref + 9830400;
  size_t o_sc   = o_big;
  size_t o_tmp  = o_big;
  size_t o_gag  = o_big + 4915200;
  size_t o_gs   = o_gag + 2457600;
  size_t o_h1   = o_gs  + 2457600;      // h1b = o_h1 + 2457600
  size_t o_a1m  = o_h1  + 4915200;
  size_t o_a2m  = o_a1m + 4194304;

  if (ws_size < off * sizeof(float)) {
    (void)hipMemsetAsync(d_out, 0x7F, (size_t)out_size * sizeof(float), stream);
    return;
  }

  // 0) stage packed weights (wqk | bqk | wih | aff)
  k_stage<<<(1765200 + 255) / 256, 256, 0, stream>>>(
      wq, wk, bq, bk, w_ih_f, w_ih_b, aff1, aff2,
      W + o_wqk, W + o_bqk, W + o_wih, W + o_aff);

  // 1) embeddings -> [t*16+b][360]
  k_embed<<<(L_ * B_ * 360 + 255) / 256, 256, 0, stream>>>(tok, pos, post, emb_w, pos_w, post_w, W + o_embs);

  // 2) pre-GEMMs batched (z=2): preT[j][t*16+b] = w_ih[j] . embs
  gemm(stream, true, W + o_wih, 360, 432000, 0, W + o_embs, 360, 0, 0,
       W + o_pref, nullptr, 8192, 9830400, 0, nullptr, 0, nullptr, 1.f, 0, 1200, 8192, 360, 2, 1);

  // 3) BiLSTM: 76 sharded blocks, u64 tagged-word sync
  k_lstm<<<2 * NCH, 256, 0, stream>>>(W + o_pref, W + o_preb, w_hh_f, w_hh_b,
                                      b_ih_f, b_hh_f, b_ih_b, b_hh_b,
                                      W + o_gcn, (u64*)(W + o_hg));

  // 4) q/k batched (z=2)
  gemm(stream, true, W + o_gcn, DM_, 0, 0, W + o_wqk, DM_, 360000, 0,
       W + o_q, nullptr, DM_, (long)(o_k - o_q), 0, W + o_bqk, 600, nullptr,
       1.f, 0, 8192, DM_, DM_, 2, 1);

  // 5) aspect structure
  k_asplist<<<1, 64, 0, stream>>>(asp_mask, (int*)(W + o_apos), (int*)(W + o_acnt));
  k_t0<<<(600 + 255) / 256, 256, 0, stream>>>(bd, wm, W + o_t0);
  k_aspd<<<(B_ * MAXA * DK_ + 255) / 256, 256, 0, stream>>>(W + o_gcn, asp_mask,
      (const int*)(W + o_apos), (const int*)(W + o_acnt), wd, bd, W + o_aspd);
  k_tasp<<<(B_ * 8 * MAXA * DK_ + 255) / 256, 256, 0, stream>>>(W + o_aspd,
      (const int*)(W + o_acnt), wm, W + o_tasp);
  k_avg<<<(B_ * 8 * L_ + 255) / 256, 256, 0, stream>>>(W + o_k, W + o_t0, W + o_tasp,
      (const int*)(W + o_acnt), bias_m, W + o_s0, W + o_avg);
  k_bar<<<(B_ * L_ + 255) / 256, 256, 0, stream>>>(W + o_s0, W + o_avg, W + o_s0bar, W + o_avbar);

  // 6) scores (bf16) -> fused adj_s ; adj_ag
  gemm(stream, true, W + o_q, DM_, (long)L_ * DM_, DK_, W + o_k, DM_, (long)L_ * DM_, DK_,
       nullptr, (bf16*)(W + o_sc), L_, (long)8 * L_ * L_, (long)L_ * L_,
       nullptr, 0, nullptr, 0.1154700538f, 0, L_, L_, DK_, B_, 8);
  k_adjs2<<<B_ * L_, 256, 0, stream>>>((const bf16*)(W + o_sc), tok, W + o_adjs, W + o_dens);
  k_adjag<<<B_ * L_, 256, 0, stream>>>(asp_mask, adjr, W + o_s0bar, W + o_avbar,
                                       W + o_adjag, W + o_denag);

  // 7) two GCN layers
  const float* waL[2] = {wa0, wa1};
  const float* baL[2] = {ba0, ba1};
  const float* wsL[2] = {ws0, ws1};
  const float* bsL[2] = {bs0, bs1};
  const float* inAg = W + o_gcn;
  const float* inS  = W + o_gcn;
  int D = DM_;
  for (int layer = 0; layer < 2; ++layer) {
    gemm(stream, false, W + o_adjag, L_, (long)L_ * L_, 0, inAg, D, (long)L_ * D, 0,
         W + o_tmp, nullptr, D, (long)L_ * D, 0, nullptr, 0, nullptr, 1.f, 0, L_, D, L_, B_, 1);
    gemm(stream, true, W + o_tmp, D, 0, 0, waL[layer], D, 0, 0,
         W + o_gag, nullptr, 300, 0, 0, baL[layer], 0, W + o_denag, 1.f, 1, 8192, 300, D, 1, 1);
    gemm(stream, false, W + o_adjs, L_, (long)L_ * L_, 0, inS, D, (long)L_ * D, 0,
         W + o_tmp, nullptr, D, (long)L_ * D, 0, nullptr, 0, nullptr, 1.f, 0, L_, D, L_, B_, 1);
    gemm(stream, true, W + o_tmp, D, 0, 0, wsL[layer], D, 0, 0,
         W + o_gs, nullptr, 300, 0, 0, bsL[layer], 0, W + o_dens, 1.f, 1, 8192, 300, D, 1, 1);
    // affine batched (z=2): h1 = gag@aff1 ; h1b = gs@aff2
    gemm(stream, false, W + o_gag, 300, (long)(o_gs - o_gag), 0, W + o_aff, 300, 90000, 0,
         W + o_h1, nullptr, 300, 2457600, 0, nullptr, 0, nullptr, 1.f, 0, 8192, 300, 300, 2, 1);
    // A1/A2 batched (z=2x16): a1m = h1 @ gs^T ; a2m = h1b @ gag^T
    gemm(stream, true, W + o_h1, 300, 2457600, (long)L_ * 300,
         W + o_gs, 300, (long)o_gag - (long)o_gs, (long)L_ * 300,
         W + o_a1m, nullptr, L_, 4194304, (long)L_ * L_,
         nullptr, 0, nullptr, 1.f, 0, L_, L_, 300, 2, B_);
    k_softmax<<<2 * B_ * L_, 256, 0, stream>>>(W + o_a1m);
    // out batched (z=2x16): out_ag = A1 @ gs ; out_s = A2 @ gag
    float* dstC; int ldcO; long sC1o, sC2o;
    if (layer == 0) { dstC = W + o_oag1; ldcO = 300; sC1o = (long)(o_os1 - o_oag1); sC2o = (long)L_ * 300; }
    else            { dstC = out;        ldcO = 600; sC1o = 300;                    sC2o = (long)L_ * 600; }
    gemm(stream, false, W + o_a1m, L_, 4194304, (long)L_ * L_,
         W + o_gs, 300, (long)o_gag - (long)o_gs, (long)L_ * 300,
         dstC, nullptr, ldcO, sC1o, sC2o,
         nullptr, 0, nullptr, 1.f, 0, L_, 300, L_, 2, B_);
    inAg = W + o_oag1;
    inS  = W + o_os1;
    D = 300;
  }
}

// Round 12
// 2946.086 us; speedup vs baseline: 1.2436x; 1.0639x over previous
//
#include <hip/hip_runtime.h>
#include <hip/hip_bf16.h>

typedef __hip_bfloat16 bf16;
typedef __attribute__((ext_vector_type(4))) short short4v;
typedef __attribute__((ext_vector_type(8))) short short8v;
typedef __attribute__((ext_vector_type(4))) float f32x4;
typedef unsigned long long u64;

#define B_   16
#define L_   512
#define HR   300
#define DM_  600
#define DK_  75
#define MAXA 8
#define NCH  38            // u-chunks per dir (37*8 + 4)

// ---------------------------------------------------------------- embed
// embs layout: [seq = t*16 + b][360]
__global__ __launch_bounds__(256) void k_embed(
    const int* __restrict__ tok, const int* __restrict__ pos, const int* __restrict__ post,
    const float* __restrict__ emb_w, const float* __restrict__ pos_w, const float* __restrict__ post_w,
    float* __restrict__ embs)
{
  int idx = blockIdx.x * 256 + threadIdx.x;
  if (idx >= L_ * B_ * 360) return;
  int d = idx % 360;
  int seq = idx / 360;
  int b = seq & 15, t = seq >> 4;
  int si = b * L_ + t;
  float v;
  if (d < 300)       v = emb_w[(long)tok[si] * 300 + d];
  else if (d < 330)  v = pos_w[pos[si] * 30 + (d - 300)];
  else               v = post_w[post[si] * 30 + (d - 330)];
  embs[idx] = v;
}

// ---------------------------------------------------------------- weight staging (one launch)
// dst: wqk[720000] | bqk[1200] | wih[864000] | aff[180000] | wsa[540000] | bsa[1200]
__global__ __launch_bounds__(256) void k_stage(
    const float* __restrict__ wq, const float* __restrict__ wk,
    const float* __restrict__ bq, const float* __restrict__ bk,
    const float* __restrict__ wihf, const float* __restrict__ wihb,
    const float* __restrict__ aff1, const float* __restrict__ aff2,
    const float* __restrict__ ws0, const float* __restrict__ wa0,
    const float* __restrict__ ws1, const float* __restrict__ wa1,
    const float* __restrict__ bs0, const float* __restrict__ ba0,
    const float* __restrict__ bs1, const float* __restrict__ ba1,
    float* __restrict__ wqk, float* __restrict__ bqk,
    float* __restrict__ wih, float* __restrict__ aff,
    float* __restrict__ wsa, float* __restrict__ bsa)
{
  int i = blockIdx.x * 256 + threadIdx.x;
  if (i < 360000) wqk[i] = wq[i];
  else if (i < 720000) wqk[i] = wk[i - 360000];
  else if (i < 720600) bqk[i - 720000] = bq[i - 720000];
  else if (i < 721200) bqk[i - 720000] = bk[i - 720600];
  else if (i < 1153200) wih[i - 721200] = wihf[i - 721200];
  else if (i < 1585200) wih[i - 721200] = wihb[i - 1153200];
  else if (i < 1675200) aff[i - 1585200] = aff1[i - 1585200];
  else if (i < 1765200) aff[i - 1585200] = aff2[i - 1675200];
  else if (i < 1945200) wsa[i - 1765200] = ws0[i - 1765200];
  else if (i < 2125200) wsa[i - 1765200] = wa0[i - 1945200];
  else if (i < 2215200) wsa[i - 1765200] = ws1[i - 2125200];
  else if (i < 2305200) wsa[i - 1765200] = wa1[i - 2215200];
  else if (i < 2305500) bsa[i - 2305200] = bs0[i - 2305200];
  else if (i < 2305800) bsa[i - 2305200] = ba0[i - 2305500];
  else if (i < 2306100) bsa[i - 2305200] = bs1[i - 2305800];
  else if (i < 2306400) bsa[i - 2305200] = ba1[i - 2306100];
}

// ---------------------------------------------------------------- MFMA GEMM (bf16x3 split), 128x64 tile
// truncation-based split: hi = top16(x); lo = top16(x - as_float(hi)) — no cvt pipeline
__device__ inline short2 splitf(float x) {
  unsigned u = __float_as_uint(x);
  unsigned hb = u & 0xffff0000u;
  float r = x - __uint_as_float(hb);
  unsigned lb = __float_as_uint(r);
  short2 out;
  out.x = (short)(hb >> 16);
  out.y = (short)(lb >> 16);
  return out;
}

__device__ inline short8v ld_frag(const short* p) {
  short4v a = *reinterpret_cast<const short4v*>(p);
  short4v b = *reinterpret_cast<const short4v*>(p + 16);
  short8v r;
  r[0]=a[0]; r[1]=a[1]; r[2]=a[2]; r[3]=a[3];
  r[4]=b[0]; r[5]=b[1]; r[6]=b[2]; r[7]=b[3];
  return r;
}

#define LDA_ 36   // row stride in shorts (32 + 4 pad)

template<bool NT>
__global__ __launch_bounds__(256) void k_mgemm(
    const float* __restrict__ A, int lda, long sA1, long sA2,
    const float* __restrict__ Bm, int ldb, long sB1, long sB2,
    float* __restrict__ C, bf16* __restrict__ Cbf, int ldc, long sC1, long sC2,
    const float* __restrict__ bias, long sBias,
    const float* __restrict__ rowdiv,
    float alpha, int relu, int M, int N, int K, int nb2)
{
  __shared__ short Ah[128 * LDA_], Al[128 * LDA_], Bh[64 * LDA_], Bl[64 * LDA_];
  const int tid = threadIdx.x;
  const int w = tid >> 6, l = tid & 63;
  const int z = blockIdx.z;
  const int b1 = z / nb2, b2 = z - b1 * nb2;
  const float* Ab = A + b1 * sA1 + b2 * sA2;
  const float* Bb = Bm + b1 * sB1 + b2 * sB2;
  const int row0 = blockIdx.y * 128, col0 = blockIdx.x * 64;

  f32x4 acc[2][4];
#pragma unroll
  for (int f = 0; f < 2; ++f)
#pragma unroll
    for (int c = 0; c < 4; ++c) acc[f][c] = (f32x4){0.f, 0.f, 0.f, 0.f};

  const int lrow = l & 15, lk = (l >> 4) * 4;

  for (int k0 = 0; k0 < K; k0 += 32) {
    // ---- stage A: 128 rows x 32 k (1024 float4-slots) ----
#pragma unroll
    for (int j = 0; j < 4; ++j) {
      int slot = j * 256 + tid;
      int r = slot >> 3, kq = slot & 7;
      int gr = row0 + r, gk = k0 + kq * 4;
      float v[4] = {0.f, 0.f, 0.f, 0.f};
      if (gr < M) {
        if (gk + 3 < K) {
          float4 t = *reinterpret_cast<const float4*>(Ab + (long)gr * lda + gk);
          v[0] = t.x; v[1] = t.y; v[2] = t.z; v[3] = t.w;
        } else {
#pragma unroll
          for (int q = 0; q < 4; ++q) if (gk + q < K) v[q] = Ab[(long)gr * lda + gk + q];
        }
      }
      short4v hv, lv;
#pragma unroll
      for (int q = 0; q < 4; ++q) {
        short2 t2 = splitf(v[q]);
        hv[q] = t2.x; lv[q] = t2.y;
      }
      *reinterpret_cast<short4v*>(&Ah[r * LDA_ + kq * 4]) = hv;
      *reinterpret_cast<short4v*>(&Al[r * LDA_ + kq * 4]) = lv;
    }
    // ---- stage B: 64 x 32 ----
    if (NT) {
#pragma unroll
      for (int j = 0; j < 2; ++j) {
        int slot = j * 256 + tid;
        int r = slot >> 3, kq = slot & 7;
        int gc = col0 + r, gk = k0 + kq * 4;
        float v[4] = {0.f, 0.f, 0.f, 0.f};
        if (gc < N) {
          if (gk + 3 < K) {
            float4 t = *reinterpret_cast<const float4*>(Bb + (long)gc * ldb + gk);
            v[0] = t.x; v[1] = t.y; v[2] = t.z; v[3] = t.w;
          } else {
#pragma unroll
            for (int q = 0; q < 4; ++q) if (gk + q < K) v[q] = Bb[(long)gc * ldb + gk + q];
          }
        }
        short4v hv, lv;
#pragma unroll
        for (int q = 0; q < 4; ++q) {
          short2 t2 = splitf(v[q]);
          hv[q] = t2.x; lv[q] = t2.y;
        }
        *reinterpret_cast<short4v*>(&Bh[r * LDA_ + kq * 4]) = hv;
        *reinterpret_cast<short4v*>(&Bl[r * LDA_ + kq * 4]) = lv;
      }
    } else {
#pragma unroll
      for (int j = 0; j < 2; ++j) {
        int slot = j * 256 + tid;
        int kk = slot >> 4, nq = slot & 15;
        int gk = k0 + kk, gn = col0 + nq * 4;
        float v[4] = {0.f, 0.f, 0.f, 0.f};
        if (gk < K) {
          if (gn + 3 < N) {
            float4 t = *reinterpret_cast<const float4*>(Bb + (long)gk * ldb + gn);
            v[0] = t.x; v[1] = t.y; v[2] = t.z; v[3] = t.w;
          } else {
#pragma unroll
            for (int q = 0; q < 4; ++q) if (gn + q < N) v[q] = Bb[(long)gk * ldb + gn + q];
          }
        }
#pragma unroll
        for (int q = 0; q < 4; ++q) {
          short2 t2 = splitf(v[q]);
          Bh[(nq * 4 + q) * LDA_ + kk] = t2.x;
          Bl[(nq * 4 + q) * LDA_ + kk] = t2.y;
        }
      }
    }
    __syncthreads();

    // ---- compute: wave w owns rows w*32..w*32+31 (2 frags) ----
    short8v ah[2], al[2];
#pragma unroll
    for (int f = 0; f < 2; ++f) {
      int ar = w * 32 + f * 16 + lrow;
      ah[f] = ld_frag(&Ah[ar * LDA_ + lk]);
      al[f] = ld_frag(&Al[ar * LDA_ + lk]);
    }
#pragma unroll
    for (int c = 0; c < 4; ++c) {
      short8v bh = ld_frag(&Bh[(c * 16 + lrow) * LDA_ + lk]);
      short8v bl = ld_frag(&Bl[(c * 16 + lrow) * LDA_ + lk]);
#pragma unroll
      for (int f = 0; f < 2; ++f) {
        acc[f][c] = __builtin_amdgcn_mfma_f32_16x16x32_bf16(ah[f], bh, acc[f][c], 0, 0, 0);
        acc[f][c] = __builtin_amdgcn_mfma_f32_16x16x32_bf16(ah[f], bl, acc[f][c], 0, 0, 0);
        acc[f][c] = __builtin_amdgcn_mfma_f32_16x16x32_bf16(al[f], bh, acc[f][c], 0, 0, 0);
      }
    }
    __syncthreads();
  }

  float* Cb = C ? C + b1 * sC1 + b2 * sC2 : (float*)0;
  bf16*  Cf = Cbf ? Cbf + b1 * sC1 + b2 * sC2 : (bf16*)0;
#pragma unroll
  for (int f = 0; f < 2; ++f)
#pragma unroll
  for (int c = 0; c < 4; ++c) {
    int cc = col0 + c * 16 + lrow;
    if (cc >= N) continue;
#pragma unroll
    for (int reg = 0; reg < 4; ++reg) {
      int r = row0 + w * 32 + f * 16 + (l >> 4) * 4 + reg;
      if (r >= M) continue;
      float v = acc[f][c][reg] * alpha;
      if (bias) v += bias[b1 * sBias + cc];
      if (rowdiv) v /= rowdiv[(long)z * M + r];
      if (relu) v = fmaxf(v, 0.f);
      if (Cf) Cf[(long)r * ldc + cc] = __float2bfloat16(v);
      else    Cb[(long)r * ldc + cc] = v;
    }
  }
}

// ---------------------------------------------------------------- BiLSTM (u64 tagged-word sync)
__global__ __launch_bounds__(256, 1) void k_lstm(
    const float* __restrict__ preT_f, const float* __restrict__ preT_b,
    const float* __restrict__ whh_f, const float* __restrict__ whh_b,
    const float* __restrict__ bih_f, const float* __restrict__ bhh_f,
    const float* __restrict__ bih_b, const float* __restrict__ bhh_b,
    float* __restrict__ gcn, u64* __restrict__ hg)
{
  const int tid = threadIdx.x;
  const int dir = blockIdx.x / NCH;
  const int blk = blockIdx.x - dir * NCH;
  const int u0 = blk * 8;
  const int uc = min(8, HR - u0);
  const float* pre = dir ? preT_b : preT_f;
  const float* whh = dir ? whh_b : whh_f;
  const float* bih = dir ? bih_b : bih_f;
  const float* bhh = dir ? bhh_b : bhh_f;
  u64* hgd = hg + dir * 2400;                   // + buf*4800

  __shared__ float4 h5[1200];                   // h[k][b] linear
  __shared__ float part[32 * 545 + 64];
  __shared__ float g_lds[512];
  float* h5f = reinterpret_cast<float*>(h5);

  const int kc = tid >> 3;
  const int rq = tid & 7;
  const int kl = (kc < 12) ? 10 : 9;
  const int k0 = kc * 9 + min(kc, 12);

  float wreg[4][10];
#pragma unroll
  for (int i = 0; i < 4; ++i) {
    int lr = rq * 4 + i;
    int gate = lr >> 3, unit = lr & 7;
    bool valid = unit < uc;
    int growc = gate * HR + u0 + min(unit, uc - 1);
#pragma unroll
    for (int kk = 0; kk < 10; ++kk) {
      int k = min(k0 + kk, 299);
      float wv = whh[(long)growc * HR + k];
      wreg[i][kk] = (valid && kk < kl) ? wv : 0.f;
    }
  }

  const int o0 = tid * 2;
  const int lr0 = o0 >> 4;
  const int b0 = o0 & 15;
  const int gate0 = lr0 >> 3, unit0 = lr0 & 7;
  const int grow0 = gate0 * HR + u0 + min(unit0, uc - 1);
  const float breg = bih[grow0] + bhh[grow0];
  const float* prebase = pre + (long)grow0 * 8192;

  const int au = tid >> 3, abp = tid & 7;
  float c_reg0 = 0.f, c_reg1 = 0.f;

  const int own_lo = u0 * 8, own_hi = (u0 + uc) * 8;   // u64-index space

#pragma unroll 1
  for (int s = 0; s < L_; ++s) {
    const int tf = dir ? (L_ - 1 - s) : s;

    float p0 = prebase[tf * 16 + b0];
    float p1 = prebase[tf * 16 + b0 + 1];

    if (s > 0) {
      u64* srcb = hgd + (s & 1) * 4800;
      const u64 tag = (u64)s;
      u64 vals[10];
      int idxs[10];
#pragma unroll
      for (int j = 0; j < 10; ++j) {
        int idx = tid + j * 256;
        bool act = (idx < 2400) && (idx < own_lo || idx >= own_hi);
        idxs[j] = act ? idx : -1;
        vals[j] = act ? __hip_atomic_load(&srcb[idx], __ATOMIC_RELAXED, __HIP_MEMORY_SCOPE_AGENT)
                      : (tag << 32);
      }
      for (;;) {
        bool ok = true;
#pragma unroll
        for (int j = 0; j < 10; ++j)
          if ((vals[j] >> 32) != tag) ok = false;
        if (ok) break;
#pragma unroll
        for (int j = 0; j < 10; ++j)
          if ((vals[j] >> 32) != tag)
            vals[j] = __hip_atomic_load(&srcb[idxs[j]], __ATOMIC_RELAXED, __HIP_MEMORY_SCOPE_AGENT);
      }
#pragma unroll
      for (int j = 0; j < 10; ++j) {
        int idx = idxs[j];
        if (idx >= 0) {
          unsigned lo = (unsigned)(vals[j] & 0xffffffffu);
          unsigned short be = (unsigned short)(lo & 0xffffu);
          unsigned short bo = (unsigned short)(lo >> 16);
          bf16 he = *reinterpret_cast<bf16*>(&be);
          bf16 ho = *reinterpret_cast<bf16*>(&bo);
          int u = idx >> 3, bp = idx & 7;
          h5f[u * 16 + bp * 2]     = __bfloat162float(he);
          h5f[u * 16 + bp * 2 + 1] = __bfloat162float(ho);
        }
      }
    }
    __syncthreads();

    if (s > 0) {
      float4 acc[4][4];
#pragma unroll
      for (int i = 0; i < 4; ++i)
#pragma unroll
        for (int q = 0; q < 4; ++q) acc[i][q] = make_float4(0.f, 0.f, 0.f, 0.f);
#pragma unroll
      for (int kk = 0; kk < 10; ++kk) {
        if (kk < kl) {
          int k = k0 + kk;
          float4 hb0 = h5[k * 4 + 0];
          float4 hb1 = h5[k * 4 + 1];
          float4 hb2 = h5[k * 4 + 2];
          float4 hb3 = h5[k * 4 + 3];
#pragma unroll
          for (int i = 0; i < 4; ++i) {
            float w = wreg[i][kk];
            acc[i][0].x = fmaf(w, hb0.x, acc[i][0].x); acc[i][0].y = fmaf(w, hb0.y, acc[i][0].y);
            acc[i][0].z = fmaf(w, hb0.z, acc[i][0].z); acc[i][0].w = fmaf(w, hb0.w, acc[i][0].w);
            acc[i][1].x = fmaf(w, hb1.x, acc[i][1].x); acc[i][1].y = fmaf(w, hb1.y, acc[i][1].y);
            acc[i][1].z = fmaf(w, hb1.z, acc[i][1].z); acc[i][1].w = fmaf(w, hb1.w, acc[i][1].w);
            acc[i][2].x = fmaf(w, hb2.x, acc[i][2].x); acc[i][2].y = fmaf(w, hb2.y, acc[i][2].y);
            acc[i][2].z = fmaf(w, hb2.z, acc[i][2].z); acc[i][2].w = fmaf(w, hb2.w, acc[i][2].w);
            acc[i][3].x = fmaf(w, hb3.x, acc[i][3].x); acc[i][3].y = fmaf(w, hb3.y, acc[i][3].y);
            acc[i][3].z = fmaf(w, hb3.z, acc[i][3].z); acc[i][3].w = fmaf(w, hb3.w, acc[i][3].w);
          }
        }
      }
#pragma unroll
      for (int i = 0; i < 4; ++i) {
        int lr = rq * 4 + i;
        float* pb = part + kc * 545 + lr * 17;
#pragma unroll
        for (int q = 0; q < 4; ++q) {
          pb[q * 4 + 0] = acc[i][q].x; pb[q * 4 + 1] = acc[i][q].y;
          pb[q * 4 + 2] = acc[i][q].z; pb[q * 4 + 3] = acc[i][q].w;
        }
      }
    }
    __syncthreads();

    float g0 = p0 + breg, g1 = p1 + breg;
    if (s > 0) {
      const float* pb = part + lr0 * 17 + b0;
#pragma unroll
      for (int q = 0; q < 32; ++q) { g0 += pb[q * 545]; g1 += pb[q * 545 + 1]; }
    }
    g_lds[o0] = g0; g_lds[o0 + 1] = g1;
    __syncthreads();

    if (tid < 64 && au < uc) {
      int be = abp * 2, bo = abp * 2 + 1;
      float gi0 = g_lds[(0 * 8 + au) * 16 + be];
      float gf0 = g_lds[(1 * 8 + au) * 16 + be];
      float gg0 = g_lds[(2 * 8 + au) * 16 + be];
      float go0 = g_lds[(3 * 8 + au) * 16 + be];
      float gi1 = g_lds[(0 * 8 + au) * 16 + bo];
      float gf1 = g_lds[(1 * 8 + au) * 16 + bo];
      float gg1 = g_lds[(2 * 8 + au) * 16 + bo];
      float go1 = g_lds[(3 * 8 + au) * 16 + bo];
      float si0 = 1.f / (1.f + __expf(-gi0));
      float sf0 = 1.f / (1.f + __expf(-gf0));
      float so0 = 1.f / (1.f + __expf(-go0));
      float tg0 = tanhf(gg0);
      float si1 = 1.f / (1.f + __expf(-gi1));
      float sf1 = 1.f / (1.f + __expf(-gf1));
      float so1 = 1.f / (1.f + __expf(-go1));
      float tg1 = tanhf(gg1);
      c_reg0 = sf0 * c_reg0 + si0 * tg0;
      c_reg1 = sf1 * c_reg1 + si1 * tg1;
      float h0 = so0 * tanhf(c_reg0);
      float h1 = so1 * tanhf(c_reg1);
      h5f[(u0 + au) * 16 + be] = h0;
      h5f[(u0 + au) * 16 + bo] = h1;
      bf16 hbe = __float2bfloat16(h0);
      bf16 hbo = __float2bfloat16(h1);
      unsigned bitse = *reinterpret_cast<unsigned short*>(&hbe);
      unsigned bitso = *reinterpret_cast<unsigned short*>(&hbo);
      u64 val = ((u64)(s + 1) << 32) | ((u64)bitso << 16) | (u64)bitse;
      __hip_atomic_store(&hgd[((s + 1) & 1) * 4800 + (u0 + au) * 8 + abp], val,
                         __ATOMIC_RELAXED, __HIP_MEMORY_SCOPE_AGENT);
      gcn[((long)be * L_ + tf) * DM_ + dir * HR + u0 + au] = h0;
      gcn[((long)bo * L_ + tf) * DM_ + dir * HR + u0 + au] = h1;
    }
  }
}

// ---------------------------------------------------------------- small aspect kernels
__global__ void k_asplist(const float* __restrict__ asp_mask, int* __restrict__ apos, int* __restrict__ acnt)
{
  int b = threadIdx.x;
  if (b >= B_) return;
  int c = 0;
  for (int l = 0; l < L_; ++l)
    if (asp_mask[b * L_ + l] > 0.f) { if (c < MAXA) apos[b * MAXA + c] = l; ++c; }
  acnt[b] = (c < MAXA) ? c : MAXA;
}

__global__ void k_t0(const float* __restrict__ bd, const float* __restrict__ wm, float* __restrict__ t0)
{
  int i = blockIdx.x * 256 + threadIdx.x;
  if (i >= 8 * DK_) return;
  int h = i / DK_, e = i % DK_;
  float s = 0.f;
  for (int d = 0; d < DK_; ++d) s += bd[d] * wm[(h * DK_ + d) * DK_ + e];
  t0[i] = s;
}

__global__ void k_aspd(const float* __restrict__ gcn, const float* __restrict__ asp_mask,
                       const int* __restrict__ apos, const int* __restrict__ acnt,
                       const float* __restrict__ wd, const float* __restrict__ bd, float* __restrict__ aspd)
{
  int i = blockIdx.x * 256 + threadIdx.x;
  if (i >= B_ * MAXA * DK_) return;
  int d = i % DK_;
  int ba = i / DK_;
  int a = ba % MAXA, b = ba / MAXA;
  if (a >= acnt[b]) { aspd[i] = 0.f; return; }
  int p = apos[b * MAXA + a];
  float mv = asp_mask[b * L_ + p];
  const float* row = gcn + ((long)b * L_ + p) * DM_;
  float s = 0.f;
  for (int k = 0; k < DM_; ++k) s += row[k] * wd[d * DM_ + k];
  aspd[i] = s * mv + bd[d];
}

__global__ void k_tasp(const float* __restrict__ aspd, const int* __restrict__ acnt,
                       const float* __restrict__ wm, float* __restrict__ tasp)
{
  int i = blockIdx.x * 256 + threadIdx.x;
  if (i >= B_ * 8 * MAXA * DK_) return;
  int e = i % DK_;
  int t3 = i / DK_;
  int a = t3 % MAXA;
  int t4 = t3 / MAXA;
  int h = t4 % 8, b = t4 / 8;
  if (a >= acnt[b]) { tasp[i] = 0.f; return; }
  const float* ar = aspd + (b * MAXA + a) * DK_;
  float s = 0.f;
  for (int d = 0; d < DK_; ++d) s += ar[d] * wm[(h * DK_ + d) * DK_ + e];
  tasp[i] = s;
}

__global__ void k_avg(const float* __restrict__ k_lin, const float* __restrict__ t0,
                      const float* __restrict__ tasp, const int* __restrict__ acnt,
                      const float* __restrict__ bias_m, float* __restrict__ s0, float* __restrict__ avg)
{
  int i = blockIdx.x * 256 + threadIdx.x;
  if (i >= B_ * 8 * L_) return;
  int m = i % L_;
  int bh = i / L_;
  int h = bh % 8, b = bh / 8;
  const float* kr = k_lin + ((long)b * L_ + m) * DM_ + h * DK_;
  float bm = bias_m[0];
  const float* t0r = t0 + h * DK_;
  float d0 = 0.f;
  for (int e = 0; e < DK_; ++e) d0 += t0r[e] * kr[e];
  float sv = tanhf(d0 + bm);
  int cnt = acnt[b];
  float acc = (float)(L_ - cnt) * sv;
  for (int a = 0; a < cnt; ++a) {
    const float* tr = tasp + (((b * 8 + h) * MAXA) + a) * DK_;
    float dd = 0.f;
    for (int e = 0; e < DK_; ++e) dd += tr[e] * kr[e];
    acc += tanhf(dd + bm);
  }
  s0[i] = sv;
  avg[i] = acc * (1.f / (float)L_);
}

__global__ void k_bar(const float* __restrict__ s0, const float* __restrict__ avg,
                      float* __restrict__ s0bar, float* __restrict__ avbar)
{
  int i = blockIdx.x * 256 + threadIdx.x;
  if (i >= B_ * L_) return;
  int m = i % L_, b = i / L_;
  float sa = 0.f, aa = 0.f;
  for (int h = 0; h < 8; ++h) { sa += s0[(b * 8 + h) * L_ + m]; aa += avg[(b * 8 + h) * L_ + m]; }
  s0bar[i] = sa * 0.125f;
  avbar[i] = aa * 0.125f;
}

__global__ __launch_bounds__(256) void k_adjag(
    const float* __restrict__ asp_mask, const float* __restrict__ adjr,
    const float* __restrict__ s0bar, const float* __restrict__ avbar,
    float* __restrict__ adjag, float* __restrict__ denag)
{
  int bl = blockIdx.x;
  int b = bl >> 9, l = bl & 511;
  bool rA = asp_mask[b * L_ + l] > 0.f;
  float avl = avbar[b * L_ + l];
  float lsum = 0.f;
  for (int q = 0; q < 2; ++q) {
    int m = threadIdx.x + q * 256;
    bool cA = asp_mask[b * L_ + m] > 0.f;
    float asv;
    if (cA && (!rA || m > l)) asv = avl;
    else if (rA)              asv = avbar[b * L_ + m];
    else                      asv = s0bar[b * L_ + m];
    float r = (asv > 0.9f) ? 1.f : __expf(0.8f * adjr[((long)b * L_ + l) * L_ + m]);
    float v = r * asv;
    adjag[((long)b * L_ + l) * L_ + m] = v;
    lsum += v;
  }
  __shared__ float red[256];
  red[threadIdx.x] = lsum;
  __syncthreads();
  for (int st = 128; st > 0; st >>= 1) {
    if (threadIdx.x < st) red[threadIdx.x] += red[threadIdx.x + st];
    __syncthreads();
  }
  if (threadIdx.x == 0) denag[bl] = red[0] + 1.f;
}

// fused stats + head-mean softmax + diag/mask + denom; one block per (b,l)
__global__ __launch_bounds__(256) void k_adjs2(
    const bf16* __restrict__ sc, const int* __restrict__ tok,
    float* __restrict__ adjs, float* __restrict__ dens)
{
  int bl = blockIdx.x;
  int b = bl >> 9, l = bl & 511;
  int tid = threadIdx.x;
  __shared__ float srow[8][512];
  __shared__ float stats[16];    // mx[0..7], inv[8..15]
  __shared__ float red[256];

  int t0v = tok[b * L_ + tid], t1v = tok[b * L_ + tid + 256];
#pragma unroll
  for (int h = 0; h < 8; ++h) {
    const bf16* p = sc + ((long)((b * 8 + h) * L_) + l) * L_;
    float v0 = __bfloat162float(p[tid]);
    float v1 = __bfloat162float(p[tid + 256]);
    srow[h][tid]       = (t0v != 0) ? v0 : -1e9f;
    srow[h][tid + 256] = (t1v != 0) ? v1 : -1e9f;
  }
  __syncthreads();

  int wv = tid >> 6, lane = tid & 63;
#pragma unroll
  for (int hh = 0; hh < 2; ++hh) {
    int h = wv * 2 + hh;
    float vv[8];
#pragma unroll
    for (int i = 0; i < 8; ++i) vv[i] = srow[h][lane + i * 64];
    float m = vv[0];
#pragma unroll
    for (int i = 1; i < 8; ++i) m = fmaxf(m, vv[i]);
    for (int off = 32; off > 0; off >>= 1) m = fmaxf(m, __shfl_xor(m, off));
    float s = 0.f;
#pragma unroll
    for (int i = 0; i < 8; ++i) s += __expf(vv[i] - m);
    for (int off = 32; off > 0; off >>= 1) s += __shfl_xor(s, off);
    if (lane == 0) { stats[h] = m; stats[8 + h] = 1.f / s; }
  }
  __syncthreads();

  float acc0 = 0.f, acc1 = 0.f;
#pragma unroll
  for (int h = 0; h < 8; ++h) {
    float m = stats[h], inv = stats[8 + h];
    acc0 += __expf(srow[h][tid] - m) * inv;
    acc1 += __expf(srow[h][tid + 256] - m) * inv;
  }
  float rmask = (tok[b * L_ + l] != 0) ? 1.f : 0.f;
  float lsum = 0.f;
  {
    int m = tid;
    float v = acc0 * 0.125f;
    v = (m == l) ? 1.f : v;
    v *= rmask;
    adjs[(long)bl * L_ + m] = v;
    lsum += v;
  }
  {
    int m = tid + 256;
    float v = acc1 * 0.125f;
    v = (m == l) ? 1.f : v;
    v *= rmask;
    adjs[(long)bl * L_ + m] = v;
    lsum += v;
  }
  red[tid] = lsum;
  __syncthreads();
  for (int st = 128; st > 0; st >>= 1) {
    if (tid < st) red[tid] += red[tid + st];
    __syncthreads();
  }
  if (tid == 0) dens[bl] = red[0] + 1.f;
}

__global__ __launch_bounds__(256) void k_softmax(float* __restrict__ X)
{
  long row = blockIdx.x;
  float* p = X + row * L_;
  int tid = threadIdx.x;
  float a = p[tid], b = p[tid + 256];
  __shared__ float red[256];
  red[tid] = fmaxf(a, b);
  __syncthreads();
  for (int st = 128; st > 0; st >>= 1) {
    if (tid < st) red[tid] = fmaxf(red[tid], red[tid + st]);
    __syncthreads();
  }
  float mxv = red[0];
  __syncthreads();
  float ea = __expf(a - mxv), eb = __expf(b - mxv);
  red[tid] = ea + eb;
  __syncthreads();
  for (int st = 128; st > 0; st >>= 1) {
    if (tid < st) red[tid] += red[tid + st];
    __syncthreads();
  }
  float inv = 1.f / red[0];
  p[tid] = ea * inv;
  p[tid + 256] = eb * inv;
}

// ---------------------------------------------------------------- host side
static void gemm(hipStream_t st, bool nt,
                 const float* A, int lda, long sA1, long sA2,
                 const float* Bm, int ldb, long sB1, long sB2,
                 float* C, bf16* Cbf, int ldc, long sC1, long sC2,
                 const float* bias, long sBias, const float* rowdiv,
                 float alpha, int relu, int M, int N, int K, int nb1, int nb2)
{
  dim3 g((N + 63) / 64, (M + 127) / 128, nb1 * nb2);
  if (nt)
    k_mgemm<true><<<g, 256, 0, st>>>(A, lda, sA1, sA2, Bm, ldb, sB1, sB2, C, Cbf, ldc, sC1, sC2,
                                     bias, sBias, rowdiv, alpha, relu, M, N, K, nb2);
  else
    k_mgemm<false><<<g, 256, 0, st>>>(A, lda, sA1, sA2, Bm, ldb, sB1, sB2, C, Cbf, ldc, sC1, sC2,
                                      bias, sBias, rowdiv, alpha, relu, M, N, K, nb2);
}

extern "C" void kernel_launch(void* const* d_in, const int* in_sizes, int n_in,
                              void* d_out, int out_size, void* d_ws, size_t ws_size,
                              hipStream_t stream)
{
  const int*   tok     = (const int*)d_in[0];
  const int*   pos     = (const int*)d_in[1];
  const int*   post    = (const int*)d_in[2];
  const float* asp_mask= (const float*)d_in[3];
  const float* adjr    = (const float*)d_in[5];
  const float* emb_w   = (const float*)d_in[6];
  const float* pos_w   = (const float*)d_in[7];
  const float* post_w  = (const float*)d_in[8];
  const float* w_ih_f  = (const float*)d_in[9];
  const float* w_hh_f  = (const float*)d_in[10];
  const float* b_ih_f  = (const float*)d_in[11];
  const float* b_hh_f  = (const float*)d_in[12];
  const float* w_ih_b  = (const float*)d_in[13];
  const float* w_hh_b  = (const float*)d_in[14];
  const float* b_ih_b  = (const float*)d_in[15];
  const float* b_hh_b  = (const float*)d_in[16];
  const float* wq      = (const float*)d_in[17];
  const float* bq      = (const float*)d_in[18];
  const float* wk      = (const float*)d_in[19];
  const float* bk      = (const float*)d_in[20];
  const float* wd      = (const float*)d_in[21];
  const float* bd      = (const float*)d_in[22];
  const float* wm      = (const float*)d_in[23];
  const float* bias_m  = (const float*)d_in[24];
  const float* wa0     = (const float*)d_in[25];
  const float* ba0     = (const float*)d_in[26];
  const float* wa1     = (const float*)d_in[27];
  const float* ba1     = (const float*)d_in[28];
  const float* ws0     = (const float*)d_in[29];
  const float* bs0     = (const float*)d_in[30];
  const float* ws1     = (const float*)d_in[31];
  const float* bs1     = (const float*)d_in[32];
  const float* aff1    = (const float*)d_in[33];
  const float* aff2    = (const float*)d_in[34];
  float* out = (float*)d_out;
  float* W = (float*)d_ws;

  // ---- workspace layout (float units) ----
  size_t off = 0;
  auto alloc = [&](size_t n) { size_t o = off; off += (n + 63) & ~(size_t)63; return o; };
  size_t o_gcn   = alloc((size_t)8192 * DM_);
  size_t o_q     = alloc((size_t)8192 * DM_);
  size_t o_k     = alloc((size_t)8192 * DM_);
  size_t o_adjs  = alloc((size_t)B_ * L_ * L_);
  size_t o_adjag = alloc((size_t)B_ * L_ * L_);
  size_t o_dens  = alloc(8192);          // dens FIRST, denag at +8192 (stage2 rowdiv z-index)
  size_t o_denag = alloc(8192);
  size_t o_t0    = alloc(600);
  size_t o_apos  = alloc(B_ * MAXA);
  size_t o_acnt  = alloc(64);
  size_t o_aspd  = alloc(B_ * MAXA * DK_);
  size_t o_tasp  = alloc(B_ * 8 * MAXA * DK_);
  size_t o_s0    = alloc(B_ * 8 * L_);
  size_t o_avg   = alloc(B_ * 8 * L_);
  size_t o_s0bar = alloc(B_ * L_);
  size_t o_avbar = alloc(B_ * L_);
  size_t o_hg    = alloc(2 * 2 * 4800);  // u64 tagged-h pairs
  size_t o_wqk   = alloc(720000);
  size_t o_bqk   = alloc(1200);
  size_t o_wih   = alloc(864000);
  size_t o_aff   = alloc(180000);
  size_t o_wsa   = alloc(540000);        // [ws0][wa0][ws1][wa1]
  size_t o_bsa   = alloc(1200);          // [bs0][ba0][bs1][ba1]
  size_t o_oag1  = alloc((size_t)8192 * 300);
  size_t o_os1   = alloc((size_t)8192 * 300);
  size_t o_big   = alloc(23134300);      // union region
  size_t o_embs = o_big;
  size_t o_pref = o_big + 2949120;
  size_t o_preb = o_pref + 9830400;
  size_t o_sc   = o_big;
  size_t o_tmp  = o_big;                 // tmpA (ag path)
  size_t o_gag  = o_big + 4915200;
  size_t o_gs   = o_gag + 2457600;
  size_t o_h1   = o_gs  + 2457600;       // h1b = o_h1 + 2457600
  size_t o_a1m  = o_h1  + 4915200;       // also tmpS (s path) during stage1/2
  size_t o_a2m  = o_a1m + 4194304;

  if (ws_size < off * sizeof(float)) {
    (void)hipMemsetAsync(d_out, 0x7F, (size_t)out_size * sizeof(float), stream);
    return;
  }

  // 0) stage packed weights
  k_stage<<<(2306400 + 255) / 256, 256, 0, stream>>>(
      wq, wk, bq, bk, w_ih_f, w_ih_b, aff1, aff2,
      ws0, wa0, ws1, wa1, bs0, ba0, bs1, ba1,
      W + o_wqk, W + o_bqk, W + o_wih, W + o_aff, W + o_wsa, W + o_bsa);

  // 1) embeddings -> [t*16+b][360]
  k_embed<<<(L_ * B_ * 360 + 255) / 256, 256, 0, stream>>>(tok, pos, post, emb_w, pos_w, post_w, W + o_embs);

  // 2) pre-GEMMs batched (z=2): preT[j][t*16+b] = w_ih[j] . embs
  gemm(stream, true, W + o_wih, 360, 432000, 0, W + o_embs, 360, 0, 0,
       W + o_pref, nullptr, 8192, 9830400, 0, nullptr, 0, nullptr, 1.f, 0, 1200, 8192, 360, 2, 1);

  // 3) BiLSTM: 76 sharded blocks, u64 tagged-word sync
  k_lstm<<<2 * NCH, 256, 0, stream>>>(W + o_pref, W + o_preb, w_hh_f, w_hh_b,
                                      b_ih_f, b_hh_f, b_ih_b, b_hh_b,
                                      W + o_gcn, (u64*)(W + o_hg));

  // 4) q/k batched (z=2)
  gemm(stream, true, W + o_gcn, DM_, 0, 0, W + o_wqk, DM_, 360000, 0,
       W + o_q, nullptr, DM_, (long)(o_k - o_q), 0, W + o_bqk, 600, nullptr,
       1.f, 0, 8192, DM_, DM_, 2, 1);

  // 5) aspect structure
  k_asplist<<<1, 64, 0, stream>>>(asp_mask, (int*)(W + o_apos), (int*)(W + o_acnt));
  k_t0<<<(600 + 255) / 256, 256, 0, stream>>>(bd, wm, W + o_t0);
  k_aspd<<<(B_ * MAXA * DK_ + 255) / 256, 256, 0, stream>>>(W + o_gcn, asp_mask,
      (const int*)(W + o_apos), (const int*)(W + o_acnt), wd, bd, W + o_aspd);
  k_tasp<<<(B_ * 8 * MAXA * DK_ + 255) / 256, 256, 0, stream>>>(W + o_aspd,
      (const int*)(W + o_acnt), wm, W + o_tasp);
  k_avg<<<(B_ * 8 * L_ + 255) / 256, 256, 0, stream>>>(W + o_k, W + o_t0, W + o_tasp,
      (const int*)(W + o_acnt), bias_m, W + o_s0, W + o_avg);
  k_bar<<<(B_ * L_ + 255) / 256, 256, 0, stream>>>(W + o_s0, W + o_avg, W + o_s0bar, W + o_avbar);

  // 6) scores (bf16) -> fused adj_s ; adj_ag
  gemm(stream, true, W + o_q, DM_, (long)L_ * DM_, DK_, W + o_k, DM_, (long)L_ * DM_, DK_,
       nullptr, (bf16*)(W + o_sc), L_, (long)8 * L_ * L_, (long)L_ * L_,
       nullptr, 0, nullptr, 0.1154700538f, 0, L_, L_, DK_, B_, 8);
  k_adjs2<<<B_ * L_, 256, 0, stream>>>((const bf16*)(W + o_sc), tok, W + o_adjs, W + o_dens);
  k_adjag<<<B_ * L_, 256, 0, stream>>>(asp_mask, adjr, W + o_s0bar, W + o_avbar,
                                       W + o_adjag, W + o_denag);

  // 7) two GCN layers
  const float* inBase;
  long inStride;
  const long tmpStride = (long)o_tmp - (long)o_a1m;   // tmpS at o_a1m, tmpA at o_tmp
  int D = DM_;
  for (int layer = 0; layer < 2; ++layer) {
    if (layer == 0) { inBase = W + o_gcn; inStride = 0; }
    else            { inBase = W + o_os1; inStride = (long)o_oag1 - (long)o_os1; }
    // stage1 batched z=32 (b1: 0=s path, 1=ag path; b2=batch): tmp = adj @ in
    gemm(stream, false,
         W + o_adjs, L_, (long)o_adjag - (long)o_adjs, (long)L_ * L_,
         inBase, D, inStride, (long)L_ * D,
         W + o_a1m, nullptr, D, tmpStride, (long)L_ * D,
         nullptr, 0, nullptr, 1.f, 0, L_, D, L_, 2, B_);
    // stage2 batched z=2: g = relu((tmp @ w^T + b) / denom)
    gemm(stream, true,
         W + o_a1m, D, tmpStride, 0,
         W + o_wsa + (layer ? 360000 : 0), D, (layer ? 90000 : 180000), 0,
         W + o_gs, nullptr, 300, (long)o_gag - (long)o_gs, 0,
         W + o_bsa + (layer ? 600 : 0), 300, W + o_dens,
         1.f, 1, 8192, 300, D, 2, 1);
    // affine batched (z=2): h1 = gag@aff1 ; h1b = gs@aff2
    gemm(stream, false, W + o_gag, 300, (long)(o_gs - o_gag), 0, W + o_aff, 300, 90000, 0,
         W + o_h1, nullptr, 300, 2457600, 0, nullptr, 0, nullptr, 1.f, 0, 8192, 300, 300, 2, 1);
    // A1/A2 batched (z=2x16): a1m = h1 @ gs^T ; a2m = h1b @ gag^T
    gemm(stream, true, W + o_h1, 300, 2457600, (long)L_ * 300,
         W + o_gs, 300, (long)o_gag - (long)o_gs, (long)L_ * 300,
         W + o_a1m, nullptr, L_, 4194304, (long)L_ * L_,
         nullptr, 0, nullptr, 1.f, 0, L_, L_, 300, 2, B_);
    k_softmax<<<2 * B_ * L_, 256, 0, stream>>>(W + o_a1m);
    // out batched (z=2x16): out_ag = A1 @ gs ; out_s = A2 @ gag
    float* dstC; int ldcO; long sC1o, sC2o;
    if (layer == 0) { dstC = W + o_oag1; ldcO = 300; sC1o = (long)(o_os1 - o_oag1); sC2o = (long)L_ * 300; }
    else            { dstC = out;        ldcO = 600; sC1o = 300;                    sC2o = (long)L_ * 600; }
    gemm(stream, false, W + o_a1m, L_, 4194304, (long)L_ * L_,
         W + o_gs, 300, (long)o_gag - (long)o_gs, (long)L_ * 300,
         dstC, nullptr, ldcO, sC1o, sC2o,
         nullptr, 0, nullptr, 1.f, 0, L_, 300, L_, 2, B_);
    D = 300;
  }
}

// Round 13
// 2778.742 us; speedup vs baseline: 1.3185x; 1.0602x over previous
//
#include <hip/hip_runtime.h>
#include <hip/hip_bf16.h>

typedef __hip_bfloat16 bf16;
typedef __attribute__((ext_vector_type(4))) short short4v;
typedef __attribute__((ext_vector_type(8))) short short8v;
typedef __attribute__((ext_vector_type(4))) float f32x4;
typedef unsigned long long u64;

#define B_   16
#define L_   512
#define HR   300
#define DM_  600
#define DK_  75
#define MAXA 8
#define NCH  38            // u-chunks per dir (37*8 + 4)

// ---------------------------------------------------------------- embed
// embs layout: [seq = t*16 + b][360]
__global__ __launch_bounds__(256) void k_embed(
    const int* __restrict__ tok, const int* __restrict__ pos, const int* __restrict__ post,
    const float* __restrict__ emb_w, const float* __restrict__ pos_w, const float* __restrict__ post_w,
    float* __restrict__ embs)
{
  int idx = blockIdx.x * 256 + threadIdx.x;
  if (idx >= L_ * B_ * 360) return;
  int d = idx % 360;
  int seq = idx / 360;
  int b = seq & 15, t = seq >> 4;
  int si = b * L_ + t;
  float v;
  if (d < 300)       v = emb_w[(long)tok[si] * 300 + d];
  else if (d < 330)  v = pos_w[pos[si] * 30 + (d - 300)];
  else               v = post_w[post[si] * 30 + (d - 330)];
  embs[idx] = v;
}

// ---------------------------------------------------------------- weight staging (one launch)
// dst: wqk[720000] | bqk[1200] | wih[864000] | aff[180000] | wsa[540000] | bsa[1200]
__global__ __launch_bounds__(256) void k_stage(
    const float* __restrict__ wq, const float* __restrict__ wk,
    const float* __restrict__ bq, const float* __restrict__ bk,
    const float* __restrict__ wihf, const float* __restrict__ wihb,
    const float* __restrict__ aff1, const float* __restrict__ aff2,
    const float* __restrict__ ws0, const float* __restrict__ wa0,
    const float* __restrict__ ws1, const float* __restrict__ wa1,
    const float* __restrict__ bs0, const float* __restrict__ ba0,
    const float* __restrict__ bs1, const float* __restrict__ ba1,
    float* __restrict__ wqk, float* __restrict__ bqk,
    float* __restrict__ wih, float* __restrict__ aff,
    float* __restrict__ wsa, float* __restrict__ bsa)
{
  int i = blockIdx.x * 256 + threadIdx.x;
  if (i < 360000) wqk[i] = wq[i];
  else if (i < 720000) wqk[i] = wk[i - 360000];
  else if (i < 720600) bqk[i - 720000] = bq[i - 720000];
  else if (i < 721200) bqk[i - 720000] = bk[i - 720600];
  else if (i < 1153200) wih[i - 721200] = wihf[i - 721200];
  else if (i < 1585200) wih[i - 721200] = wihb[i - 1153200];
  else if (i < 1675200) aff[i - 1585200] = aff1[i - 1585200];
  else if (i < 1765200) aff[i - 1585200] = aff2[i - 1675200];
  else if (i < 1945200) wsa[i - 1765200] = ws0[i - 1765200];
  else if (i < 2125200) wsa[i - 1765200] = wa0[i - 1945200];
  else if (i < 2215200) wsa[i - 1765200] = ws1[i - 2125200];
  else if (i < 2305200) wsa[i - 1765200] = wa1[i - 2215200];
  else if (i < 2305500) bsa[i - 2305200] = bs0[i - 2305200];
  else if (i < 2305800) bsa[i - 2305200] = ba0[i - 2305500];
  else if (i < 2306100) bsa[i - 2305200] = bs1[i - 2305800];
  else if (i < 2306400) bsa[i - 2305200] = ba1[i - 2306100];
}

// ---------------------------------------------------------------- MFMA GEMM (bf16x3 split), 128x64 tile
// truncation-based split: hi = top16(x); lo = top16(x - as_float(hi)) — no cvt pipeline
__device__ inline short2 splitf(float x) {
  unsigned u = __float_as_uint(x);
  unsigned hb = u & 0xffff0000u;
  float r = x - __uint_as_float(hb);
  unsigned lb = __float_as_uint(r);
  short2 out;
  out.x = (short)(hb >> 16);
  out.y = (short)(lb >> 16);
  return out;
}

__device__ inline short8v ld_frag(const short* p) {
  short4v a = *reinterpret_cast<const short4v*>(p);
  short4v b = *reinterpret_cast<const short4v*>(p + 16);
  short8v r;
  r[0]=a[0]; r[1]=a[1]; r[2]=a[2]; r[3]=a[3];
  r[4]=b[0]; r[5]=b[1]; r[6]=b[2]; r[7]=b[3];
  return r;
}

#define LDA_ 36   // row stride in shorts (32 + 4 pad)

template<bool NT>
__global__ __launch_bounds__(256) void k_mgemm(
    const float* __restrict__ A, int lda, long sA1, long sA2,
    const float* __restrict__ Bm, int ldb, long sB1, long sB2,
    float* __restrict__ C, bf16* __restrict__ Cbf, int ldc, long sC1, long sC2,
    const float* __restrict__ bias, long sBias,
    const float* __restrict__ rowdiv,
    float alpha, int relu, int M, int N, int K, int nb2)
{
  __shared__ short Ah[128 * LDA_], Al[128 * LDA_], Bh[64 * LDA_], Bl[64 * LDA_];
  const int tid = threadIdx.x;
  const int w = tid >> 6, l = tid & 63;
  const int z = blockIdx.z;
  const int b1 = z / nb2, b2 = z - b1 * nb2;
  const float* Ab = A + b1 * sA1 + b2 * sA2;
  const float* Bb = Bm + b1 * sB1 + b2 * sB2;
  const int row0 = blockIdx.y * 128, col0 = blockIdx.x * 64;

  f32x4 acc[2][4];
#pragma unroll
  for (int f = 0; f < 2; ++f)
#pragma unroll
    for (int c = 0; c < 4; ++c) acc[f][c] = (f32x4){0.f, 0.f, 0.f, 0.f};

  const int lrow = l & 15, lk = (l >> 4) * 4;

  for (int k0 = 0; k0 < K; k0 += 32) {
    // ---- stage A: 128 rows x 32 k (1024 float4-slots) ----
#pragma unroll
    for (int j = 0; j < 4; ++j) {
      int slot = j * 256 + tid;
      int r = slot >> 3, kq = slot & 7;
      int gr = row0 + r, gk = k0 + kq * 4;
      float v[4] = {0.f, 0.f, 0.f, 0.f};
      if (gr < M) {
        if (gk + 3 < K) {
          float4 t = *reinterpret_cast<const float4*>(Ab + (long)gr * lda + gk);
          v[0] = t.x; v[1] = t.y; v[2] = t.z; v[3] = t.w;
        } else {
#pragma unroll
          for (int q = 0; q < 4; ++q) if (gk + q < K) v[q] = Ab[(long)gr * lda + gk + q];
        }
      }
      short4v hv, lv;
#pragma unroll
      for (int q = 0; q < 4; ++q) {
        short2 t2 = splitf(v[q]);
        hv[q] = t2.x; lv[q] = t2.y;
      }
      *reinterpret_cast<short4v*>(&Ah[r * LDA_ + kq * 4]) = hv;
      *reinterpret_cast<short4v*>(&Al[r * LDA_ + kq * 4]) = lv;
    }
    // ---- stage B: 64 x 32 ----
    if (NT) {
#pragma unroll
      for (int j = 0; j < 2; ++j) {
        int slot = j * 256 + tid;
        int r = slot >> 3, kq = slot & 7;
        int gc = col0 + r, gk = k0 + kq * 4;
        float v[4] = {0.f, 0.f, 0.f, 0.f};
        if (gc < N) {
          if (gk + 3 < K) {
            float4 t = *reinterpret_cast<const float4*>(Bb + (long)gc * ldb + gk);
            v[0] = t.x; v[1] = t.y; v[2] = t.z; v[3] = t.w;
          } else {
#pragma unroll
            for (int q = 0; q < 4; ++q) if (gk + q < K) v[q] = Bb[(long)gc * ldb + gk + q];
          }
        }
        short4v hv, lv;
#pragma unroll
        for (int q = 0; q < 4; ++q) {
          short2 t2 = splitf(v[q]);
          hv[q] = t2.x; lv[q] = t2.y;
        }
        *reinterpret_cast<short4v*>(&Bh[r * LDA_ + kq * 4]) = hv;
        *reinterpret_cast<short4v*>(&Bl[r * LDA_ + kq * 4]) = lv;
      }
    } else {
#pragma unroll
      for (int j = 0; j < 2; ++j) {
        int slot = j * 256 + tid;
        int kk = slot >> 4, nq = slot & 15;
        int gk = k0 + kk, gn = col0 + nq * 4;
        float v[4] = {0.f, 0.f, 0.f, 0.f};
        if (gk < K) {
          if (gn + 3 < N) {
            float4 t = *reinterpret_cast<const float4*>(Bb + (long)gk * ldb + gn);
            v[0] = t.x; v[1] = t.y; v[2] = t.z; v[3] = t.w;
          } else {
#pragma unroll
            for (int q = 0; q < 4; ++q) if (gn + q < N) v[q] = Bb[(long)gk * ldb + gn + q];
          }
        }
#pragma unroll
        for (int q = 0; q < 4; ++q) {
          short2 t2 = splitf(v[q]);
          Bh[(nq * 4 + q) * LDA_ + kk] = t2.x;
          Bl[(nq * 4 + q) * LDA_ + kk] = t2.y;
        }
      }
    }
    __syncthreads();

    // ---- compute: wave w owns rows w*32..w*32+31 (2 frags) ----
    short8v ah[2], al[2];
#pragma unroll
    for (int f = 0; f < 2; ++f) {
      int ar = w * 32 + f * 16 + lrow;
      ah[f] = ld_frag(&Ah[ar * LDA_ + lk]);
      al[f] = ld_frag(&Al[ar * LDA_ + lk]);
    }
#pragma unroll
    for (int c = 0; c < 4; ++c) {
      short8v bh = ld_frag(&Bh[(c * 16 + lrow) * LDA_ + lk]);
      short8v bl = ld_frag(&Bl[(c * 16 + lrow) * LDA_ + lk]);
#pragma unroll
      for (int f = 0; f < 2; ++f) {
        acc[f][c] = __builtin_amdgcn_mfma_f32_16x16x32_bf16(ah[f], bh, acc[f][c], 0, 0, 0);
        acc[f][c] = __builtin_amdgcn_mfma_f32_16x16x32_bf16(ah[f], bl, acc[f][c], 0, 0, 0);
        acc[f][c] = __builtin_amdgcn_mfma_f32_16x16x32_bf16(al[f], bh, acc[f][c], 0, 0, 0);
      }
    }
    __syncthreads();
  }

  float* Cb = C ? C + b1 * sC1 + b2 * sC2 : (float*)0;
  bf16*  Cf = Cbf ? Cbf + b1 * sC1 + b2 * sC2 : (bf16*)0;
#pragma unroll
  for (int f = 0; f < 2; ++f)
#pragma unroll
  for (int c = 0; c < 4; ++c) {
    int cc = col0 + c * 16 + lrow;
    if (cc >= N) continue;
#pragma unroll
    for (int reg = 0; reg < 4; ++reg) {
      int r = row0 + w * 32 + f * 16 + (l >> 4) * 4 + reg;
      if (r >= M) continue;
      float v = acc[f][c][reg] * alpha;
      if (bias) v += bias[b1 * sBias + cc];
      if (rowdiv) v /= rowdiv[(long)z * M + r];
      if (relu) v = fmaxf(v, 0.f);
      if (Cf) Cf[(long)r * ldc + cc] = __float2bfloat16(v);
      else    Cb[(long)r * ldc + cc] = v;
    }
  }
}

// ---------------------------------------------------------------- BiLSTM (u64 tagged-word sync, 512 threads)
// tid = kc*16 + rq: kc = k-chunk (32), rq = row-pair (16, 2 rows each).
// Reduce role: one gate element per thread (lr0 = tid>>4, b0 = tid&15).
__global__ __launch_bounds__(512, 1) void k_lstm(
    const float* __restrict__ preT_f, const float* __restrict__ preT_b,
    const float* __restrict__ whh_f, const float* __restrict__ whh_b,
    const float* __restrict__ bih_f, const float* __restrict__ bhh_f,
    const float* __restrict__ bih_b, const float* __restrict__ bhh_b,
    float* __restrict__ gcn, u64* __restrict__ hg)
{
  const int tid = threadIdx.x;
  const int dir = blockIdx.x / NCH;
  const int blk = blockIdx.x - dir * NCH;
  const int u0 = blk * 8;
  const int uc = min(8, HR - u0);
  const float* pre = dir ? preT_b : preT_f;
  const float* whh = dir ? whh_b : whh_f;
  const float* bih = dir ? bih_b : bih_f;
  const float* bhh = dir ? bhh_b : bhh_f;
  u64* hgd = hg + dir * 2400;                   // + buf*4800

  __shared__ float4 h5[1200];                   // h[k][b] linear
  __shared__ float part[32 * 545 + 64];
  __shared__ float g_lds[512];
  float* h5f = reinterpret_cast<float*>(h5);

  const int kc = tid >> 4;                      // 0..31
  const int rq = tid & 15;                      // 0..15 (2 rows each)
  const int kl = (kc < 12) ? 10 : 9;
  const int k0 = kc * 9 + min(kc, 12);

  float wreg[2][10];
#pragma unroll
  for (int i = 0; i < 2; ++i) {
    int lr = rq * 2 + i;
    int gate = lr >> 3, unit = lr & 7;
    bool valid = unit < uc;
    int growc = gate * HR + u0 + min(unit, uc - 1);
#pragma unroll
    for (int kk = 0; kk < 10; ++kk) {
      int k = min(k0 + kk, 299);
      float wv = whh[(long)growc * HR + k];
      wreg[i][kk] = (valid && kk < kl) ? wv : 0.f;
    }
  }

  const int lr0 = tid >> 4;                     // 0..31 (row for reduce role)
  const int b0 = tid & 15;
  const int gate0 = lr0 >> 3, unit0 = lr0 & 7;
  const int grow0 = gate0 * HR + u0 + min(unit0, uc - 1);
  const float breg = bih[grow0] + bhh[grow0];
  const float* prebase = pre + (long)grow0 * 8192;

  const int au = tid >> 3, abp = tid & 7;       // activation role (tid<64)
  float c_reg0 = 0.f, c_reg1 = 0.f;

  const int own_lo = u0 * 8, own_hi = (u0 + uc) * 8;   // u64-index space

#pragma unroll 1
  for (int s = 0; s < L_; ++s) {
    const int tf = dir ? (L_ - 1 - s) : s;

    float p0 = prebase[tf * 16 + b0];

    if (s > 0) {
      u64* srcb = hgd + (s & 1) * 4800;
      const u64 tag = (u64)s;
      u64 vals[5];
      int idxs[5];
#pragma unroll
      for (int j = 0; j < 5; ++j) {
        int idx = tid + j * 512;
        bool act = (idx < 2400) && (idx < own_lo || idx >= own_hi);
        idxs[j] = act ? idx : -1;
        vals[j] = act ? __hip_atomic_load(&srcb[idx], __ATOMIC_RELAXED, __HIP_MEMORY_SCOPE_AGENT)
                      : (tag << 32);
      }
      for (;;) {
        bool ok = true;
#pragma unroll
        for (int j = 0; j < 5; ++j)
          if ((vals[j] >> 32) != tag) ok = false;
        if (ok) break;
#pragma unroll
        for (int j = 0; j < 5; ++j)
          if ((vals[j] >> 32) != tag)
            vals[j] = __hip_atomic_load(&srcb[idxs[j]], __ATOMIC_RELAXED, __HIP_MEMORY_SCOPE_AGENT);
      }
#pragma unroll
      for (int j = 0; j < 5; ++j) {
        int idx = idxs[j];
        if (idx >= 0) {
          unsigned lo = (unsigned)(vals[j] & 0xffffffffu);
          unsigned short be = (unsigned short)(lo & 0xffffu);
          unsigned short bo = (unsigned short)(lo >> 16);
          bf16 he = *reinterpret_cast<bf16*>(&be);
          bf16 ho = *reinterpret_cast<bf16*>(&bo);
          int u = idx >> 3, bp = idx & 7;
          h5f[u * 16 + bp * 2]     = __bfloat162float(he);
          h5f[u * 16 + bp * 2 + 1] = __bfloat162float(ho);
        }
      }
    }
    __syncthreads();

    if (s > 0) {
      float4 acc[2][4];
#pragma unroll
      for (int i = 0; i < 2; ++i)
#pragma unroll
        for (int q = 0; q < 4; ++q) acc[i][q] = make_float4(0.f, 0.f, 0.f, 0.f);
#pragma unroll
      for (int kk = 0; kk < 10; ++kk) {
        if (kk < kl) {
          int k = k0 + kk;
          float4 hb0 = h5[k * 4 + 0];
          float4 hb1 = h5[k * 4 + 1];
          float4 hb2 = h5[k * 4 + 2];
          float4 hb3 = h5[k * 4 + 3];
#pragma unroll
          for (int i = 0; i < 2; ++i) {
            float w = wreg[i][kk];
            acc[i][0].x = fmaf(w, hb0.x, acc[i][0].x); acc[i][0].y = fmaf(w, hb0.y, acc[i][0].y);
            acc[i][0].z = fmaf(w, hb0.z, acc[i][0].z); acc[i][0].w = fmaf(w, hb0.w, acc[i][0].w);
            acc[i][1].x = fmaf(w, hb1.x, acc[i][1].x); acc[i][1].y = fmaf(w, hb1.y, acc[i][1].y);
            acc[i][1].z = fmaf(w, hb1.z, acc[i][1].z); acc[i][1].w = fmaf(w, hb1.w, acc[i][1].w);
            acc[i][2].x = fmaf(w, hb2.x, acc[i][2].x); acc[i][2].y = fmaf(w, hb2.y, acc[i][2].y);
            acc[i][2].z = fmaf(w, hb2.z, acc[i][2].z); acc[i][2].w = fmaf(w, hb2.w, acc[i][2].w);
            acc[i][3].x = fmaf(w, hb3.x, acc[i][3].x); acc[i][3].y = fmaf(w, hb3.y, acc[i][3].y);
            acc[i][3].z = fmaf(w, hb3.z, acc[i][3].z); acc[i][3].w = fmaf(w, hb3.w, acc[i][3].w);
          }
        }
      }
#pragma unroll
      for (int i = 0; i < 2; ++i) {
        int lr = rq * 2 + i;
        float* pb = part + kc * 545 + lr * 17;
#pragma unroll
        for (int q = 0; q < 4; ++q) {
          pb[q * 4 + 0] = acc[i][q].x; pb[q * 4 + 1] = acc[i][q].y;
          pb[q * 4 + 2] = acc[i][q].z; pb[q * 4 + 3] = acc[i][q].w;
        }
      }
    }
    __syncthreads();

    float g0 = p0 + breg;
    if (s > 0) {
      const float* pb = part + lr0 * 17 + b0;
#pragma unroll
      for (int q = 0; q < 32; ++q) g0 += pb[q * 545];
    }
    g_lds[tid] = g0;
    __syncthreads();

    if (tid < 64 && au < uc) {
      int be = abp * 2, bo = abp * 2 + 1;
      float gi0 = g_lds[(0 * 8 + au) * 16 + be];
      float gf0 = g_lds[(1 * 8 + au) * 16 + be];
      float gg0 = g_lds[(2 * 8 + au) * 16 + be];
      float go0 = g_lds[(3 * 8 + au) * 16 + be];
      float gi1 = g_lds[(0 * 8 + au) * 16 + bo];
      float gf1 = g_lds[(1 * 8 + au) * 16 + bo];
      float gg1 = g_lds[(2 * 8 + au) * 16 + bo];
      float go1 = g_lds[(3 * 8 + au) * 16 + bo];
      float si0 = 1.f / (1.f + __expf(-gi0));
      float sf0 = 1.f / (1.f + __expf(-gf0));
      float so0 = 1.f / (1.f + __expf(-go0));
      float tg0 = tanhf(gg0);
      float si1 = 1.f / (1.f + __expf(-gi1));
      float sf1 = 1.f / (1.f + __expf(-gf1));
      float so1 = 1.f / (1.f + __expf(-go1));
      float tg1 = tanhf(gg1);
      c_reg0 = sf0 * c_reg0 + si0 * tg0;
      c_reg1 = sf1 * c_reg1 + si1 * tg1;
      float h0 = so0 * tanhf(c_reg0);
      float h1 = so1 * tanhf(c_reg1);
      h5f[(u0 + au) * 16 + be] = h0;
      h5f[(u0 + au) * 16 + bo] = h1;
      bf16 hbe = __float2bfloat16(h0);
      bf16 hbo = __float2bfloat16(h1);
      unsigned bitse = *reinterpret_cast<unsigned short*>(&hbe);
      unsigned bitso = *reinterpret_cast<unsigned short*>(&hbo);
      u64 val = ((u64)(s + 1) << 32) | ((u64)bitso << 16) | (u64)bitse;
      __hip_atomic_store(&hgd[((s + 1) & 1) * 4800 + (u0 + au) * 8 + abp], val,
                         __ATOMIC_RELAXED, __HIP_MEMORY_SCOPE_AGENT);
      gcn[((long)be * L_ + tf) * DM_ + dir * HR + u0 + au] = h0;
      gcn[((long)bo * L_ + tf) * DM_ + dir * HR + u0 + au] = h1;
    }
  }
}

// ---------------------------------------------------------------- small aspect kernels
__global__ void k_asplist(const float* __restrict__ asp_mask, int* __restrict__ apos, int* __restrict__ acnt)
{
  int b = threadIdx.x;
  if (b >= B_) return;
  int c = 0;
  for (int l = 0; l < L_; ++l)
    if (asp_mask[b * L_ + l] > 0.f) { if (c < MAXA) apos[b * MAXA + c] = l; ++c; }
  acnt[b] = (c < MAXA) ? c : MAXA;
}

__global__ void k_t0(const float* __restrict__ bd, const float* __restrict__ wm, float* __restrict__ t0)
{
  int i = blockIdx.x * 256 + threadIdx.x;
  if (i >= 8 * DK_) return;
  int h = i / DK_, e = i % DK_;
  float s = 0.f;
  for (int d = 0; d < DK_; ++d) s += bd[d] * wm[(h * DK_ + d) * DK_ + e];
  t0[i] = s;
}

__global__ void k_aspd(const float* __restrict__ gcn, const float* __restrict__ asp_mask,
                       const int* __restrict__ apos, const int* __restrict__ acnt,
                       const float* __restrict__ wd, const float* __restrict__ bd, float* __restrict__ aspd)
{
  int i = blockIdx.x * 256 + threadIdx.x;
  if (i >= B_ * MAXA * DK_) return;
  int d = i % DK_;
  int ba = i / DK_;
  int a = ba % MAXA, b = ba / MAXA;
  if (a >= acnt[b]) { aspd[i] = 0.f; return; }
  int p = apos[b * MAXA + a];
  float mv = asp_mask[b * L_ + p];
  const float* row = gcn + ((long)b * L_ + p) * DM_;
  float s = 0.f;
  for (int k = 0; k < DM_; ++k) s += row[k] * wd[d * DM_ + k];
  aspd[i] = s * mv + bd[d];
}

__global__ void k_tasp(const float* __restrict__ aspd, const int* __restrict__ acnt,
                       const float* __restrict__ wm, float* __restrict__ tasp)
{
  int i = blockIdx.x * 256 + threadIdx.x;
  if (i >= B_ * 8 * MAXA * DK_) return;
  int e = i % DK_;
  int t3 = i / DK_;
  int a = t3 % MAXA;
  int t4 = t3 / MAXA;
  int h = t4 % 8, b = t4 / 8;
  if (a >= acnt[b]) { tasp[i] = 0.f; return; }
  const float* ar = aspd + (b * MAXA + a) * DK_;
  float s = 0.f;
  for (int d = 0; d < DK_; ++d) s += ar[d] * wm[(h * DK_ + d) * DK_ + e];
  tasp[i] = s;
}

__global__ void k_avg(const float* __restrict__ k_lin, const float* __restrict__ t0,
                      const float* __restrict__ tasp, const int* __restrict__ acnt,
                      const float* __restrict__ bias_m, float* __restrict__ s0, float* __restrict__ avg)
{
  int i = blockIdx.x * 256 + threadIdx.x;
  if (i >= B_ * 8 * L_) return;
  int m = i % L_;
  int bh = i / L_;
  int h = bh % 8, b = bh / 8;
  const float* kr = k_lin + ((long)b * L_ + m) * DM_ + h * DK_;
  float bm = bias_m[0];
  const float* t0r = t0 + h * DK_;
  float d0 = 0.f;
  for (int e = 0; e < DK_; ++e) d0 += t0r[e] * kr[e];
  float sv = tanhf(d0 + bm);
  int cnt = acnt[b];
  float acc = (float)(L_ - cnt) * sv;
  for (int a = 0; a < cnt; ++a) {
    const float* tr = tasp + (((b * 8 + h) * MAXA) + a) * DK_;
    float dd = 0.f;
    for (int e = 0; e < DK_; ++e) dd += tr[e] * kr[e];
    acc += tanhf(dd + bm);
  }
  s0[i] = sv;
  avg[i] = acc * (1.f / (float)L_);
}

__global__ void k_bar(const float* __restrict__ s0, const float* __restrict__ avg,
                      float* __restrict__ s0bar, float* __restrict__ avbar)
{
  int i = blockIdx.x * 256 + threadIdx.x;
  if (i >= B_ * L_) return;
  int m = i % L_, b = i / L_;
  float sa = 0.f, aa = 0.f;
  for (int h = 0; h < 8; ++h) { sa += s0[(b * 8 + h) * L_ + m]; aa += avg[(b * 8 + h) * L_ + m]; }
  s0bar[i] = sa * 0.125f;
  avbar[i] = aa * 0.125f;
}

__global__ __launch_bounds__(256) void k_adjag(
    const float* __restrict__ asp_mask, const float* __restrict__ adjr,
    const float* __restrict__ s0bar, const float* __restrict__ avbar,
    float* __restrict__ adjag, float* __restrict__ denag)
{
  int bl = blockIdx.x;
  int b = bl >> 9, l = bl & 511;
  bool rA = asp_mask[b * L_ + l] > 0.f;
  float avl = avbar[b * L_ + l];
  float lsum = 0.f;
  for (int q = 0; q < 2; ++q) {
    int m = threadIdx.x + q * 256;
    bool cA = asp_mask[b * L_ + m] > 0.f;
    float asv;
    if (cA && (!rA || m > l)) asv = avl;
    else if (rA)              asv = avbar[b * L_ + m];
    else                      asv = s0bar[b * L_ + m];
    float r = (asv > 0.9f) ? 1.f : __expf(0.8f * adjr[((long)b * L_ + l) * L_ + m]);
    float v = r * asv;
    adjag[((long)b * L_ + l) * L_ + m] = v;
    lsum += v;
  }
  __shared__ float red[256];
  red[threadIdx.x] = lsum;
  __syncthreads();
  for (int st = 128; st > 0; st >>= 1) {
    if (threadIdx.x < st) red[threadIdx.x] += red[threadIdx.x + st];
    __syncthreads();
  }
  if (threadIdx.x == 0) denag[bl] = red[0] + 1.f;
}

// fused stats + head-mean softmax + diag/mask + denom; one block per (b,l)
__global__ __launch_bounds__(256) void k_adjs2(
    const bf16* __restrict__ sc, const int* __restrict__ tok,
    float* __restrict__ adjs, float* __restrict__ dens)
{
  int bl = blockIdx.x;
  int b = bl >> 9, l = bl & 511;
  int tid = threadIdx.x;
  __shared__ float srow[8][512];
  __shared__ float stats[16];    // mx[0..7], inv[8..15]
  __shared__ float red[256];

  int t0v = tok[b * L_ + tid], t1v = tok[b * L_ + tid + 256];
#pragma unroll
  for (int h = 0; h < 8; ++h) {
    const bf16* p = sc + ((long)((b * 8 + h) * L_) + l) * L_;
    float v0 = __bfloat162float(p[tid]);
    float v1 = __bfloat162float(p[tid + 256]);
    srow[h][tid]       = (t0v != 0) ? v0 : -1e9f;
    srow[h][tid + 256] = (t1v != 0) ? v1 : -1e9f;
  }
  __syncthreads();

  int wv = tid >> 6, lane = tid & 63;
#pragma unroll
  for (int hh = 0; hh < 2; ++hh) {
    int h = wv * 2 + hh;
    float vv[8];
#pragma unroll
    for (int i = 0; i < 8; ++i) vv[i] = srow[h][lane + i * 64];
    float m = vv[0];
#pragma unroll
    for (int i = 1; i < 8; ++i) m = fmaxf(m, vv[i]);
    for (int off = 32; off > 0; off >>= 1) m = fmaxf(m, __shfl_xor(m, off));
    float s = 0.f;
#pragma unroll
    for (int i = 0; i < 8; ++i) s += __expf(vv[i] - m);
    for (int off = 32; off > 0; off >>= 1) s += __shfl_xor(s, off);
    if (lane == 0) { stats[h] = m; stats[8 + h] = 1.f / s; }
  }
  __syncthreads();

  float acc0 = 0.f, acc1 = 0.f;
#pragma unroll
  for (int h = 0; h < 8; ++h) {
    float m = stats[h], inv = stats[8 + h];
    acc0 += __expf(srow[h][tid] - m) * inv;
    acc1 += __expf(srow[h][tid + 256] - m) * inv;
  }
  float rmask = (tok[b * L_ + l] != 0) ? 1.f : 0.f;
  float lsum = 0.f;
  {
    int m = tid;
    float v = acc0 * 0.125f;
    v = (m == l) ? 1.f : v;
    v *= rmask;
    adjs[(long)bl * L_ + m] = v;
    lsum += v;
  }
  {
    int m = tid + 256;
    float v = acc1 * 0.125f;
    v = (m == l) ? 1.f : v;
    v *= rmask;
    adjs[(long)bl * L_ + m] = v;
    lsum += v;
  }
  red[tid] = lsum;
  __syncthreads();
  for (int st = 128; st > 0; st >>= 1) {
    if (tid < st) red[tid] += red[tid + st];
    __syncthreads();
  }
  if (tid == 0) dens[bl] = red[0] + 1.f;
}

__global__ __launch_bounds__(256) void k_softmax(float* __restrict__ X)
{
  long row = blockIdx.x;
  float* p = X + row * L_;
  int tid = threadIdx.x;
  float a = p[tid], b = p[tid + 256];
  __shared__ float red[256];
  red[tid] = fmaxf(a, b);
  __syncthreads();
  for (int st = 128; st > 0; st >>= 1) {
    if (tid < st) red[tid] = fmaxf(red[tid], red[tid + st]);
    __syncthreads();
  }
  float mxv = red[0];
  __syncthreads();
  float ea = __expf(a - mxv), eb = __expf(b - mxv);
  red[tid] = ea + eb;
  __syncthreads();
  for (int st = 128; st > 0; st >>= 1) {
    if (tid < st) red[tid] += red[tid + st];
    __syncthreads();
  }
  float inv = 1.f / red[0];
  p[tid] = ea * inv;
  p[tid + 256] = eb * inv;
}

// ---------------------------------------------------------------- host side
static void gemm(hipStream_t st, bool nt,
                 const float* A, int lda, long sA1, long sA2,
                 const float* Bm, int ldb, long sB1, long sB2,
                 float* C, bf16* Cbf, int ldc, long sC1, long sC2,
                 const float* bias, long sBias, const float* rowdiv,
                 float alpha, int relu, int M, int N, int K, int nb1, int nb2)
{
  dim3 g((N + 63) / 64, (M + 127) / 128, nb1 * nb2);
  if (nt)
    k_mgemm<true><<<g, 256, 0, st>>>(A, lda, sA1, sA2, Bm, ldb, sB1, sB2, C, Cbf, ldc, sC1, sC2,
                                     bias, sBias, rowdiv, alpha, relu, M, N, K, nb2);
  else
    k_mgemm<false><<<g, 256, 0, st>>>(A, lda, sA1, sA2, Bm, ldb, sB1, sB2, C, Cbf, ldc, sC1, sC2,
                                      bias, sBias, rowdiv, alpha, relu, M, N, K, nb2);
}

extern "C" void kernel_launch(void* const* d_in, const int* in_sizes, int n_in,
                              void* d_out, int out_size, void* d_ws, size_t ws_size,
                              hipStream_t stream)
{
  const int*   tok     = (const int*)d_in[0];
  const int*   pos     = (const int*)d_in[1];
  const int*   post    = (const int*)d_in[2];
  const float* asp_mask= (const float*)d_in[3];
  const float* adjr    = (const float*)d_in[5];
  const float* emb_w   = (const float*)d_in[6];
  const float* pos_w   = (const float*)d_in[7];
  const float* post_w  = (const float*)d_in[8];
  const float* w_ih_f  = (const float*)d_in[9];
  const float* w_hh_f  = (const float*)d_in[10];
  const float* b_ih_f  = (const float*)d_in[11];
  const float* b_hh_f  = (const float*)d_in[12];
  const float* w_ih_b  = (const float*)d_in[13];
  const float* w_hh_b  = (const float*)d_in[14];
  const float* b_ih_b  = (const float*)d_in[15];
  const float* b_hh_b  = (const float*)d_in[16];
  const float* wq      = (const float*)d_in[17];
  const float* bq      = (const float*)d_in[18];
  const float* wk      = (const float*)d_in[19];
  const float* bk      = (const float*)d_in[20];
  const float* wd      = (const float*)d_in[21];
  const float* bd      = (const float*)d_in[22];
  const float* wm      = (const float*)d_in[23];
  const float* bias_m  = (const float*)d_in[24];
  const float* wa0     = (const float*)d_in[25];
  const float* ba0     = (const float*)d_in[26];
  const float* wa1     = (const float*)d_in[27];
  const float* ba1     = (const float*)d_in[28];
  const float* ws0     = (const float*)d_in[29];
  const float* bs0     = (const float*)d_in[30];
  const float* ws1     = (const float*)d_in[31];
  const float* bs1     = (const float*)d_in[32];
  const float* aff1    = (const float*)d_in[33];
  const float* aff2    = (const float*)d_in[34];
  float* out = (float*)d_out;
  float* W = (float*)d_ws;

  // ---- workspace layout (float units) ----
  size_t off = 0;
  auto alloc = [&](size_t n) { size_t o = off; off += (n + 63) & ~(size_t)63; return o; };
  size_t o_gcn   = alloc((size_t)8192 * DM_);
  size_t o_q     = alloc((size_t)8192 * DM_);
  size_t o_k     = alloc((size_t)8192 * DM_);
  size_t o_adjs  = alloc((size_t)B_ * L_ * L_);
  size_t o_adjag = alloc((size_t)B_ * L_ * L_);
  size_t o_dens  = alloc(8192);          // dens FIRST, denag at +8192 (stage2 rowdiv z-index)
  size_t o_denag = alloc(8192);
  size_t o_t0    = alloc(600);
  size_t o_apos  = alloc(B_ * MAXA);
  size_t o_acnt  = alloc(64);
  size_t o_aspd  = alloc(B_ * MAXA * DK_);
  size_t o_tasp  = alloc(B_ * 8 * MAXA * DK_);
  size_t o_s0    = alloc(B_ * 8 * L_);
  size_t o_avg   = alloc(B_ * 8 * L_);
  size_t o_s0bar = alloc(B_ * L_);
  size_t o_avbar = alloc(B_ * L_);
  size_t o_hg    = alloc(2 * 2 * 4800);  // u64 tagged-h pairs
  size_t o_wqk   = alloc(720000);
  size_t o_bqk   = alloc(1200);
  size_t o_wih   = alloc(864000);
  size_t o_aff   = alloc(180000);
  size_t o_wsa   = alloc(540000);        // [ws0][wa0][ws1][wa1]
  size_t o_bsa   = alloc(1200);          // [bs0][ba0][bs1][ba1]
  size_t o_oag1  = alloc((size_t)8192 * 300);
  size_t o_os1   = alloc((size_t)8192 * 300);
  size_t o_big   = alloc(23134300);      // union region
  size_t o_embs = o_big;
  size_t o_pref = o_big + 2949120;
  size_t o_preb = o_pref + 9830400;
  size_t o_sc   = o_big;
  size_t o_tmp  = o_big;                 // tmpA (ag path)
  size_t o_gag  = o_big + 4915200;
  size_t o_gs   = o_gag + 2457600;
  size_t o_h1   = o_gs  + 2457600;       // h1b = o_h1 + 2457600
  size_t o_a1m  = o_h1  + 4915200;       // also tmpS (s path) during stage1/2
  size_t o_a2m  = o_a1m + 4194304;

  if (ws_size < off * sizeof(float)) {
    (void)hipMemsetAsync(d_out, 0x7F, (size_t)out_size * sizeof(float), stream);
    return;
  }

  // 0) stage packed weights
  k_stage<<<(2306400 + 255) / 256, 256, 0, stream>>>(
      wq, wk, bq, bk, w_ih_f, w_ih_b, aff1, aff2,
      ws0, wa0, ws1, wa1, bs0, ba0, bs1, ba1,
      W + o_wqk, W + o_bqk, W + o_wih, W + o_aff, W + o_wsa, W + o_bsa);

  // 1) embeddings -> [t*16+b][360]
  k_embed<<<(L_ * B_ * 360 + 255) / 256, 256, 0, stream>>>(tok, pos, post, emb_w, pos_w, post_w, W + o_embs);

  // 2) pre-GEMMs batched (z=2): preT[j][t*16+b] = w_ih[j] . embs
  gemm(stream, true, W + o_wih, 360, 432000, 0, W + o_embs, 360, 0, 0,
       W + o_pref, nullptr, 8192, 9830400, 0, nullptr, 0, nullptr, 1.f, 0, 1200, 8192, 360, 2, 1);

  // 3) BiLSTM: 76 sharded blocks, u64 tagged-word sync, 512 threads
  k_lstm<<<2 * NCH, 512, 0, stream>>>(W + o_pref, W + o_preb, w_hh_f, w_hh_b,
                                      b_ih_f, b_hh_f, b_ih_b, b_hh_b,
                                      W + o_gcn, (u64*)(W + o_hg));

  // 4) q/k batched (z=2)
  gemm(stream, true, W + o_gcn, DM_, 0, 0, W + o_wqk, DM_, 360000, 0,
       W + o_q, nullptr, DM_, (long)(o_k - o_q), 0, W + o_bqk, 600, nullptr,
       1.f, 0, 8192, DM_, DM_, 2, 1);

  // 5) aspect structure
  k_asplist<<<1, 64, 0, stream>>>(asp_mask, (int*)(W + o_apos), (int*)(W + o_acnt));
  k_t0<<<(600 + 255) / 256, 256, 0, stream>>>(bd, wm, W + o_t0);
  k_aspd<<<(B_ * MAXA * DK_ + 255) / 256, 256, 0, stream>>>(W + o_gcn, asp_mask,
      (const int*)(W + o_apos), (const int*)(W + o_acnt), wd, bd, W + o_aspd);
  k_tasp<<<(B_ * 8 * MAXA * DK_ + 255) / 256, 256, 0, stream>>>(W + o_aspd,
      (const int*)(W + o_acnt), wm, W + o_tasp);
  k_avg<<<(B_ * 8 * L_ + 255) / 256, 256, 0, stream>>>(W + o_k, W + o_t0, W + o_tasp,
      (const int*)(W + o_acnt), bias_m, W + o_s0, W + o_avg);
  k_bar<<<(B_ * L_ + 255) / 256, 256, 0, stream>>>(W + o_s0, W + o_avg, W + o_s0bar, W + o_avbar);

  // 6) scores (bf16) -> fused adj_s ; adj_ag
  gemm(stream, true, W + o_q, DM_, (long)L_ * DM_, DK_, W + o_k, DM_, (long)L_ * DM_, DK_,
       nullptr, (bf16*)(W + o_sc), L_, (long)8 * L_ * L_, (long)L_ * L_,
       nullptr, 0, nullptr, 0.1154700538f, 0, L_, L_, DK_, B_, 8);
  k_adjs2<<<B_ * L_, 256, 0, stream>>>((const bf16*)(W + o_sc), tok, W + o_adjs, W + o_dens);
  k_adjag<<<B_ * L_, 256, 0, stream>>>(asp_mask, adjr, W + o_s0bar, W + o_avbar,
                                       W + o_adjag, W + o_denag);

  // 7) two GCN layers
  const float* inBase;
  long inStride;
  const long tmpStride = (long)o_tmp - (long)o_a1m;   // tmpS at o_a1m, tmpA at o_tmp
  int D = DM_;
  for (int layer = 0; layer < 2; ++layer) {
    if (layer == 0) { inBase = W + o_gcn; inStride = 0; }
    else            { inBase = W + o_os1; inStride = (long)o_oag1 - (long)o_os1; }
    // stage1 batched z=32 (b1: 0=s path, 1=ag path; b2=batch): tmp = adj @ in
    gemm(stream, false,
         W + o_adjs, L_, (long)o_adjag - (long)o_adjs, (long)L_ * L_,
         inBase, D, inStride, (long)L_ * D,
         W + o_a1m, nullptr, D, tmpStride, (long)L_ * D,
         nullptr, 0, nullptr, 1.f, 0, L_, D, L_, 2, B_);
    // stage2 batched z=2: g = relu((tmp @ w^T + b) / denom)
    gemm(stream, true,
         W + o_a1m, D, tmpStride, 0,
         W + o_wsa + (layer ? 360000 : 0), D, (layer ? 90000 : 180000), 0,
         W + o_gs, nullptr, 300, (long)o_gag - (long)o_gs, 0,
         W + o_bsa + (layer ? 600 : 0), 300, W + o_dens,
         1.f, 1, 8192, 300, D, 2, 1);
    // affine batched (z=2): h1 = gag@aff1 ; h1b = gs@aff2
    gemm(stream, false, W + o_gag, 300, (long)(o_gs - o_gag), 0, W + o_aff, 300, 90000, 0,
         W + o_h1, nullptr, 300, 2457600, 0, nullptr, 0, nullptr, 1.f, 0, 8192, 300, 300, 2, 1);
    // A1/A2 batched (z=2x16): a1m = h1 @ gs^T ; a2m = h1b @ gag^T
    gemm(stream, true, W + o_h1, 300, 2457600, (long)L_ * 300,
         W + o_gs, 300, (long)o_gag - (long)o_gs, (long)L_ * 300,
         W + o_a1m, nullptr, L_, 4194304, (long)L_ * L_,
         nullptr, 0, nullptr, 1.f, 0, L_, L_, 300, 2, B_);
    k_softmax<<<2 * B_ * L_, 256, 0, stream>>>(W + o_a1m);
    // out batched (z=2x16): out_ag = A1 @ gs ; out_s = A2 @ gag
    float* dstC; int ldcO; long sC1o, sC2o;
    if (layer == 0) { dstC = W + o_oag1; ldcO = 300; sC1o = (long)(o_os1 - o_oag1); sC2o = (long)L_ * 300; }
    else            { dstC = out;        ldcO = 600; sC1o = 300;                    sC2o = (long)L_ * 600; }
    gemm(stream, false, W + o_a1m, L_, 4194304, (long)L_ * L_,
         W + o_gs, 300, (long)o_gag - (long)o_gs, (long)L_ * 300,
         dstC, nullptr, ldcO, sC1o, sC2o,
         nullptr, 0, nullptr, 1.f, 0, L_, 300, L_, 2, B_);
    D = 300;
  }
}

// Round 14
// 2514.592 us; speedup vs baseline: 1.4570x; 1.1050x over previous
//
#include <hip/hip_runtime.h>
#include <hip/hip_bf16.h>

typedef __hip_bfloat16 bf16;
typedef __attribute__((ext_vector_type(4))) short short4v;
typedef __attribute__((ext_vector_type(8))) short short8v;
typedef __attribute__((ext_vector_type(4))) float f32x4;
typedef unsigned long long u64;

#define B_   16
#define L_   512
#define HR   300
#define DM_  600
#define DK_  75
#define MAXA 8
#define NCH  75            // u-chunks per dir (75*4 = 300)

// ---------------------------------------------------------------- embed
// embs layout: [seq = t*16 + b][360]
__global__ __launch_bounds__(256) void k_embed(
    const int* __restrict__ tok, const int* __restrict__ pos, const int* __restrict__ post,
    const float* __restrict__ emb_w, const float* __restrict__ pos_w, const float* __restrict__ post_w,
    float* __restrict__ embs)
{
  int idx = blockIdx.x * 256 + threadIdx.x;
  if (idx >= L_ * B_ * 360) return;
  int d = idx % 360;
  int seq = idx / 360;
  int b = seq & 15, t = seq >> 4;
  int si = b * L_ + t;
  float v;
  if (d < 300)       v = emb_w[(long)tok[si] * 300 + d];
  else if (d < 330)  v = pos_w[pos[si] * 30 + (d - 300)];
  else               v = post_w[post[si] * 30 + (d - 330)];
  embs[idx] = v;
}

// ---------------------------------------------------------------- weight staging (one launch)
// dst: wqk[720000] | bqk[1200] | wih[864000] | aff[180000] | wsa[540000] | bsa[1200]
__global__ __launch_bounds__(256) void k_stage(
    const float* __restrict__ wq, const float* __restrict__ wk,
    const float* __restrict__ bq, const float* __restrict__ bk,
    const float* __restrict__ wihf, const float* __restrict__ wihb,
    const float* __restrict__ aff1, const float* __restrict__ aff2,
    const float* __restrict__ ws0, const float* __restrict__ wa0,
    const float* __restrict__ ws1, const float* __restrict__ wa1,
    const float* __restrict__ bs0, const float* __restrict__ ba0,
    const float* __restrict__ bs1, const float* __restrict__ ba1,
    float* __restrict__ wqk, float* __restrict__ bqk,
    float* __restrict__ wih, float* __restrict__ aff,
    float* __restrict__ wsa, float* __restrict__ bsa)
{
  int i = blockIdx.x * 256 + threadIdx.x;
  if (i < 360000) wqk[i] = wq[i];
  else if (i < 720000) wqk[i] = wk[i - 360000];
  else if (i < 720600) bqk[i - 720000] = bq[i - 720000];
  else if (i < 721200) bqk[i - 720000] = bk[i - 720600];
  else if (i < 1153200) wih[i - 721200] = wihf[i - 721200];
  else if (i < 1585200) wih[i - 721200] = wihb[i - 1153200];
  else if (i < 1675200) aff[i - 1585200] = aff1[i - 1585200];
  else if (i < 1765200) aff[i - 1585200] = aff2[i - 1675200];
  else if (i < 1945200) wsa[i - 1765200] = ws0[i - 1765200];
  else if (i < 2125200) wsa[i - 1765200] = wa0[i - 1945200];
  else if (i < 2215200) wsa[i - 1765200] = ws1[i - 2125200];
  else if (i < 2305200) wsa[i - 1765200] = wa1[i - 2215200];
  else if (i < 2305500) bsa[i - 2305200] = bs0[i - 2305200];
  else if (i < 2305800) bsa[i - 2305200] = ba0[i - 2305500];
  else if (i < 2306100) bsa[i - 2305200] = bs1[i - 2305800];
  else if (i < 2306400) bsa[i - 2305200] = ba1[i - 2306100];
}

// ---------------------------------------------------------------- MFMA GEMM (bf16x3 split), 128x64 tile
__device__ inline short2 splitf(float x) {
  unsigned u = __float_as_uint(x);
  unsigned hb = u & 0xffff0000u;
  float r = x - __uint_as_float(hb);
  unsigned lb = __float_as_uint(r);
  short2 out;
  out.x = (short)(hb >> 16);
  out.y = (short)(lb >> 16);
  return out;
}

__device__ inline short8v ld_frag(const short* p) {
  short4v a = *reinterpret_cast<const short4v*>(p);
  short4v b = *reinterpret_cast<const short4v*>(p + 16);
  short8v r;
  r[0]=a[0]; r[1]=a[1]; r[2]=a[2]; r[3]=a[3];
  r[4]=b[0]; r[5]=b[1]; r[6]=b[2]; r[7]=b[3];
  return r;
}

#define LDA_ 36   // row stride in shorts (32 + 4 pad)

template<bool NT>
__global__ __launch_bounds__(256) void k_mgemm(
    const float* __restrict__ A, int lda, long sA1, long sA2,
    const float* __restrict__ Bm, int ldb, long sB1, long sB2,
    float* __restrict__ C, bf16* __restrict__ Cbf, int ldc, long sC1, long sC2,
    const float* __restrict__ bias, long sBias,
    const float* __restrict__ rowdiv,
    float alpha, int relu, int M, int N, int K, int nb2)
{
  __shared__ short Ah[128 * LDA_], Al[128 * LDA_], Bh[64 * LDA_], Bl[64 * LDA_];
  const int tid = threadIdx.x;
  const int w = tid >> 6, l = tid & 63;
  const int z = blockIdx.z;
  const int b1 = z / nb2, b2 = z - b1 * nb2;
  const float* Ab = A + b1 * sA1 + b2 * sA2;
  const float* Bb = Bm + b1 * sB1 + b2 * sB2;
  const int row0 = blockIdx.y * 128, col0 = blockIdx.x * 64;

  f32x4 acc[2][4];
#pragma unroll
  for (int f = 0; f < 2; ++f)
#pragma unroll
    for (int c = 0; c < 4; ++c) acc[f][c] = (f32x4){0.f, 0.f, 0.f, 0.f};

  const int lrow = l & 15, lk = (l >> 4) * 4;

  for (int k0 = 0; k0 < K; k0 += 32) {
#pragma unroll
    for (int j = 0; j < 4; ++j) {
      int slot = j * 256 + tid;
      int r = slot >> 3, kq = slot & 7;
      int gr = row0 + r, gk = k0 + kq * 4;
      float v[4] = {0.f, 0.f, 0.f, 0.f};
      if (gr < M) {
        if (gk + 3 < K) {
          float4 t = *reinterpret_cast<const float4*>(Ab + (long)gr * lda + gk);
          v[0] = t.x; v[1] = t.y; v[2] = t.z; v[3] = t.w;
        } else {
#pragma unroll
          for (int q = 0; q < 4; ++q) if (gk + q < K) v[q] = Ab[(long)gr * lda + gk + q];
        }
      }
      short4v hv, lv;
#pragma unroll
      for (int q = 0; q < 4; ++q) {
        short2 t2 = splitf(v[q]);
        hv[q] = t2.x; lv[q] = t2.y;
      }
      *reinterpret_cast<short4v*>(&Ah[r * LDA_ + kq * 4]) = hv;
      *reinterpret_cast<short4v*>(&Al[r * LDA_ + kq * 4]) = lv;
    }
    if (NT) {
#pragma unroll
      for (int j = 0; j < 2; ++j) {
        int slot = j * 256 + tid;
        int r = slot >> 3, kq = slot & 7;
        int gc = col0 + r, gk = k0 + kq * 4;
        float v[4] = {0.f, 0.f, 0.f, 0.f};
        if (gc < N) {
          if (gk + 3 < K) {
            float4 t = *reinterpret_cast<const float4*>(Bb + (long)gc * ldb + gk);
            v[0] = t.x; v[1] = t.y; v[2] = t.z; v[3] = t.w;
          } else {
#pragma unroll
            for (int q = 0; q < 4; ++q) if (gk + q < K) v[q] = Bb[(long)gc * ldb + gk + q];
          }
        }
        short4v hv, lv;
#pragma unroll
        for (int q = 0; q < 4; ++q) {
          short2 t2 = splitf(v[q]);
          hv[q] = t2.x; lv[q] = t2.y;
        }
        *reinterpret_cast<short4v*>(&Bh[r * LDA_ + kq * 4]) = hv;
        *reinterpret_cast<short4v*>(&Bl[r * LDA_ + kq * 4]) = lv;
      }
    } else {
#pragma unroll
      for (int j = 0; j < 2; ++j) {
        int slot = j * 256 + tid;
        int kk = slot >> 4, nq = slot & 15;
        int gk = k0 + kk, gn = col0 + nq * 4;
        float v[4] = {0.f, 0.f, 0.f, 0.f};
        if (gk < K) {
          if (gn + 3 < N) {
            float4 t = *reinterpret_cast<const float4*>(Bb + (long)gk * ldb + gn);
            v[0] = t.x; v[1] = t.y; v[2] = t.z; v[3] = t.w;
          } else {
#pragma unroll
            for (int q = 0; q < 4; ++q) if (gn + q < N) v[q] = Bb[(long)gk * ldb + gn + q];
          }
        }
#pragma unroll
        for (int q = 0; q < 4; ++q) {
          short2 t2 = splitf(v[q]);
          Bh[(nq * 4 + q) * LDA_ + kk] = t2.x;
          Bl[(nq * 4 + q) * LDA_ + kk] = t2.y;
        }
      }
    }
    __syncthreads();

    short8v ah[2], al[2];
#pragma unroll
    for (int f = 0; f < 2; ++f) {
      int ar = w * 32 + f * 16 + lrow;
      ah[f] = ld_frag(&Ah[ar * LDA_ + lk]);
      al[f] = ld_frag(&Al[ar * LDA_ + lk]);
    }
#pragma unroll
    for (int c = 0; c < 4; ++c) {
      short8v bh = ld_frag(&Bh[(c * 16 + lrow) * LDA_ + lk]);
      short8v bl = ld_frag(&Bl[(c * 16 + lrow) * LDA_ + lk]);
#pragma unroll
      for (int f = 0; f < 2; ++f) {
        acc[f][c] = __builtin_amdgcn_mfma_f32_16x16x32_bf16(ah[f], bh, acc[f][c], 0, 0, 0);
        acc[f][c] = __builtin_amdgcn_mfma_f32_16x16x32_bf16(ah[f], bl, acc[f][c], 0, 0, 0);
        acc[f][c] = __builtin_amdgcn_mfma_f32_16x16x32_bf16(al[f], bh, acc[f][c], 0, 0, 0);
      }
    }
    __syncthreads();
  }

  float* Cb = C ? C + b1 * sC1 + b2 * sC2 : (float*)0;
  bf16*  Cf = Cbf ? Cbf + b1 * sC1 + b2 * sC2 : (bf16*)0;
#pragma unroll
  for (int f = 0; f < 2; ++f)
#pragma unroll
  for (int c = 0; c < 4; ++c) {
    int cc = col0 + c * 16 + lrow;
    if (cc >= N) continue;
#pragma unroll
    for (int reg = 0; reg < 4; ++reg) {
      int r = row0 + w * 32 + f * 16 + (l >> 4) * 4 + reg;
      if (r >= M) continue;
      float v = acc[f][c][reg] * alpha;
      if (bias) v += bias[b1 * sBias + cc];
      if (rowdiv) v /= rowdiv[(long)z * M + r];
      if (relu) v = fmaxf(v, 0.f);
      if (Cf) Cf[(long)r * ldc + cc] = __float2bfloat16(v);
      else    Cb[(long)r * ldc + cc] = v;
    }
  }
}

// ---------------------------------------------------------------- BiLSTM (u64 tagged-word sync, 150 blocks x 512 threads)
// Block owns 4 units (16 gate-rows). Matvec: tid = kc*16 + rq, one row per
// thread x 10 k-chunk. Reduce: pairs (t, t^1) split kc range, __shfl_xor
// combine. Activation: 32 threads x 2 batch-pairs.
__global__ __launch_bounds__(512, 1) void k_lstm(
    const float* __restrict__ preT_f, const float* __restrict__ preT_b,
    const float* __restrict__ whh_f, const float* __restrict__ whh_b,
    const float* __restrict__ bih_f, const float* __restrict__ bhh_f,
    const float* __restrict__ bih_b, const float* __restrict__ bhh_b,
    float* __restrict__ gcn, u64* __restrict__ hg)
{
  const int tid = threadIdx.x;
  const int dir = blockIdx.x / NCH;
  const int blk = blockIdx.x - dir * NCH;
  const int u0 = blk * 4;
  const float* pre = dir ? preT_b : preT_f;
  const float* whh = dir ? whh_b : whh_f;
  const float* bih = dir ? bih_b : bih_f;
  const float* bhh = dir ? bhh_b : bhh_f;
  u64* hgd = hg + dir * 2400;                   // + buf*4800

  __shared__ float4 h5[1200];                   // h[k][b] linear
  __shared__ float part[32 * 273 + 16];         // [kc][lr pad17][b]
  __shared__ float g_lds[256];
  float* h5f = reinterpret_cast<float*>(h5);

  const int kc = tid >> 4;                      // 0..31
  const int rq = tid & 15;                      // 0..15 (one gate-row)
  const int kl = (kc < 12) ? 10 : 9;
  const int k0 = kc * 9 + min(kc, 12);

  float wreg[10];
  {
    int gate = rq >> 2, unit = rq & 3;
    int grow = gate * HR + u0 + unit;
#pragma unroll
    for (int kk = 0; kk < 10; ++kk) {
      int k = min(k0 + kk, 299);
      float wv = whh[(long)grow * HR + k];
      wreg[kk] = (kk < kl) ? wv : 0.f;
    }
  }

  // reduce role: element e0 = tid>>1, half = tid&1
  const int e0 = tid >> 1;                      // 0..255
  const int half = tid & 1;
  const int lr0 = e0 >> 4, b0 = e0 & 15;
  const int gate0 = lr0 >> 2, unit0 = lr0 & 3;
  const int grow0 = gate0 * HR + u0 + unit0;
  const float breg = bih[grow0] + bhh[grow0];
  const float* prebase = pre + (long)grow0 * 8192;

  // activation role (tid < 32): unit au = tid>>3, batch-pair abp = tid&7
  const int au = tid >> 3, abp = tid & 7;
  float c_reg0 = 0.f, c_reg1 = 0.f;

  const int own_lo = u0 * 8, own_hi = (u0 + 4) * 8;   // u64-index space

#pragma unroll 1
  for (int s = 0; s < L_; ++s) {
    const int tf = dir ? (L_ - 1 - s) : s;

    float p0 = prebase[tf * 16 + b0];

    if (s > 0) {
      u64* srcb = hgd + (s & 1) * 4800;
      const u64 tag = (u64)s;
      u64 vals[5];
      int idxs[5];
#pragma unroll
      for (int j = 0; j < 5; ++j) {
        int idx = tid + j * 512;
        bool act = (idx < 2400) && (idx < own_lo || idx >= own_hi);
        idxs[j] = act ? idx : -1;
        vals[j] = act ? __hip_atomic_load(&srcb[idx], __ATOMIC_RELAXED, __HIP_MEMORY_SCOPE_AGENT)
                      : (tag << 32);
      }
      for (;;) {
        bool ok = true;
#pragma unroll
        for (int j = 0; j < 5; ++j)
          if ((vals[j] >> 32) != tag) ok = false;
        if (ok) break;
#pragma unroll
        for (int j = 0; j < 5; ++j)
          if ((vals[j] >> 32) != tag)
            vals[j] = __hip_atomic_load(&srcb[idxs[j]], __ATOMIC_RELAXED, __HIP_MEMORY_SCOPE_AGENT);
      }
#pragma unroll
      for (int j = 0; j < 5; ++j) {
        int idx = idxs[j];
        if (idx >= 0) {
          unsigned lo = (unsigned)(vals[j] & 0xffffffffu);
          unsigned short be = (unsigned short)(lo & 0xffffu);
          unsigned short bo = (unsigned short)(lo >> 16);
          bf16 he = *reinterpret_cast<bf16*>(&be);
          bf16 ho = *reinterpret_cast<bf16*>(&bo);
          int u = idx >> 3, bp = idx & 7;
          h5f[u * 16 + bp * 2]     = __bfloat162float(he);
          h5f[u * 16 + bp * 2 + 1] = __bfloat162float(ho);
        }
      }
    }
    __syncthreads();

    if (s > 0) {
      float4 acc[4];
#pragma unroll
      for (int q = 0; q < 4; ++q) acc[q] = make_float4(0.f, 0.f, 0.f, 0.f);
#pragma unroll
      for (int kk = 0; kk < 10; ++kk) {
        if (kk < kl) {
          int k = k0 + kk;
          float4 hb0 = h5[k * 4 + 0];
          float4 hb1 = h5[k * 4 + 1];
          float4 hb2 = h5[k * 4 + 2];
          float4 hb3 = h5[k * 4 + 3];
          float w = wreg[kk];
          acc[0].x = fmaf(w, hb0.x, acc[0].x); acc[0].y = fmaf(w, hb0.y, acc[0].y);
          acc[0].z = fmaf(w, hb0.z, acc[0].z); acc[0].w = fmaf(w, hb0.w, acc[0].w);
          acc[1].x = fmaf(w, hb1.x, acc[1].x); acc[1].y = fmaf(w, hb1.y, acc[1].y);
          acc[1].z = fmaf(w, hb1.z, acc[1].z); acc[1].w = fmaf(w, hb1.w, acc[1].w);
          acc[2].x = fmaf(w, hb2.x, acc[2].x); acc[2].y = fmaf(w, hb2.y, acc[2].y);
          acc[2].z = fmaf(w, hb2.z, acc[2].z); acc[2].w = fmaf(w, hb2.w, acc[2].w);
          acc[3].x = fmaf(w, hb3.x, acc[3].x); acc[3].y = fmaf(w, hb3.y, acc[3].y);
          acc[3].w = fmaf(w, hb3.w, acc[3].w); acc[3].z = fmaf(w, hb3.z, acc[3].z);
        }
      }
      float* pb = part + kc * 273 + rq * 17;
#pragma unroll
      for (int q = 0; q < 4; ++q) {
        pb[q * 4 + 0] = acc[q].x; pb[q * 4 + 1] = acc[q].y;
        pb[q * 4 + 2] = acc[q].z; pb[q * 4 + 3] = acc[q].w;
      }
    }
    __syncthreads();

    float sum = 0.f;
    if (s > 0) {
      const float* pb = part + half * 16 * 273 + lr0 * 17 + b0;
#pragma unroll
      for (int q = 0; q < 16; ++q) sum += pb[q * 273];
    }
    float other = __shfl_xor(sum, 1);
    if (half == 0) g_lds[e0] = p0 + breg + sum + other;
    __syncthreads();

    if (tid < 32) {
      int be = abp * 2, bo = abp * 2 + 1;
      float gi0 = g_lds[(0 * 4 + au) * 16 + be];
      float gf0 = g_lds[(1 * 4 + au) * 16 + be];
      float gg0 = g_lds[(2 * 4 + au) * 16 + be];
      float go0 = g_lds[(3 * 4 + au) * 16 + be];
      float gi1 = g_lds[(0 * 4 + au) * 16 + bo];
      float gf1 = g_lds[(1 * 4 + au) * 16 + bo];
      float gg1 = g_lds[(2 * 4 + au) * 16 + bo];
      float go1 = g_lds[(3 * 4 + au) * 16 + bo];
      float si0 = 1.f / (1.f + __expf(-gi0));
      float sf0 = 1.f / (1.f + __expf(-gf0));
      float so0 = 1.f / (1.f + __expf(-go0));
      float tg0 = tanhf(gg0);
      float si1 = 1.f / (1.f + __expf(-gi1));
      float sf1 = 1.f / (1.f + __expf(-gf1));
      float so1 = 1.f / (1.f + __expf(-go1));
      float tg1 = tanhf(gg1);
      c_reg0 = sf0 * c_reg0 + si0 * tg0;
      c_reg1 = sf1 * c_reg1 + si1 * tg1;
      float h0 = so0 * tanhf(c_reg0);
      float h1 = so1 * tanhf(c_reg1);
      h5f[(u0 + au) * 16 + be] = h0;
      h5f[(u0 + au) * 16 + bo] = h1;
      bf16 hbe = __float2bfloat16(h0);
      bf16 hbo = __float2bfloat16(h1);
      unsigned bitse = *reinterpret_cast<unsigned short*>(&hbe);
      unsigned bitso = *reinterpret_cast<unsigned short*>(&hbo);
      u64 val = ((u64)(s + 1) << 32) | ((u64)bitso << 16) | (u64)bitse;
      __hip_atomic_store(&hgd[((s + 1) & 1) * 4800 + (u0 + au) * 8 + abp], val,
                         __ATOMIC_RELAXED, __HIP_MEMORY_SCOPE_AGENT);
      gcn[((long)be * L_ + tf) * DM_ + dir * HR + u0 + au] = h0;
      gcn[((long)bo * L_ + tf) * DM_ + dir * HR + u0 + au] = h1;
    }
  }
}

// ---------------------------------------------------------------- small aspect kernels
__global__ void k_asplist(const float* __restrict__ asp_mask, int* __restrict__ apos, int* __restrict__ acnt)
{
  int b = threadIdx.x;
  if (b >= B_) return;
  int c = 0;
  for (int l = 0; l < L_; ++l)
    if (asp_mask[b * L_ + l] > 0.f) { if (c < MAXA) apos[b * MAXA + c] = l; ++c; }
  acnt[b] = (c < MAXA) ? c : MAXA;
}

__global__ void k_t0(const float* __restrict__ bd, const float* __restrict__ wm, float* __restrict__ t0)
{
  int i = blockIdx.x * 256 + threadIdx.x;
  if (i >= 8 * DK_) return;
  int h = i / DK_, e = i % DK_;
  float s = 0.f;
  for (int d = 0; d < DK_; ++d) s += bd[d] * wm[(h * DK_ + d) * DK_ + e];
  t0[i] = s;
}

__global__ void k_aspd(const float* __restrict__ gcn, const float* __restrict__ asp_mask,
                       const int* __restrict__ apos, const int* __restrict__ acnt,
                       const float* __restrict__ wd, const float* __restrict__ bd, float* __restrict__ aspd)
{
  int i = blockIdx.x * 256 + threadIdx.x;
  if (i >= B_ * MAXA * DK_) return;
  int d = i % DK_;
  int ba = i / DK_;
  int a = ba % MAXA, b = ba / MAXA;
  if (a >= acnt[b]) { aspd[i] = 0.f; return; }
  int p = apos[b * MAXA + a];
  float mv = asp_mask[b * L_ + p];
  const float* row = gcn + ((long)b * L_ + p) * DM_;
  float s = 0.f;
  for (int k = 0; k < DM_; ++k) s += row[k] * wd[d * DM_ + k];
  aspd[i] = s * mv + bd[d];
}

__global__ void k_tasp(const float* __restrict__ aspd, const int* __restrict__ acnt,
                       const float* __restrict__ wm, float* __restrict__ tasp)
{
  int i = blockIdx.x * 256 + threadIdx.x;
  if (i >= B_ * 8 * MAXA * DK_) return;
  int e = i % DK_;
  int t3 = i / DK_;
  int a = t3 % MAXA;
  int t4 = t3 / MAXA;
  int h = t4 % 8, b = t4 / 8;
  if (a >= acnt[b]) { tasp[i] = 0.f; return; }
  const float* ar = aspd + (b * MAXA + a) * DK_;
  float s = 0.f;
  for (int d = 0; d < DK_; ++d) s += ar[d] * wm[(h * DK_ + d) * DK_ + e];
  tasp[i] = s;
}

__global__ void k_avg(const float* __restrict__ k_lin, const float* __restrict__ t0,
                      const float* __restrict__ tasp, const int* __restrict__ acnt,
                      const float* __restrict__ bias_m, float* __restrict__ s0, float* __restrict__ avg)
{
  int i = blockIdx.x * 256 + threadIdx.x;
  if (i >= B_ * 8 * L_) return;
  int m = i % L_;
  int bh = i / L_;
  int h = bh % 8, b = bh / 8;
  const float* kr = k_lin + ((long)b * L_ + m) * DM_ + h * DK_;
  float bm = bias_m[0];
  const float* t0r = t0 + h * DK_;
  float d0 = 0.f;
  for (int e = 0; e < DK_; ++e) d0 += t0r[e] * kr[e];
  float sv = tanhf(d0 + bm);
  int cnt = acnt[b];
  float acc = (float)(L_ - cnt) * sv;
  for (int a = 0; a < cnt; ++a) {
    const float* tr = tasp + (((b * 8 + h) * MAXA) + a) * DK_;
    float dd = 0.f;
    for (int e = 0; e < DK_; ++e) dd += tr[e] * kr[e];
    acc += tanhf(dd + bm);
  }
  s0[i] = sv;
  avg[i] = acc * (1.f / (float)L_);
}

__global__ void k_bar(const float* __restrict__ s0, const float* __restrict__ avg,
                      float* __restrict__ s0bar, float* __restrict__ avbar)
{
  int i = blockIdx.x * 256 + threadIdx.x;
  if (i >= B_ * L_) return;
  int m = i % L_, b = i / L_;
  float sa = 0.f, aa = 0.f;
  for (int h = 0; h < 8; ++h) { sa += s0[(b * 8 + h) * L_ + m]; aa += avg[(b * 8 + h) * L_ + m]; }
  s0bar[i] = sa * 0.125f;
  avbar[i] = aa * 0.125f;
}

__global__ __launch_bounds__(256) void k_adjag(
    const float* __restrict__ asp_mask, const float* __restrict__ adjr,
    const float* __restrict__ s0bar, const float* __restrict__ avbar,
    float* __restrict__ adjag, float* __restrict__ denag)
{
  int bl = blockIdx.x;
  int b = bl >> 9, l = bl & 511;
  bool rA = asp_mask[b * L_ + l] > 0.f;
  float avl = avbar[b * L_ + l];
  float lsum = 0.f;
  for (int q = 0; q < 2; ++q) {
    int m = threadIdx.x + q * 256;
    bool cA = asp_mask[b * L_ + m] > 0.f;
    float asv;
    if (cA && (!rA || m > l)) asv = avl;
    else if (rA)              asv = avbar[b * L_ + m];
    else                      asv = s0bar[b * L_ + m];
    float r = (asv > 0.9f) ? 1.f : __expf(0.8f * adjr[((long)b * L_ + l) * L_ + m]);
    float v = r * asv;
    adjag[((long)b * L_ + l) * L_ + m] = v;
    lsum += v;
  }
  __shared__ float red[256];
  red[threadIdx.x] = lsum;
  __syncthreads();
  for (int st = 128; st > 0; st >>= 1) {
    if (threadIdx.x < st) red[threadIdx.x] += red[threadIdx.x + st];
    __syncthreads();
  }
  if (threadIdx.x == 0) denag[bl] = red[0] + 1.f;
}

// fused stats + head-mean softmax + diag/mask + denom; one block per (b,l)
__global__ __launch_bounds__(256) void k_adjs2(
    const bf16* __restrict__ sc, const int* __restrict__ tok,
    float* __restrict__ adjs, float* __restrict__ dens)
{
  int bl = blockIdx.x;
  int b = bl >> 9, l = bl & 511;
  int tid = threadIdx.x;
  __shared__ float srow[8][512];
  __shared__ float stats[16];    // mx[0..7], inv[8..15]
  __shared__ float red[256];

  int t0v = tok[b * L_ + tid], t1v = tok[b * L_ + tid + 256];
#pragma unroll
  for (int h = 0; h < 8; ++h) {
    const bf16* p = sc + ((long)((b * 8 + h) * L_) + l) * L_;
    float v0 = __bfloat162float(p[tid]);
    float v1 = __bfloat162float(p[tid + 256]);
    srow[h][tid]       = (t0v != 0) ? v0 : -1e9f;
    srow[h][tid + 256] = (t1v != 0) ? v1 : -1e9f;
  }
  __syncthreads();

  int wv = tid >> 6, lane = tid & 63;
#pragma unroll
  for (int hh = 0; hh < 2; ++hh) {
    int h = wv * 2 + hh;
    float vv[8];
#pragma unroll
    for (int i = 0; i < 8; ++i) vv[i] = srow[h][lane + i * 64];
    float m = vv[0];
#pragma unroll
    for (int i = 1; i < 8; ++i) m = fmaxf(m, vv[i]);
    for (int off = 32; off > 0; off >>= 1) m = fmaxf(m, __shfl_xor(m, off));
    float s = 0.f;
#pragma unroll
    for (int i = 0; i < 8; ++i) s += __expf(vv[i] - m);
    for (int off = 32; off > 0; off >>= 1) s += __shfl_xor(s, off);
    if (lane == 0) { stats[h] = m; stats[8 + h] = 1.f / s; }
  }
  __syncthreads();

  float acc0 = 0.f, acc1 = 0.f;
#pragma unroll
  for (int h = 0; h < 8; ++h) {
    float m = stats[h], inv = stats[8 + h];
    acc0 += __expf(srow[h][tid] - m) * inv;
    acc1 += __expf(srow[h][tid + 256] - m) * inv;
  }
  float rmask = (tok[b * L_ + l] != 0) ? 1.f : 0.f;
  float lsum = 0.f;
  {
    int m = tid;
    float v = acc0 * 0.125f;
    v = (m == l) ? 1.f : v;
    v *= rmask;
    adjs[(long)bl * L_ + m] = v;
    lsum += v;
  }
  {
    int m = tid + 256;
    float v = acc1 * 0.125f;
    v = (m == l) ? 1.f : v;
    v *= rmask;
    adjs[(long)bl * L_ + m] = v;
    lsum += v;
  }
  red[tid] = lsum;
  __syncthreads();
  for (int st = 128; st > 0; st >>= 1) {
    if (tid < st) red[tid] += red[tid + st];
    __syncthreads();
  }
  if (tid == 0) dens[bl] = red[0] + 1.f;
}

__global__ __launch_bounds__(256) void k_softmax(float* __restrict__ X)
{
  long row = blockIdx.x;
  float* p = X + row * L_;
  int tid = threadIdx.x;
  float a = p[tid], b = p[tid + 256];
  __shared__ float red[256];
  red[tid] = fmaxf(a, b);
  __syncthreads();
  for (int st = 128; st > 0; st >>= 1) {
    if (tid < st) red[tid] = fmaxf(red[tid], red[tid + st]);
    __syncthreads();
  }
  float mxv = red[0];
  __syncthreads();
  float ea = __expf(a - mxv), eb = __expf(b - mxv);
  red[tid] = ea + eb;
  __syncthreads();
  for (int st = 128; st > 0; st >>= 1) {
    if (tid < st) red[tid] += red[tid + st];
    __syncthreads();
  }
  float inv = 1.f / red[0];
  p[tid] = ea * inv;
  p[tid + 256] = eb * inv;
}

// ---------------------------------------------------------------- host side
static void gemm(hipStream_t st, bool nt,
                 const float* A, int lda, long sA1, long sA2,
                 const float* Bm, int ldb, long sB1, long sB2,
                 float* C, bf16* Cbf, int ldc, long sC1, long sC2,
                 const float* bias, long sBias, const float* rowdiv,
                 float alpha, int relu, int M, int N, int K, int nb1, int nb2)
{
  dim3 g((N + 63) / 64, (M + 127) / 128, nb1 * nb2);
  if (nt)
    k_mgemm<true><<<g, 256, 0, st>>>(A, lda, sA1, sA2, Bm, ldb, sB1, sB2, C, Cbf, ldc, sC1, sC2,
                                     bias, sBias, rowdiv, alpha, relu, M, N, K, nb2);
  else
    k_mgemm<false><<<g, 256, 0, st>>>(A, lda, sA1, sA2, Bm, ldb, sB1, sB2, C, Cbf, ldc, sC1, sC2,
                                      bias, sBias, rowdiv, alpha, relu, M, N, K, nb2);
}

extern "C" void kernel_launch(void* const* d_in, const int* in_sizes, int n_in,
                              void* d_out, int out_size, void* d_ws, size_t ws_size,
                              hipStream_t stream)
{
  const int*   tok     = (const int*)d_in[0];
  const int*   pos     = (const int*)d_in[1];
  const int*   post    = (const int*)d_in[2];
  const float* asp_mask= (const float*)d_in[3];
  const float* adjr    = (const float*)d_in[5];
  const float* emb_w   = (const float*)d_in[6];
  const float* pos_w   = (const float*)d_in[7];
  const float* post_w  = (const float*)d_in[8];
  const float* w_ih_f  = (const float*)d_in[9];
  const float* w_hh_f  = (const float*)d_in[10];
  const float* b_ih_f  = (const float*)d_in[11];
  const float* b_hh_f  = (const float*)d_in[12];
  const float* w_ih_b  = (const float*)d_in[13];
  const float* w_hh_b  = (const float*)d_in[14];
  const float* b_ih_b  = (const float*)d_in[15];
  const float* b_hh_b  = (const float*)d_in[16];
  const float* wq      = (const float*)d_in[17];
  const float* bq      = (const float*)d_in[18];
  const float* wk      = (const float*)d_in[19];
  const float* bk      = (const float*)d_in[20];
  const float* wd      = (const float*)d_in[21];
  const float* bd      = (const float*)d_in[22];
  const float* wm      = (const float*)d_in[23];
  const float* bias_m  = (const float*)d_in[24];
  const float* wa0     = (const float*)d_in[25];
  const float* ba0     = (const float*)d_in[26];
  const float* wa1     = (const float*)d_in[27];
  const float* ba1     = (const float*)d_in[28];
  const float* ws0     = (const float*)d_in[29];
  const float* bs0     = (const float*)d_in[30];
  const float* ws1     = (const float*)d_in[31];
  const float* bs1     = (const float*)d_in[32];
  const float* aff1    = (const float*)d_in[33];
  const float* aff2    = (const float*)d_in[34];
  float* out = (float*)d_out;
  float* W = (float*)d_ws;

  // ---- workspace layout (float units) ----
  size_t off = 0;
  auto alloc = [&](size_t n) { size_t o = off; off += (n + 63) & ~(size_t)63; return o; };
  size_t o_gcn   = alloc((size_t)8192 * DM_);
  size_t o_q     = alloc((size_t)8192 * DM_);
  size_t o_k     = alloc((size_t)8192 * DM_);
  size_t o_adjs  = alloc((size_t)B_ * L_ * L_);
  size_t o_adjag = alloc((size_t)B_ * L_ * L_);
  size_t o_dens  = alloc(8192);          // dens FIRST, denag at +8192 (stage2 rowdiv z-index)
  size_t o_denag = alloc(8192);
  size_t o_t0    = alloc(600);
  size_t o_apos  = alloc(B_ * MAXA);
  size_t o_acnt  = alloc(64);
  size_t o_aspd  = alloc(B_ * MAXA * DK_);
  size_t o_tasp  = alloc(B_ * 8 * MAXA * DK_);
  size_t o_s0    = alloc(B_ * 8 * L_);
  size_t o_avg   = alloc(B_ * 8 * L_);
  size_t o_s0bar = alloc(B_ * L_);
  size_t o_avbar = alloc(B_ * L_);
  size_t o_hg    = alloc(2 * 2 * 4800);  // u64 tagged-h pairs
  size_t o_wqk   = alloc(720000);
  size_t o_bqk   = alloc(1200);
  size_t o_wih   = alloc(864000);
  size_t o_aff   = alloc(180000);
  size_t o_wsa   = alloc(540000);        // [ws0][wa0][ws1][wa1]
  size_t o_bsa   = alloc(1200);          // [bs0][ba0][bs1][ba1]
  size_t o_oag1  = alloc((size_t)8192 * 300);
  size_t o_os1   = alloc((size_t)8192 * 300);
  size_t o_big   = alloc(23134300);      // union region
  size_t o_embs = o_big;
  size_t o_pref = o_big + 2949120;
  size_t o_preb = o_pref + 9830400;
  size_t o_sc   = o_big;
  size_t o_tmp  = o_big;                 // tmpA (ag path)
  size_t o_gag  = o_big + 4915200;
  size_t o_gs   = o_gag + 2457600;
  size_t o_h1   = o_gs  + 2457600;       // h1b = o_h1 + 2457600
  size_t o_a1m  = o_h1  + 4915200;       // also tmpS (s path) during stage1/2
  size_t o_a2m  = o_a1m + 4194304;

  if (ws_size < off * sizeof(float)) {
    (void)hipMemsetAsync(d_out, 0x7F, (size_t)out_size * sizeof(float), stream);
    return;
  }

  // 0) stage packed weights
  k_stage<<<(2306400 + 255) / 256, 256, 0, stream>>>(
      wq, wk, bq, bk, w_ih_f, w_ih_b, aff1, aff2,
      ws0, wa0, ws1, wa1, bs0, ba0, bs1, ba1,
      W + o_wqk, W + o_bqk, W + o_wih, W + o_aff, W + o_wsa, W + o_bsa);

  // 1) embeddings -> [t*16+b][360]
  k_embed<<<(L_ * B_ * 360 + 255) / 256, 256, 0, stream>>>(tok, pos, post, emb_w, pos_w, post_w, W + o_embs);

  // 2) pre-GEMMs batched (z=2): preT[j][t*16+b] = w_ih[j] . embs
  gemm(stream, true, W + o_wih, 360, 432000, 0, W + o_embs, 360, 0, 0,
       W + o_pref, nullptr, 8192, 9830400, 0, nullptr, 0, nullptr, 1.f, 0, 1200, 8192, 360, 2, 1);

  // 3) BiLSTM: 150 sharded blocks (4 units each), u64 tagged-word sync
  k_lstm<<<2 * NCH, 512, 0, stream>>>(W + o_pref, W + o_preb, w_hh_f, w_hh_b,
                                      b_ih_f, b_hh_f, b_ih_b, b_hh_b,
                                      W + o_gcn, (u64*)(W + o_hg));

  // 4) q/k batched (z=2)
  gemm(stream, true, W + o_gcn, DM_, 0, 0, W + o_wqk, DM_, 360000, 0,
       W + o_q, nullptr, DM_, (long)(o_k - o_q), 0, W + o_bqk, 600, nullptr,
       1.f, 0, 8192, DM_, DM_, 2, 1);

  // 5) aspect structure
  k_asplist<<<1, 64, 0, stream>>>(asp_mask, (int*)(W + o_apos), (int*)(W + o_acnt));
  k_t0<<<(600 + 255) / 256, 256, 0, stream>>>(bd, wm, W + o_t0);
  k_aspd<<<(B_ * MAXA * DK_ + 255) / 256, 256, 0, stream>>>(W + o_gcn, asp_mask,
      (const int*)(W + o_apos), (const int*)(W + o_acnt), wd, bd, W + o_aspd);
  k_tasp<<<(B_ * 8 * MAXA * DK_ + 255) / 256, 256, 0, stream>>>(W + o_aspd,
      (const int*)(W + o_acnt), wm, W + o_tasp);
  k_avg<<<(B_ * 8 * L_ + 255) / 256, 256, 0, stream>>>(W + o_k, W + o_t0, W + o_tasp,
      (const int*)(W + o_acnt), bias_m, W + o_s0, W + o_avg);
  k_bar<<<(B_ * L_ + 255) / 256, 256, 0, stream>>>(W + o_s0, W + o_avg, W + o_s0bar, W + o_avbar);

  // 6) scores (bf16) -> fused adj_s ; adj_ag
  gemm(stream, true, W + o_q, DM_, (long)L_ * DM_, DK_, W + o_k, DM_, (long)L_ * DM_, DK_,
       nullptr, (bf16*)(W + o_sc), L_, (long)8 * L_ * L_, (long)L_ * L_,
       nullptr, 0, nullptr, 0.1154700538f, 0, L_, L_, DK_, B_, 8);
  k_adjs2<<<B_ * L_, 256, 0, stream>>>((const bf16*)(W + o_sc), tok, W + o_adjs, W + o_dens);
  k_adjag<<<B_ * L_, 256, 0, stream>>>(asp_mask, adjr, W + o_s0bar, W + o_avbar,
                                       W + o_adjag, W + o_denag);

  // 7) two GCN layers
  const float* inBase;
  long inStride;
  const long tmpStride = (long)o_tmp - (long)o_a1m;   // tmpS at o_a1m, tmpA at o_tmp
  int D = DM_;
  for (int layer = 0; layer < 2; ++layer) {
    if (layer == 0) { inBase = W + o_gcn; inStride = 0; }
    else            { inBase = W + o_os1; inStride = (long)o_oag1 - (long)o_os1; }
    // stage1 batched z=32 (b1: 0=s path, 1=ag path; b2=batch): tmp = adj @ in
    gemm(stream, false,
         W + o_adjs, L_, (long)o_adjag - (long)o_adjs, (long)L_ * L_,
         inBase, D, inStride, (long)L_ * D,
         W + o_a1m, nullptr, D, tmpStride, (long)L_ * D,
         nullptr, 0, nullptr, 1.f, 0, L_, D, L_, 2, B_);
    // stage2 batched z=2: g = relu((tmp @ w^T + b) / denom)
    gemm(stream, true,
         W + o_a1m, D, tmpStride, 0,
         W + o_wsa + (layer ? 360000 : 0), D, (layer ? 90000 : 180000), 0,
         W + o_gs, nullptr, 300, (long)o_gag - (long)o_gs, 0,
         W + o_bsa + (layer ? 600 : 0), 300, W + o_dens,
         1.f, 1, 8192, 300, D, 2, 1);
    // affine batched (z=2): h1 = gag@aff1 ; h1b = gs@aff2
    gemm(stream, false, W + o_gag, 300, (long)(o_gs - o_gag), 0, W + o_aff, 300, 90000, 0,
         W + o_h1, nullptr, 300, 2457600, 0, nullptr, 0, nullptr, 1.f, 0, 8192, 300, 300, 2, 1);
    // A1/A2 batched (z=2x16): a1m = h1 @ gs^T ; a2m = h1b @ gag^T
    gemm(stream, true, W + o_h1, 300, 2457600, (long)L_ * 300,
         W + o_gs, 300, (long)o_gag - (long)o_gs, (long)L_ * 300,
         W + o_a1m, nullptr, L_, 4194304, (long)L_ * L_,
         nullptr, 0, nullptr, 1.f, 0, L_, L_, 300, 2, B_);
    k_softmax<<<2 * B_ * L_, 256, 0, stream>>>(W + o_a1m);
    // out batched (z=2x16): out_ag = A1 @ gs ; out_s = A2 @ gag
    float* dstC; int ldcO; long sC1o, sC2o;
    if (layer == 0) { dstC = W + o_oag1; ldcO = 300; sC1o = (long)(o_os1 - o_oag1); sC2o = (long)L_ * 300; }
    else            { dstC = out;        ldcO = 600; sC1o = 300;                    sC2o = (long)L_ * 600; }
    gemm(stream, false, W + o_a1m, L_, 4194304, (long)L_ * L_,
         W + o_gs, 300, (long)o_gag - (long)o_gs, (long)L_ * 300,
         dstC, nullptr, ldcO, sC1o, sC2o,
         nullptr, 0, nullptr, 1.f, 0, L_, 300, L_, 2, B_);
    D = 300;
  }
}

// Round 15
// 2414.999 us; speedup vs baseline: 1.5171x; 1.0412x over previous
//
#include <hip/hip_runtime.h>
#include <hip/hip_bf16.h>

typedef __hip_bfloat16 bf16;
typedef __attribute__((ext_vector_type(4))) short short4v;
typedef __attribute__((ext_vector_type(8))) short short8v;
typedef __attribute__((ext_vector_type(4))) float f32x4;
typedef unsigned long long u64;

#define B_   16
#define L_   512
#define HR   300
#define DM_  600
#define DK_  75
#define MAXA 8
#define NCH  75            // u-chunks per dir (75*4 = 300)

// ---------------------------------------------------------------- embed
// embs layout: [seq = t*16 + b][360]
__global__ __launch_bounds__(256) void k_embed(
    const int* __restrict__ tok, const int* __restrict__ pos, const int* __restrict__ post,
    const float* __restrict__ emb_w, const float* __restrict__ pos_w, const float* __restrict__ post_w,
    float* __restrict__ embs)
{
  int idx = blockIdx.x * 256 + threadIdx.x;
  if (idx >= L_ * B_ * 360) return;
  int d = idx % 360;
  int seq = idx / 360;
  int b = seq & 15, t = seq >> 4;
  int si = b * L_ + t;
  float v;
  if (d < 300)       v = emb_w[(long)tok[si] * 300 + d];
  else if (d < 330)  v = pos_w[pos[si] * 30 + (d - 300)];
  else               v = post_w[post[si] * 30 + (d - 330)];
  embs[idx] = v;
}

// ---------------------------------------------------------------- weight staging (one launch)
// dst: wqk[720000] | bqk[1200] | wih[864000] | aff[180000] | wsa[540000] | bsa[1200]
__global__ __launch_bounds__(256) void k_stage(
    const float* __restrict__ wq, const float* __restrict__ wk,
    const float* __restrict__ bq, const float* __restrict__ bk,
    const float* __restrict__ wihf, const float* __restrict__ wihb,
    const float* __restrict__ aff1, const float* __restrict__ aff2,
    const float* __restrict__ ws0, const float* __restrict__ wa0,
    const float* __restrict__ ws1, const float* __restrict__ wa1,
    const float* __restrict__ bs0, const float* __restrict__ ba0,
    const float* __restrict__ bs1, const float* __restrict__ ba1,
    float* __restrict__ wqk, float* __restrict__ bqk,
    float* __restrict__ wih, float* __restrict__ aff,
    float* __restrict__ wsa, float* __restrict__ bsa)
{
  int i = blockIdx.x * 256 + threadIdx.x;
  if (i < 360000) wqk[i] = wq[i];
  else if (i < 720000) wqk[i] = wk[i - 360000];
  else if (i < 720600) bqk[i - 720000] = bq[i - 720000];
  else if (i < 721200) bqk[i - 720000] = bk[i - 720600];
  else if (i < 1153200) wih[i - 721200] = wihf[i - 721200];
  else if (i < 1585200) wih[i - 721200] = wihb[i - 1153200];
  else if (i < 1675200) aff[i - 1585200] = aff1[i - 1585200];
  else if (i < 1765200) aff[i - 1585200] = aff2[i - 1675200];
  else if (i < 1945200) wsa[i - 1765200] = ws0[i - 1765200];
  else if (i < 2125200) wsa[i - 1765200] = wa0[i - 1945200];
  else if (i < 2215200) wsa[i - 1765200] = ws1[i - 2125200];
  else if (i < 2305200) wsa[i - 1765200] = wa1[i - 2215200];
  else if (i < 2305500) bsa[i - 2305200] = bs0[i - 2305200];
  else if (i < 2305800) bsa[i - 2305200] = ba0[i - 2305500];
  else if (i < 2306100) bsa[i - 2305200] = bs1[i - 2305800];
  else if (i < 2306400) bsa[i - 2305200] = ba1[i - 2306100];
}

// ---------------------------------------------------------------- MFMA GEMM (bf16x3 split), 128x64 tile
__device__ inline short2 splitf(float x) {
  unsigned u = __float_as_uint(x);
  unsigned hb = u & 0xffff0000u;
  float r = x - __uint_as_float(hb);
  unsigned lb = __float_as_uint(r);
  short2 out;
  out.x = (short)(hb >> 16);
  out.y = (short)(lb >> 16);
  return out;
}

__device__ inline short8v ld_frag(const short* p) {
  short4v a = *reinterpret_cast<const short4v*>(p);
  short4v b = *reinterpret_cast<const short4v*>(p + 16);
  short8v r;
  r[0]=a[0]; r[1]=a[1]; r[2]=a[2]; r[3]=a[3];
  r[4]=b[0]; r[5]=b[1]; r[6]=b[2]; r[7]=b[3];
  return r;
}

#define LDA_ 36   // row stride in shorts (32 + 4 pad)

template<bool NT>
__global__ __launch_bounds__(256) void k_mgemm(
    const float* __restrict__ A, int lda, long sA1, long sA2,
    const float* __restrict__ Bm, int ldb, long sB1, long sB2,
    float* __restrict__ C, bf16* __restrict__ Cbf, int ldc, long sC1, long sC2,
    const float* __restrict__ bias, long sBias,
    const float* __restrict__ rowdiv,
    float alpha, int relu, int M, int N, int K, int nb2)
{
  __shared__ short Ah[128 * LDA_], Al[128 * LDA_], Bh[64 * LDA_], Bl[64 * LDA_];
  const int tid = threadIdx.x;
  const int w = tid >> 6, l = tid & 63;
  const int z = blockIdx.z;
  const int b1 = z / nb2, b2 = z - b1 * nb2;
  const float* Ab = A + b1 * sA1 + b2 * sA2;
  const float* Bb = Bm + b1 * sB1 + b2 * sB2;
  const int row0 = blockIdx.y * 128, col0 = blockIdx.x * 64;

  f32x4 acc[2][4];
#pragma unroll
  for (int f = 0; f < 2; ++f)
#pragma unroll
    for (int c = 0; c < 4; ++c) acc[f][c] = (f32x4){0.f, 0.f, 0.f, 0.f};

  const int lrow = l & 15, lk = (l >> 4) * 4;

  for (int k0 = 0; k0 < K; k0 += 32) {
#pragma unroll
    for (int j = 0; j < 4; ++j) {
      int slot = j * 256 + tid;
      int r = slot >> 3, kq = slot & 7;
      int gr = row0 + r, gk = k0 + kq * 4;
      float v[4] = {0.f, 0.f, 0.f, 0.f};
      if (gr < M) {
        if (gk + 3 < K) {
          float4 t = *reinterpret_cast<const float4*>(Ab + (long)gr * lda + gk);
          v[0] = t.x; v[1] = t.y; v[2] = t.z; v[3] = t.w;
        } else {
#pragma unroll
          for (int q = 0; q < 4; ++q) if (gk + q < K) v[q] = Ab[(long)gr * lda + gk + q];
        }
      }
      short4v hv, lv;
#pragma unroll
      for (int q = 0; q < 4; ++q) {
        short2 t2 = splitf(v[q]);
        hv[q] = t2.x; lv[q] = t2.y;
      }
      *reinterpret_cast<short4v*>(&Ah[r * LDA_ + kq * 4]) = hv;
      *reinterpret_cast<short4v*>(&Al[r * LDA_ + kq * 4]) = lv;
    }
    if (NT) {
#pragma unroll
      for (int j = 0; j < 2; ++j) {
        int slot = j * 256 + tid;
        int r = slot >> 3, kq = slot & 7;
        int gc = col0 + r, gk = k0 + kq * 4;
        float v[4] = {0.f, 0.f, 0.f, 0.f};
        if (gc < N) {
          if (gk + 3 < K) {
            float4 t = *reinterpret_cast<const float4*>(Bb + (long)gc * ldb + gk);
            v[0] = t.x; v[1] = t.y; v[2] = t.z; v[3] = t.w;
          } else {
#pragma unroll
            for (int q = 0; q < 4; ++q) if (gk + q < K) v[q] = Bb[(long)gc * ldb + gk + q];
          }
        }
        short4v hv, lv;
#pragma unroll
        for (int q = 0; q < 4; ++q) {
          short2 t2 = splitf(v[q]);
          hv[q] = t2.x; lv[q] = t2.y;
        }
        *reinterpret_cast<short4v*>(&Bh[r * LDA_ + kq * 4]) = hv;
        *reinterpret_cast<short4v*>(&Bl[r * LDA_ + kq * 4]) = lv;
      }
    } else {
#pragma unroll
      for (int j = 0; j < 2; ++j) {
        int slot = j * 256 + tid;
        int kk = slot >> 4, nq = slot & 15;
        int gk = k0 + kk, gn = col0 + nq * 4;
        float v[4] = {0.f, 0.f, 0.f, 0.f};
        if (gk < K) {
          if (gn + 3 < N) {
            float4 t = *reinterpret_cast<const float4*>(Bb + (long)gk * ldb + gn);
            v[0] = t.x; v[1] = t.y; v[2] = t.z; v[3] = t.w;
          } else {
#pragma unroll
            for (int q = 0; q < 4; ++q) if (gn + q < N) v[q] = Bb[(long)gk * ldb + gn + q];
          }
        }
#pragma unroll
        for (int q = 0; q < 4; ++q) {
          short2 t2 = splitf(v[q]);
          Bh[(nq * 4 + q) * LDA_ + kk] = t2.x;
          Bl[(nq * 4 + q) * LDA_ + kk] = t2.y;
        }
      }
    }
    __syncthreads();

    short8v ah[2], al[2];
#pragma unroll
    for (int f = 0; f < 2; ++f) {
      int ar = w * 32 + f * 16 + lrow;
      ah[f] = ld_frag(&Ah[ar * LDA_ + lk]);
      al[f] = ld_frag(&Al[ar * LDA_ + lk]);
    }
#pragma unroll
    for (int c = 0; c < 4; ++c) {
      short8v bh = ld_frag(&Bh[(c * 16 + lrow) * LDA_ + lk]);
      short8v bl = ld_frag(&Bl[(c * 16 + lrow) * LDA_ + lk]);
#pragma unroll
      for (int f = 0; f < 2; ++f) {
        acc[f][c] = __builtin_amdgcn_mfma_f32_16x16x32_bf16(ah[f], bh, acc[f][c], 0, 0, 0);
        acc[f][c] = __builtin_amdgcn_mfma_f32_16x16x32_bf16(ah[f], bl, acc[f][c], 0, 0, 0);
        acc[f][c] = __builtin_amdgcn_mfma_f32_16x16x32_bf16(al[f], bh, acc[f][c], 0, 0, 0);
      }
    }
    __syncthreads();
  }

  float* Cb = C ? C + b1 * sC1 + b2 * sC2 : (float*)0;
  bf16*  Cf = Cbf ? Cbf + b1 * sC1 + b2 * sC2 : (bf16*)0;
#pragma unroll
  for (int f = 0; f < 2; ++f)
#pragma unroll
  for (int c = 0; c < 4; ++c) {
    int cc = col0 + c * 16 + lrow;
    if (cc >= N) continue;
#pragma unroll
    for (int reg = 0; reg < 4; ++reg) {
      int r = row0 + w * 32 + f * 16 + (l >> 4) * 4 + reg;
      if (r >= M) continue;
      float v = acc[f][c][reg] * alpha;
      if (bias) v += bias[b1 * sBias + cc];
      if (rowdiv) v /= rowdiv[(long)z * M + r];
      if (relu) v = fmaxf(v, 0.f);
      if (Cf) Cf[(long)r * ldc + cc] = __float2bfloat16(v);
      else    Cb[(long)r * ldc + cc] = v;
    }
  }
}

// ---------------------------------------------------------------- BiLSTM (u64 tagged-word sync, 150 blocks x 512 threads)
// Block owns 4 units. Poll retry has s_sleep backoff (reduces MALL spin
// congestion). Activation: 64 threads, one (unit,batch) each; u64 pair
// packing via __shfl_xor(h,1) within wave 0.
__global__ __launch_bounds__(512, 1) void k_lstm(
    const float* __restrict__ preT_f, const float* __restrict__ preT_b,
    const float* __restrict__ whh_f, const float* __restrict__ whh_b,
    const float* __restrict__ bih_f, const float* __restrict__ bhh_f,
    const float* __restrict__ bih_b, const float* __restrict__ bhh_b,
    float* __restrict__ gcn, u64* __restrict__ hg)
{
  const int tid = threadIdx.x;
  const int dir = blockIdx.x / NCH;
  const int blk = blockIdx.x - dir * NCH;
  const int u0 = blk * 4;
  const float* pre = dir ? preT_b : preT_f;
  const float* whh = dir ? whh_b : whh_f;
  const float* bih = dir ? bih_b : bih_f;
  const float* bhh = dir ? bhh_b : bhh_f;
  u64* hgd = hg + dir * 2400;                   // + buf*4800

  __shared__ float4 h5[1200];                   // h[k][b] linear
  __shared__ float part[32 * 273 + 16];         // [kc][lr pad17][b]
  __shared__ float g_lds[256];
  float* h5f = reinterpret_cast<float*>(h5);

  const int kc = tid >> 4;                      // 0..31
  const int rq = tid & 15;                      // 0..15 (one gate-row)
  const int kl = (kc < 12) ? 10 : 9;
  const int k0 = kc * 9 + min(kc, 12);

  float wreg[10];
  {
    int gate = rq >> 2, unit = rq & 3;
    int grow = gate * HR + u0 + unit;
#pragma unroll
    for (int kk = 0; kk < 10; ++kk) {
      int k = min(k0 + kk, 299);
      float wv = whh[(long)grow * HR + k];
      wreg[kk] = (kk < kl) ? wv : 0.f;
    }
  }

  // reduce role: element e0 = tid>>1, half = tid&1
  const int e0 = tid >> 1;                      // 0..255
  const int half = tid & 1;
  const int lr0 = e0 >> 4, b0 = e0 & 15;
  const int gate0 = lr0 >> 2, unit0 = lr0 & 3;
  const int grow0 = gate0 * HR + u0 + unit0;
  const float breg = bih[grow0] + bhh[grow0];
  const float* prebase = pre + (long)grow0 * 8192;

  // activation role (tid < 64): unit au2 = tid>>4, batch ab2 = tid&15
  const int au2 = tid >> 4, ab2 = tid & 15;
  float c_reg = 0.f;

  const int own_lo = u0 * 8, own_hi = (u0 + 4) * 8;   // u64-index space

#pragma unroll 1
  for (int s = 0; s < L_; ++s) {
    const int tf = dir ? (L_ - 1 - s) : s;

    float p0 = prebase[tf * 16 + b0];

    if (s > 0) {
      u64* srcb = hgd + (s & 1) * 4800;
      const u64 tag = (u64)s;
      u64 vals[5];
      int idxs[5];
#pragma unroll
      for (int j = 0; j < 5; ++j) {
        int idx = tid + j * 512;
        bool act = (idx < 2400) && (idx < own_lo || idx >= own_hi);
        idxs[j] = act ? idx : -1;
        vals[j] = act ? __hip_atomic_load(&srcb[idx], __ATOMIC_RELAXED, __HIP_MEMORY_SCOPE_AGENT)
                      : (tag << 32);
      }
      for (;;) {
        bool ok = true;
#pragma unroll
        for (int j = 0; j < 5; ++j)
          if ((vals[j] >> 32) != tag) ok = false;
        if (ok) break;
        __builtin_amdgcn_s_sleep(1);            // backoff: reduce MALL spin congestion
#pragma unroll
        for (int j = 0; j < 5; ++j)
          if ((vals[j] >> 32) != tag)
            vals[j] = __hip_atomic_load(&srcb[idxs[j]], __ATOMIC_RELAXED, __HIP_MEMORY_SCOPE_AGENT);
      }
#pragma unroll
      for (int j = 0; j < 5; ++j) {
        int idx = idxs[j];
        if (idx >= 0) {
          unsigned lo = (unsigned)(vals[j] & 0xffffffffu);
          unsigned short be = (unsigned short)(lo & 0xffffu);
          unsigned short bo = (unsigned short)(lo >> 16);
          bf16 he = *reinterpret_cast<bf16*>(&be);
          bf16 ho = *reinterpret_cast<bf16*>(&bo);
          int u = idx >> 3, bp = idx & 7;
          h5f[u * 16 + bp * 2]     = __bfloat162float(he);
          h5f[u * 16 + bp * 2 + 1] = __bfloat162float(ho);
        }
      }
    }
    __syncthreads();

    if (s > 0) {
      float4 acc[4];
#pragma unroll
      for (int q = 0; q < 4; ++q) acc[q] = make_float4(0.f, 0.f, 0.f, 0.f);
#pragma unroll
      for (int kk = 0; kk < 10; ++kk) {
        if (kk < kl) {
          int k = k0 + kk;
          float4 hb0 = h5[k * 4 + 0];
          float4 hb1 = h5[k * 4 + 1];
          float4 hb2 = h5[k * 4 + 2];
          float4 hb3 = h5[k * 4 + 3];
          float w = wreg[kk];
          acc[0].x = fmaf(w, hb0.x, acc[0].x); acc[0].y = fmaf(w, hb0.y, acc[0].y);
          acc[0].z = fmaf(w, hb0.z, acc[0].z); acc[0].w = fmaf(w, hb0.w, acc[0].w);
          acc[1].x = fmaf(w, hb1.x, acc[1].x); acc[1].y = fmaf(w, hb1.y, acc[1].y);
          acc[1].z = fmaf(w, hb1.z, acc[1].z); acc[1].w = fmaf(w, hb1.w, acc[1].w);
          acc[2].x = fmaf(w, hb2.x, acc[2].x); acc[2].y = fmaf(w, hb2.y, acc[2].y);
          acc[2].z = fmaf(w, hb2.z, acc[2].z); acc[2].w = fmaf(w, hb2.w, acc[2].w);
          acc[3].x = fmaf(w, hb3.x, acc[3].x); acc[3].y = fmaf(w, hb3.y, acc[3].y);
          acc[3].w = fmaf(w, hb3.w, acc[3].w); acc[3].z = fmaf(w, hb3.z, acc[3].z);
        }
      }
      float* pb = part + kc * 273 + rq * 17;
#pragma unroll
      for (int q = 0; q < 4; ++q) {
        pb[q * 4 + 0] = acc[q].x; pb[q * 4 + 1] = acc[q].y;
        pb[q * 4 + 2] = acc[q].z; pb[q * 4 + 3] = acc[q].w;
      }
    }
    __syncthreads();

    float sum = 0.f;
    if (s > 0) {
      const float* pb = part + half * 16 * 273 + lr0 * 17 + b0;
#pragma unroll
      for (int q = 0; q < 16; ++q) sum += pb[q * 273];
    }
    float other = __shfl_xor(sum, 1);
    if (half == 0) g_lds[e0] = p0 + breg + sum + other;
    __syncthreads();

    if (tid < 64) {
      float gi = g_lds[(0 * 4 + au2) * 16 + ab2];
      float gf = g_lds[(1 * 4 + au2) * 16 + ab2];
      float gg = g_lds[(2 * 4 + au2) * 16 + ab2];
      float go = g_lds[(3 * 4 + au2) * 16 + ab2];
      float si = 1.f / (1.f + __expf(-gi));
      float sf = 1.f / (1.f + __expf(-gf));
      float so = 1.f / (1.f + __expf(-go));
      float tg = tanhf(gg);
      c_reg = sf * c_reg + si * tg;
      float h = so * tanhf(c_reg);
      h5f[(u0 + au2) * 16 + ab2] = h;
      float hp = __shfl_xor(h, 1);              // partner batch's h
      if ((ab2 & 1) == 0) {
        bf16 hbe = __float2bfloat16(h);
        bf16 hbo = __float2bfloat16(hp);
        unsigned bitse = *reinterpret_cast<unsigned short*>(&hbe);
        unsigned bitso = *reinterpret_cast<unsigned short*>(&hbo);
        u64 val = ((u64)(s + 1) << 32) | ((u64)bitso << 16) | (u64)bitse;
        __hip_atomic_store(&hgd[((s + 1) & 1) * 4800 + (u0 + au2) * 8 + (ab2 >> 1)], val,
                           __ATOMIC_RELAXED, __HIP_MEMORY_SCOPE_AGENT);
      }
      gcn[((long)ab2 * L_ + tf) * DM_ + dir * HR + u0 + au2] = h;
    }
  }
}

// ---------------------------------------------------------------- small aspect kernels
__global__ void k_asplist(const float* __restrict__ asp_mask, int* __restrict__ apos, int* __restrict__ acnt)
{
  int b = threadIdx.x;
  if (b >= B_) return;
  int c = 0;
  for (int l = 0; l < L_; ++l)
    if (asp_mask[b * L_ + l] > 0.f) { if (c < MAXA) apos[b * MAXA + c] = l; ++c; }
  acnt[b] = (c < MAXA) ? c : MAXA;
}

__global__ void k_t0(const float* __restrict__ bd, const float* __restrict__ wm, float* __restrict__ t0)
{
  int i = blockIdx.x * 256 + threadIdx.x;
  if (i >= 8 * DK_) return;
  int h = i / DK_, e = i % DK_;
  float s = 0.f;
  for (int d = 0; d < DK_; ++d) s += bd[d] * wm[(h * DK_ + d) * DK_ + e];
  t0[i] = s;
}

__global__ void k_aspd(const float* __restrict__ gcn, const float* __restrict__ asp_mask,
                       const int* __restrict__ apos, const int* __restrict__ acnt,
                       const float* __restrict__ wd, const float* __restrict__ bd, float* __restrict__ aspd)
{
  int i = blockIdx.x * 256 + threadIdx.x;
  if (i >= B_ * MAXA * DK_) return;
  int d = i % DK_;
  int ba = i / DK_;
  int a = ba % MAXA, b = ba / MAXA;
  if (a >= acnt[b]) { aspd[i] = 0.f; return; }
  int p = apos[b * MAXA + a];
  float mv = asp_mask[b * L_ + p];
  const float* row = gcn + ((long)b * L_ + p) * DM_;
  float s = 0.f;
  for (int k = 0; k < DM_; ++k) s += row[k] * wd[d * DM_ + k];
  aspd[i] = s * mv + bd[d];
}

__global__ void k_tasp(const float* __restrict__ aspd, const int* __restrict__ acnt,
                       const float* __restrict__ wm, float* __restrict__ tasp)
{
  int i = blockIdx.x * 256 + threadIdx.x;
  if (i >= B_ * 8 * MAXA * DK_) return;
  int e = i % DK_;
  int t3 = i / DK_;
  int a = t3 % MAXA;
  int t4 = t3 / MAXA;
  int h = t4 % 8, b = t4 / 8;
  if (a >= acnt[b]) { tasp[i] = 0.f; return; }
  const float* ar = aspd + (b * MAXA + a) * DK_;
  float s = 0.f;
  for (int d = 0; d < DK_; ++d) s += ar[d] * wm[(h * DK_ + d) * DK_ + e];
  tasp[i] = s;
}

__global__ void k_avg(const float* __restrict__ k_lin, const float* __restrict__ t0,
                      const float* __restrict__ tasp, const int* __restrict__ acnt,
                      const float* __restrict__ bias_m, float* __restrict__ s0, float* __restrict__ avg)
{
  int i = blockIdx.x * 256 + threadIdx.x;
  if (i >= B_ * 8 * L_) return;
  int m = i % L_;
  int bh = i / L_;
  int h = bh % 8, b = bh / 8;
  const float* kr = k_lin + ((long)b * L_ + m) * DM_ + h * DK_;
  float bm = bias_m[0];
  const float* t0r = t0 + h * DK_;
  float d0 = 0.f;
  for (int e = 0; e < DK_; ++e) d0 += t0r[e] * kr[e];
  float sv = tanhf(d0 + bm);
  int cnt = acnt[b];
  float acc = (float)(L_ - cnt) * sv;
  for (int a = 0; a < cnt; ++a) {
    const float* tr = tasp + (((b * 8 + h) * MAXA) + a) * DK_;
    float dd = 0.f;
    for (int e = 0; e < DK_; ++e) dd += tr[e] * kr[e];
    acc += tanhf(dd + bm);
  }
  s0[i] = sv;
  avg[i] = acc * (1.f / (float)L_);
}

__global__ void k_bar(const float* __restrict__ s0, const float* __restrict__ avg,
                      float* __restrict__ s0bar, float* __restrict__ avbar)
{
  int i = blockIdx.x * 256 + threadIdx.x;
  if (i >= B_ * L_) return;
  int m = i % L_, b = i / L_;
  float sa = 0.f, aa = 0.f;
  for (int h = 0; h < 8; ++h) { sa += s0[(b * 8 + h) * L_ + m]; aa += avg[(b * 8 + h) * L_ + m]; }
  s0bar[i] = sa * 0.125f;
  avbar[i] = aa * 0.125f;
}

__global__ __launch_bounds__(256) void k_adjag(
    const float* __restrict__ asp_mask, const float* __restrict__ adjr,
    const float* __restrict__ s0bar, const float* __restrict__ avbar,
    float* __restrict__ adjag, float* __restrict__ denag)
{
  int bl = blockIdx.x;
  int b = bl >> 9, l = bl & 511;
  bool rA = asp_mask[b * L_ + l] > 0.f;
  float avl = avbar[b * L_ + l];
  float lsum = 0.f;
  for (int q = 0; q < 2; ++q) {
    int m = threadIdx.x + q * 256;
    bool cA = asp_mask[b * L_ + m] > 0.f;
    float asv;
    if (cA && (!rA || m > l)) asv = avl;
    else if (rA)              asv = avbar[b * L_ + m];
    else                      asv = s0bar[b * L_ + m];
    float r = (asv > 0.9f) ? 1.f : __expf(0.8f * adjr[((long)b * L_ + l) * L_ + m]);
    float v = r * asv;
    adjag[((long)b * L_ + l) * L_ + m] = v;
    lsum += v;
  }
  __shared__ float red[256];
  red[threadIdx.x] = lsum;
  __syncthreads();
  for (int st = 128; st > 0; st >>= 1) {
    if (threadIdx.x < st) red[threadIdx.x] += red[threadIdx.x + st];
    __syncthreads();
  }
  if (threadIdx.x == 0) denag[bl] = red[0] + 1.f;
}

// fused stats + head-mean softmax + diag/mask + denom; one block per (b,l)
__global__ __launch_bounds__(256) void k_adjs2(
    const bf16* __restrict__ sc, const int* __restrict__ tok,
    float* __restrict__ adjs, float* __restrict__ dens)
{
  int bl = blockIdx.x;
  int b = bl >> 9, l = bl & 511;
  int tid = threadIdx.x;
  __shared__ float srow[8][512];
  __shared__ float stats[16];    // mx[0..7], inv[8..15]
  __shared__ float red[256];

  int t0v = tok[b * L_ + tid], t1v = tok[b * L_ + tid + 256];
#pragma unroll
  for (int h = 0; h < 8; ++h) {
    const bf16* p = sc + ((long)((b * 8 + h) * L_) + l) * L_;
    float v0 = __bfloat162float(p[tid]);
    float v1 = __bfloat162float(p[tid + 256]);
    srow[h][tid]       = (t0v != 0) ? v0 : -1e9f;
    srow[h][tid + 256] = (t1v != 0) ? v1 : -1e9f;
  }
  __syncthreads();

  int wv = tid >> 6, lane = tid & 63;
#pragma unroll
  for (int hh = 0; hh < 2; ++hh) {
    int h = wv * 2 + hh;
    float vv[8];
#pragma unroll
    for (int i = 0; i < 8; ++i) vv[i] = srow[h][lane + i * 64];
    float m = vv[0];
#pragma unroll
    for (int i = 1; i < 8; ++i) m = fmaxf(m, vv[i]);
    for (int off = 32; off > 0; off >>= 1) m = fmaxf(m, __shfl_xor(m, off));
    float s = 0.f;
#pragma unroll
    for (int i = 0; i < 8; ++i) s += __expf(vv[i] - m);
    for (int off = 32; off > 0; off >>= 1) s += __shfl_xor(s, off);
    if (lane == 0) { stats[h] = m; stats[8 + h] = 1.f / s; }
  }
  __syncthreads();

  float acc0 = 0.f, acc1 = 0.f;
#pragma unroll
  for (int h = 0; h < 8; ++h) {
    float m = stats[h], inv = stats[8 + h];
    acc0 += __expf(srow[h][tid] - m) * inv;
    acc1 += __expf(srow[h][tid + 256] - m) * inv;
  }
  float rmask = (tok[b * L_ + l] != 0) ? 1.f : 0.f;
  float lsum = 0.f;
  {
    int m = tid;
    float v = acc0 * 0.125f;
    v = (m == l) ? 1.f : v;
    v *= rmask;
    adjs[(long)bl * L_ + m] = v;
    lsum += v;
  }
  {
    int m = tid + 256;
    float v = acc1 * 0.125f;
    v = (m == l) ? 1.f : v;
    v *= rmask;
    adjs[(long)bl * L_ + m] = v;
    lsum += v;
  }
  red[tid] = lsum;
  __syncthreads();
  for (int st = 128; st > 0; st >>= 1) {
    if (tid < st) red[tid] += red[tid + st];
    __syncthreads();
  }
  if (tid == 0) dens[bl] = red[0] + 1.f;
}

__global__ __launch_bounds__(256) void k_softmax(float* __restrict__ X)
{
  long row = blockIdx.x;
  float* p = X + row * L_;
  int tid = threadIdx.x;
  float a = p[tid], b = p[tid + 256];
  __shared__ float red[256];
  red[tid] = fmaxf(a, b);
  __syncthreads();
  for (int st = 128; st > 0; st >>= 1) {
    if (tid < st) red[tid] = fmaxf(red[tid], red[tid + st]);
    __syncthreads();
  }
  float mxv = red[0];
  __syncthreads();
  float ea = __expf(a - mxv), eb = __expf(b - mxv);
  red[tid] = ea + eb;
  __syncthreads();
  for (int st = 128; st > 0; st >>= 1) {
    if (tid < st) red[tid] += red[tid + st];
    __syncthreads();
  }
  float inv = 1.f / red[0];
  p[tid] = ea * inv;
  p[tid + 256] = eb * inv;
}

// ---------------------------------------------------------------- host side
static void gemm(hipStream_t st, bool nt,
                 const float* A, int lda, long sA1, long sA2,
                 const float* Bm, int ldb, long sB1, long sB2,
                 float* C, bf16* Cbf, int ldc, long sC1, long sC2,
                 const float* bias, long sBias, const float* rowdiv,
                 float alpha, int relu, int M, int N, int K, int nb1, int nb2)
{
  dim3 g((N + 63) / 64, (M + 127) / 128, nb1 * nb2);
  if (nt)
    k_mgemm<true><<<g, 256, 0, st>>>(A, lda, sA1, sA2, Bm, ldb, sB1, sB2, C, Cbf, ldc, sC1, sC2,
                                     bias, sBias, rowdiv, alpha, relu, M, N, K, nb2);
  else
    k_mgemm<false><<<g, 256, 0, st>>>(A, lda, sA1, sA2, Bm, ldb, sB1, sB2, C, Cbf, ldc, sC1, sC2,
                                      bias, sBias, rowdiv, alpha, relu, M, N, K, nb2);
}

extern "C" void kernel_launch(void* const* d_in, const int* in_sizes, int n_in,
                              void* d_out, int out_size, void* d_ws, size_t ws_size,
                              hipStream_t stream)
{
  const int*   tok     = (const int*)d_in[0];
  const int*   pos     = (const int*)d_in[1];
  const int*   post    = (const int*)d_in[2];
  const float* asp_mask= (const float*)d_in[3];
  const float* adjr    = (const float*)d_in[5];
  const float* emb_w   = (const float*)d_in[6];
  const float* pos_w   = (const float*)d_in[7];
  const float* post_w  = (const float*)d_in[8];
  const float* w_ih_f  = (const float*)d_in[9];
  const float* w_hh_f  = (const float*)d_in[10];
  const float* b_ih_f  = (const float*)d_in[11];
  const float* b_hh_f  = (const float*)d_in[12];
  const float* w_ih_b  = (const float*)d_in[13];
  const float* w_hh_b  = (const float*)d_in[14];
  const float* b_ih_b  = (const float*)d_in[15];
  const float* b_hh_b  = (const float*)d_in[16];
  const float* wq      = (const float*)d_in[17];
  const float* bq      = (const float*)d_in[18];
  const float* wk      = (const float*)d_in[19];
  const float* bk      = (const float*)d_in[20];
  const float* wd      = (const float*)d_in[21];
  const float* bd      = (const float*)d_in[22];
  const float* wm      = (const float*)d_in[23];
  const float* bias_m  = (const float*)d_in[24];
  const float* wa0     = (const float*)d_in[25];
  const float* ba0     = (const float*)d_in[26];
  const float* wa1     = (const float*)d_in[27];
  const float* ba1     = (const float*)d_in[28];
  const float* ws0     = (const float*)d_in[29];
  const float* bs0     = (const float*)d_in[30];
  const float* ws1     = (const float*)d_in[31];
  const float* bs1     = (const float*)d_in[32];
  const float* aff1    = (const float*)d_in[33];
  const float* aff2    = (const float*)d_in[34];
  float* out = (float*)d_out;
  float* W = (float*)d_ws;

  // ---- workspace layout (float units) ----
  size_t off = 0;
  auto alloc = [&](size_t n) { size_t o = off; off += (n + 63) & ~(size_t)63; return o; };
  size_t o_gcn   = alloc((size_t)8192 * DM_);
  size_t o_q     = alloc((size_t)8192 * DM_);
  size_t o_k     = alloc((size_t)8192 * DM_);
  size_t o_adjs  = alloc((size_t)B_ * L_ * L_);
  size_t o_adjag = alloc((size_t)B_ * L_ * L_);
  size_t o_dens  = alloc(8192);          // dens FIRST, denag at +8192 (stage2 rowdiv z-index)
  size_t o_denag = alloc(8192);
  size_t o_t0    = alloc(600);
  size_t o_apos  = alloc(B_ * MAXA);
  size_t o_acnt  = alloc(64);
  size_t o_aspd  = alloc(B_ * MAXA * DK_);
  size_t o_tasp  = alloc(B_ * 8 * MAXA * DK_);
  size_t o_s0    = alloc(B_ * 8 * L_);
  size_t o_avg   = alloc(B_ * 8 * L_);
  size_t o_s0bar = alloc(B_ * L_);
  size_t o_avbar = alloc(B_ * L_);
  size_t o_hg    = alloc(2 * 2 * 4800);  // u64 tagged-h pairs
  size_t o_wqk   = alloc(720000);
  size_t o_bqk   = alloc(1200);
  size_t o_wih   = alloc(864000);
  size_t o_aff   = alloc(180000);
  size_t o_wsa   = alloc(540000);        // [ws0][wa0][ws1][wa1]
  size_t o_bsa   = alloc(1200);          // [bs0][ba0][bs1][ba1]
  size_t o_oag1  = alloc((size_t)8192 * 300);
  size_t o_os1   = alloc((size_t)8192 * 300);
  size_t o_big   = alloc(23134300);      // union region
  size_t o_embs = o_big;
  size_t o_pref = o_big + 2949120;
  size_t o_preb = o_pref + 9830400;
  size_t o_sc   = o_big;
  size_t o_tmp  = o_big;                 // tmpA (ag path)
  size_t o_gag  = o_big + 4915200;
  size_t o_gs   = o_gag + 2457600;
  size_t o_h1   = o_gs  + 2457600;       // h1b = o_h1 + 2457600
  size_t o_a1m  = o_h1  + 4915200;       // also tmpS (s path) during stage1/2
  size_t o_a2m  = o_a1m + 4194304;

  if (ws_size < off * sizeof(float)) {
    (void)hipMemsetAsync(d_out, 0x7F, (size_t)out_size * sizeof(float), stream);
    return;
  }

  // 0) stage packed weights
  k_stage<<<(2306400 + 255) / 256, 256, 0, stream>>>(
      wq, wk, bq, bk, w_ih_f, w_ih_b, aff1, aff2,
      ws0, wa0, ws1, wa1, bs0, ba0, bs1, ba1,
      W + o_wqk, W + o_bqk, W + o_wih, W + o_aff, W + o_wsa, W + o_bsa);

  // 1) embeddings -> [t*16+b][360]
  k_embed<<<(L_ * B_ * 360 + 255) / 256, 256, 0, stream>>>(tok, pos, post, emb_w, pos_w, post_w, W + o_embs);

  // 2) pre-GEMMs batched (z=2): preT[j][t*16+b] = w_ih[j] . embs
  gemm(stream, true, W + o_wih, 360, 432000, 0, W + o_embs, 360, 0, 0,
       W + o_pref, nullptr, 8192, 9830400, 0, nullptr, 0, nullptr, 1.f, 0, 1200, 8192, 360, 2, 1);

  // 3) BiLSTM: 150 sharded blocks (4 units each), u64 tagged-word sync
  k_lstm<<<2 * NCH, 512, 0, stream>>>(W + o_pref, W + o_preb, w_hh_f, w_hh_b,
                                      b_ih_f, b_hh_f, b_ih_b, b_hh_b,
                                      W + o_gcn, (u64*)(W + o_hg));

  // 4) q/k batched (z=2)
  gemm(stream, true, W + o_gcn, DM_, 0, 0, W + o_wqk, DM_, 360000, 0,
       W + o_q, nullptr, DM_, (long)(o_k - o_q), 0, W + o_bqk, 600, nullptr,
       1.f, 0, 8192, DM_, DM_, 2, 1);

  // 5) aspect structure
  k_asplist<<<1, 64, 0, stream>>>(asp_mask, (int*)(W + o_apos), (int*)(W + o_acnt));
  k_t0<<<(600 + 255) / 256, 256, 0, stream>>>(bd, wm, W + o_t0);
  k_aspd<<<(B_ * MAXA * DK_ + 255) / 256, 256, 0, stream>>>(W + o_gcn, asp_mask,
      (const int*)(W + o_apos), (const int*)(W + o_acnt), wd, bd, W + o_aspd);
  k_tasp<<<(B_ * 8 * MAXA * DK_ + 255) / 256, 256, 0, stream>>>(W + o_aspd,
      (const int*)(W + o_acnt), wm, W + o_tasp);
  k_avg<<<(B_ * 8 * L_ + 255) / 256, 256, 0, stream>>>(W + o_k, W + o_t0, W + o_tasp,
      (const int*)(W + o_acnt), bias_m, W + o_s0, W + o_avg);
  k_bar<<<(B_ * L_ + 255) / 256, 256, 0, stream>>>(W + o_s0, W + o_avg, W + o_s0bar, W + o_avbar);

  // 6) scores (bf16) -> fused adj_s ; adj_ag
  gemm(stream, true, W + o_q, DM_, (long)L_ * DM_, DK_, W + o_k, DM_, (long)L_ * DM_, DK_,
       nullptr, (bf16*)(W + o_sc), L_, (long)8 * L_ * L_, (long)L_ * L_,
       nullptr, 0, nullptr, 0.1154700538f, 0, L_, L_, DK_, B_, 8);
  k_adjs2<<<B_ * L_, 256, 0, stream>>>((const bf16*)(W + o_sc), tok, W + o_adjs, W + o_dens);
  k_adjag<<<B_ * L_, 256, 0, stream>>>(asp_mask, adjr, W + o_s0bar, W + o_avbar,
                                       W + o_adjag, W + o_denag);

  // 7) two GCN layers
  const float* inBase;
  long inStride;
  const long tmpStride = (long)o_tmp - (long)o_a1m;   // tmpS at o_a1m, tmpA at o_tmp
  int D = DM_;
  for (int layer = 0; layer < 2; ++layer) {
    if (layer == 0) { inBase = W + o_gcn; inStride = 0; }
    else            { inBase = W + o_os1; inStride = (long)o_oag1 - (long)o_os1; }
    // stage1 batched z=32 (b1: 0=s path, 1=ag path; b2=batch): tmp = adj @ in
    gemm(stream, false,
         W + o_adjs, L_, (long)o_adjag - (long)o_adjs, (long)L_ * L_,
         inBase, D, inStride, (long)L_ * D,
         W + o_a1m, nullptr, D, tmpStride, (long)L_ * D,
         nullptr, 0, nullptr, 1.f, 0, L_, D, L_, 2, B_);
    // stage2 batched z=2: g = relu((tmp @ w^T + b) / denom)
    gemm(stream, true,
         W + o_a1m, D, tmpStride, 0,
         W + o_wsa + (layer ? 360000 : 0), D, (layer ? 90000 : 180000), 0,
         W + o_gs, nullptr, 300, (long)o_gag - (long)o_gs, 0,
         W + o_bsa + (layer ? 600 : 0), 300, W + o_dens,
         1.f, 1, 8192, 300, D, 2, 1);
    // affine batched (z=2): h1 = gag@aff1 ; h1b = gs@aff2
    gemm(stream, false, W + o_gag, 300, (long)(o_gs - o_gag), 0, W + o_aff, 300, 90000, 0,
         W + o_h1, nullptr, 300, 2457600, 0, nullptr, 0, nullptr, 1.f, 0, 8192, 300, 300, 2, 1);
    // A1/A2 batched (z=2x16): a1m = h1 @ gs^T ; a2m = h1b @ gag^T
    gemm(stream, true, W + o_h1, 300, 2457600, (long)L_ * 300,
         W + o_gs, 300, (long)o_gag - (long)o_gs, (long)L_ * 300,
         W + o_a1m, nullptr, L_, 4194304, (long)L_ * L_,
         nullptr, 0, nullptr, 1.f, 0, L_, L_, 300, 2, B_);
    k_softmax<<<2 * B_ * L_, 256, 0, stream>>>(W + o_a1m);
    // out batched (z=2x16): out_ag = A1 @ gs ; out_s = A2 @ gag
    float* dstC; int ldcO; long sC1o, sC2o;
    if (layer == 0) { dstC = W + o_oag1; ldcO = 300; sC1o = (long)(o_os1 - o_oag1); sC2o = (long)L_ * 300; }
    else            { dstC = out;        ldcO = 600; sC1o = 300;                    sC2o = (long)L_ * 600; }
    gemm(stream, false, W + o_a1m, L_, 4194304, (long)L_ * L_,
         W + o_gs, 300, (long)o_gag - (long)o_gs, (long)L_ * 300,
         dstC, nullptr, ldcO, sC1o, sC2o,
         nullptr, 0, nullptr, 1.f, 0, L_, 300, L_, 2, B_);
    D = 300;
  }
}